// Round 2
// baseline (405.960 us; speedup 1.0000x reference)
//
#include <hip/hip_runtime.h>
#include <hip/hip_bf16.h>
#include <cstdint>
#include <cstddef>

#define D_ 1024
#define H_ 16
#define HD_ 64
#define T_ 2048
#define B_ 2
#define FF_ 4096
#define BT_ (B_*T_)   // 4096 rows

typedef unsigned short u16;
typedef __attribute__((ext_vector_type(8))) __bf16 bf16x8;
typedef __attribute__((ext_vector_type(4))) float f32x4;

__device__ __forceinline__ u16 f2bf(float f) {
  unsigned u = __builtin_bit_cast(unsigned, f);
  u += 0x7FFFu + ((u >> 16) & 1u);
  return (u16)(u >> 16);
}

__device__ __forceinline__ void gload16(const void* g, void* l) {
  __builtin_amdgcn_global_load_lds((__attribute__((address_space(1))) void*)g,
                                   (__attribute__((address_space(3))) void*)l, 16, 0, 0);
}

// ---------------- transpose + fp32->bf16 cast:  out[(z*C+c)*R + r] = in[z*R*C + r*C + c]
__global__ __launch_bounds__(256) void transpose_w(const float* __restrict__ in,
                                                   u16* __restrict__ out, int R, int C) {
  __shared__ float tile[32][33];
  const int z = blockIdx.z;
  const float* inz = in + (size_t)z * R * C;
  const int x = blockIdx.x * 32 + threadIdx.x;
  const int y0 = blockIdx.y * 32 + threadIdx.y;
  #pragma unroll
  for (int j = 0; j < 32; j += 8)
    tile[threadIdx.y + j][threadIdx.x] = inz[(size_t)(y0 + j) * C + x];
  __syncthreads();
  const int orr = blockIdx.y * 32 + threadIdx.x;   // output col (input row)
  const int oc0 = blockIdx.x * 32 + threadIdx.y;   // output row (input col)
  u16* outz = out + (size_t)z * C * R;
  #pragma unroll
  for (int j = 0; j < 32; j += 8)
    outz[(size_t)(oc0 + j) * R + orr] = f2bf(tile[threadIdx.x][threadIdx.y + j]);
}

// ---------------- LayerNorm (fp32 in -> bf16 out), one row (D=1024) per block of 256
__global__ __launch_bounds__(256) void ln_rows(const float* __restrict__ x,
    const float* __restrict__ g, const float* __restrict__ bb, u16* __restrict__ out) {
  const int row = blockIdx.x, tid = threadIdx.x;
  const float4 v = ((const float4*)(x + (size_t)row * D_))[tid];
  float s = v.x + v.y + v.z + v.w;
  float sq = v.x*v.x + v.y*v.y + v.z*v.z + v.w*v.w;
  #pragma unroll
  for (int m = 1; m < 64; m <<= 1) { s += __shfl_xor(s, m); sq += __shfl_xor(sq, m); }
  __shared__ float ss[4], qs[4];
  if ((tid & 63) == 0) { ss[tid >> 6] = s; qs[tid >> 6] = sq; }
  __syncthreads();
  s  = ss[0] + ss[1] + ss[2] + ss[3];
  sq = qs[0] + qs[1] + qs[2] + qs[3];
  const float mean = s * (1.f / D_);
  const float var  = sq * (1.f / D_) - mean * mean;
  const float rstd = rsqrtf(var + 1e-5f);
  const float4 gv = ((const float4*)g)[tid];
  const float4 bv = ((const float4*)bb)[tid];
  u16 o[4];
  o[0] = f2bf((v.x - mean) * rstd * gv.x + bv.x);
  o[1] = f2bf((v.y - mean) * rstd * gv.y + bv.y);
  o[2] = f2bf((v.z - mean) * rstd * gv.z + bv.z);
  o[3] = f2bf((v.w - mean) * rstd * gv.w + bv.w);
  *(ushort4*)(out + (size_t)row * D_ + tid * 4) = *(ushort4*)o;
}

// ---------------- GEMM: C[M,N] = act(A[M,K] * Bt[N,K]^T + bias) (+resid)
// m97 structure: 128x128 tile, BK=32, 4 waves (2x2 of 64x64), global_load_lds w=16.
template<int ACT, int BIAS, int RESID, int OUTBF>
__global__ __launch_bounds__(256) void gemm_bt(
    const u16* __restrict__ A, const u16* __restrict__ Bt,
    const float* __restrict__ bias, const float* resid,
    void* Cout, int M, int N, int K) {
  __shared__ __attribute__((aligned(16))) u16 As[128 * 32];
  __shared__ __attribute__((aligned(16))) u16 Bs[128 * 32];
  const int tid = threadIdx.x;
  const int wid = tid >> 6, lane = tid & 63;
  const int bm = blockIdx.y * 128, bn = blockIdx.x * 128;
  const int wm = (wid >> 1) * 64, wn = (wid & 1) * 64;

  f32x4 acc[4][4] = {};

  const u16* Ag = A + (size_t)(bm + wid * 32 + (lane >> 2)) * K + (lane & 3) * 8;
  const u16* Bg = Bt + (size_t)(bn + wid * 32 + (lane >> 2)) * K + (lane & 3) * 8;
  u16* AsW = As + (wid * 32) * 32;
  u16* BsW = Bs + (wid * 32) * 32;
  const int ro = (lane & 15) * 32 + (lane >> 4) * 8;

  for (int k0 = 0; k0 < K; k0 += 32) {
    gload16(Ag + k0,                 AsW);
    gload16(Ag + k0 + (size_t)16 * K, AsW + 16 * 32);
    gload16(Bg + k0,                 BsW);
    gload16(Bg + k0 + (size_t)16 * K, BsW + 16 * 32);
    __syncthreads();
    bf16x8 af[4], bfr[4];
    #pragma unroll
    for (int i = 0; i < 4; i++) af[i]  = *(const bf16x8*)(As + (wm + i * 16) * 32 + ro);
    #pragma unroll
    for (int i = 0; i < 4; i++) bfr[i] = *(const bf16x8*)(Bs + (wn + i * 16) * 32 + ro);
    #pragma unroll
    for (int mi = 0; mi < 4; mi++)
      #pragma unroll
      for (int ni = 0; ni < 4; ni++)
        acc[mi][ni] = __builtin_amdgcn_mfma_f32_16x16x32_bf16(af[mi], bfr[ni], acc[mi][ni], 0, 0, 0);
    __syncthreads();
  }

  const int r0 = bm + wm + ((lane >> 4) << 2);
  const int c0 = bn + wn + (lane & 15);
  #pragma unroll
  for (int mi = 0; mi < 4; mi++) {
    #pragma unroll
    for (int ni = 0; ni < 4; ni++) {
      #pragma unroll
      for (int r = 0; r < 4; r++) {
        float v = acc[mi][ni][r];
        const int rr = r0 + mi * 16 + r;
        const int cc = c0 + ni * 16;
        if (BIAS) v += bias[cc];
        if (ACT == 1) v = 0.5f * v * (1.0f + erff(v * 0.70710678118f));
        if (RESID) v += resid[(size_t)rr * N + cc];
        if (OUTBF) ((u16*)Cout)[(size_t)rr * N + cc] = f2bf(v);
        else       ((float*)Cout)[(size_t)rr * N + cc] = v;
      }
    }
  }
}

// ---------------- repack qkv [bt, 3*D] -> q,k [bh, T, 64] and v^T [bh, 64, T]
__global__ __launch_bounds__(256) void repack_qkv(const u16* __restrict__ qkv,
    u16* __restrict__ q, u16* __restrict__ k, u16* __restrict__ vt) {
  const int t0 = blockIdx.x * 64, bh = blockIdx.y;
  const int b = bh >> 4, h = bh & 15;
  const int tid = threadIdx.x;
  const int c = (tid & 7) * 8;
  __shared__ __attribute__((aligned(16))) u16 vs[64][72];
  #pragma unroll
  for (int p = 0; p < 2; p++) {
    const int tl = p * 32 + (tid >> 3);
    const size_t inrow = ((size_t)b * T_ + t0 + tl) * 3072 + h * 64;
    bf16x8 qv = *(const bf16x8*)(qkv + inrow + c);
    bf16x8 kv = *(const bf16x8*)(qkv + inrow + 1024 + c);
    bf16x8 vv = *(const bf16x8*)(qkv + inrow + 2048 + c);
    *(bf16x8*)(q + ((size_t)bh * T_ + t0 + tl) * HD_ + c) = qv;
    *(bf16x8*)(k + ((size_t)bh * T_ + t0 + tl) * HD_ + c) = kv;
    *(bf16x8*)&vs[tl][c] = vv;
  }
  __syncthreads();
  const int d = tid >> 2, tc = (tid & 3) * 16;
  alignas(16) u16 tmp[16];
  #pragma unroll
  for (int j = 0; j < 16; j++) tmp[j] = vs[tc + j][d];
  *(bf16x8*)(vt + ((size_t)bh * HD_ + d) * T_ + t0 + tc)     = *(bf16x8*)&tmp[0];
  *(bf16x8*)(vt + ((size_t)bh * HD_ + d) * T_ + t0 + tc + 8) = *(bf16x8*)&tmp[8];
}

// ---------------- flash attention: 64 q-rows per block (4 waves x 16 rows), causal
__global__ __launch_bounds__(256) void attn_fwd(
    const u16* __restrict__ q, const u16* __restrict__ k,
    const u16* __restrict__ vt, u16* __restrict__ out) {
  __shared__ __attribute__((aligned(16))) u16 Qs[64][72];
  __shared__ __attribute__((aligned(16))) u16 Ks[64][72];
  __shared__ __attribute__((aligned(16))) u16 Vs[64][72];
  __shared__ __attribute__((aligned(16))) u16 Ps[64][72];
  const int qt = blockIdx.x, bh = blockIdx.y;
  const int b = bh >> 4, h = bh & 15;
  const int tid = threadIdx.x, wid = tid >> 6, lane = tid & 63;
  const int q0 = qt * 64;
  const int cst = (tid & 7) * 8;

  #pragma unroll
  for (int p = 0; p < 2; p++) {
    const int t = p * 32 + (tid >> 3);
    *(bf16x8*)&Qs[t][cst] = *(const bf16x8*)(q + ((size_t)bh * T_ + q0 + t) * HD_ + cst);
  }
  __syncthreads();
  const int frow = lane & 15, fk = (lane >> 4) * 8;
  bf16x8 aq[2];
  aq[0] = *(const bf16x8*)&Qs[wid * 16 + frow][fk];
  aq[1] = *(const bf16x8*)&Qs[wid * 16 + frow][32 + fk];

  float m_r[4] = {-1e30f, -1e30f, -1e30f, -1e30f};
  float l_r[4] = {0.f, 0.f, 0.f, 0.f};
  f32x4 acc_o[4] = {};
  const int rowb = (lane >> 4) * 4;
  const int colb = lane & 15;

  for (int kt = 0; kt <= qt; ++kt) {
    __syncthreads();
    #pragma unroll
    for (int p = 0; p < 2; p++) {
      const int t = p * 32 + (tid >> 3);
      *(bf16x8*)&Ks[t][cst] = *(const bf16x8*)(k + ((size_t)bh * T_ + kt * 64 + t) * HD_ + cst);
      *(bf16x8*)&Vs[t][cst] = *(const bf16x8*)(vt + ((size_t)bh * HD_ + t) * T_ + kt * 64 + cst);
    }
    __syncthreads();

    float p_[4][4];
    #pragma unroll
    for (int ni = 0; ni < 4; ni++) {
      f32x4 s = {};
      #pragma unroll
      for (int ks = 0; ks < 2; ks++) {
        bf16x8 bk = *(const bf16x8*)&Ks[ni * 16 + frow][ks * 32 + fk];
        s = __builtin_amdgcn_mfma_f32_16x16x32_bf16(aq[ks], bk, s, 0, 0, 0);
      }
      #pragma unroll
      for (int r = 0; r < 4; r++) {
        float sv = s[r] * 0.125f;
        if (kt == qt && (ni * 16 + colb) > (wid * 16 + rowb + r)) sv = -1e30f;
        p_[ni][r] = sv;
      }
    }
    #pragma unroll
    for (int r = 0; r < 4; r++) {
      float rm = fmaxf(fmaxf(p_[0][r], p_[1][r]), fmaxf(p_[2][r], p_[3][r]));
      rm = fmaxf(rm, __shfl_xor(rm, 1));
      rm = fmaxf(rm, __shfl_xor(rm, 2));
      rm = fmaxf(rm, __shfl_xor(rm, 4));
      rm = fmaxf(rm, __shfl_xor(rm, 8));
      const float mnew = fmaxf(m_r[r], rm);
      const float corr = __expf(m_r[r] - mnew);
      m_r[r] = mnew;
      float rs = 0.f;
      #pragma unroll
      for (int ni = 0; ni < 4; ni++) { p_[ni][r] = __expf(p_[ni][r] - mnew); rs += p_[ni][r]; }
      rs += __shfl_xor(rs, 1); rs += __shfl_xor(rs, 2);
      rs += __shfl_xor(rs, 4); rs += __shfl_xor(rs, 8);
      l_r[r] = l_r[r] * corr + rs;
      #pragma unroll
      for (int ni = 0; ni < 4; ni++) acc_o[ni][r] *= corr;
    }
    #pragma unroll
    for (int ni = 0; ni < 4; ni++)
      #pragma unroll
      for (int r = 0; r < 4; r++)
        Ps[wid * 16 + rowb + r][ni * 16 + colb] = f2bf(p_[ni][r]);
    bf16x8 ap[2];
    ap[0] = *(const bf16x8*)&Ps[wid * 16 + frow][fk];
    ap[1] = *(const bf16x8*)&Ps[wid * 16 + frow][32 + fk];
    #pragma unroll
    for (int ni = 0; ni < 4; ni++) {
      #pragma unroll
      for (int ks = 0; ks < 2; ks++) {
        bf16x8 bv = *(const bf16x8*)&Vs[ni * 16 + frow][ks * 32 + fk];
        acc_o[ni] = __builtin_amdgcn_mfma_f32_16x16x32_bf16(ap[ks], bv, acc_o[ni], 0, 0, 0);
      }
    }
  }

  #pragma unroll
  for (int ni = 0; ni < 4; ni++)
    #pragma unroll
    for (int r = 0; r < 4; r++) {
      const float ov = acc_o[ni][r] / l_r[r];
      const size_t row = (size_t)b * T_ + q0 + wid * 16 + rowb + r;
      out[row * D_ + h * HD_ + ni * 16 + colb] = f2bf(ov);
    }
}

extern "C" void kernel_launch(void* const* d_in, const int* in_sizes, int n_in,
                              void* d_out, int out_size, void* d_ws, size_t ws_size,
                              hipStream_t stream) {
  (void)in_sizes; (void)n_in; (void)out_size; (void)ws_size;
  const float* x      = (const float*)d_in[0];
  const float* wq     = (const float*)d_in[1];
  const float* wk     = (const float*)d_in[2];
  const float* wv     = (const float*)d_in[3];
  const float* w_proj = (const float*)d_in[4];
  const float* b_proj = (const float*)d_in[5];
  const float* ln1_g  = (const float*)d_in[6];
  const float* ln1_b  = (const float*)d_in[7];
  const float* ln2_g  = (const float*)d_in[8];
  const float* ln2_b  = (const float*)d_in[9];
  const float* w1     = (const float*)d_in[10];
  const float* b1     = (const float*)d_in[11];
  const float* w2     = (const float*)d_in[12];
  const float* b2     = (const float*)d_in[13];

  uint8_t* ws = (uint8_t*)d_ws;
  const size_t MB = 1024 * 1024;
  u16* wqkv_t = (u16*)(ws + 0);        // [3072,1024]
  u16* wproj_t = (u16*)(ws + 6 * MB);  // [1024,1024]
  u16* w1t  = (u16*)(ws + 8 * MB);     // [4096,1024]
  u16* w2t  = (u16*)(ws + 16 * MB);    // [1024,4096]
  u16* hbuf = (u16*)(ws + 24 * MB);    // [4096,1024]
  u16* qkv  = (u16*)(ws + 32 * MB);    // [4096,3072]
  u16* qb   = (u16*)(ws + 56 * MB);    // [32,2048,64]
  u16* kb   = (u16*)(ws + 64 * MB);
  u16* vtb  = (u16*)(ws + 72 * MB);    // [32,64,2048]
  u16* aout = (u16*)(ws + 80 * MB);    // [4096,1024]
  u16* h2   = (u16*)(ws + 88 * MB);    // [4096,1024]
  u16* ff1  = (u16*)(ws + 96 * MB);    // [4096,4096]
  float* xout = (float*)d_out;

  const dim3 tb(32, 8);
  transpose_w<<<dim3(HD_/32, D_/32, H_), tb, 0, stream>>>(wq, wqkv_t, D_, HD_);
  transpose_w<<<dim3(HD_/32, D_/32, H_), tb, 0, stream>>>(wk, wqkv_t + (size_t)D_*D_, D_, HD_);
  transpose_w<<<dim3(HD_/32, D_/32, H_), tb, 0, stream>>>(wv, wqkv_t + 2*(size_t)D_*D_, D_, HD_);
  transpose_w<<<dim3(D_/32, D_/32, 1),  tb, 0, stream>>>(w_proj, wproj_t, D_, D_);
  transpose_w<<<dim3(FF_/32, D_/32, 1), tb, 0, stream>>>(w1, w1t, D_, FF_);
  transpose_w<<<dim3(D_/32, FF_/32, 1), tb, 0, stream>>>(w2, w2t, FF_, D_);

  ln_rows<<<BT_, 256, 0, stream>>>(x, ln1_g, ln1_b, hbuf);

  gemm_bt<0,0,0,1><<<dim3(3072/128, BT_/128), 256, 0, stream>>>(
      hbuf, wqkv_t, nullptr, nullptr, qkv, BT_, 3072, D_);

  repack_qkv<<<dim3(T_/64, B_*H_), 256, 0, stream>>>(qkv, qb, kb, vtb);

  attn_fwd<<<dim3(T_/64, B_*H_), 256, 0, stream>>>(qb, kb, vtb, aout);

  gemm_bt<0,1,1,0><<<dim3(D_/128, BT_/128), 256, 0, stream>>>(
      aout, wproj_t, b_proj, x, xout, BT_, D_, D_);

  ln_rows<<<BT_, 256, 0, stream>>>(xout, ln2_g, ln2_b, h2);

  gemm_bt<1,1,0,1><<<dim3(FF_/128, BT_/128), 256, 0, stream>>>(
      h2, w1t, b1, nullptr, ff1, BT_, FF_, D_);

  gemm_bt<0,1,1,0><<<dim3(D_/128, BT_/128), 256, 0, stream>>>(
      ff1, w2t, b2, xout, xout, BT_, D_, FF_);
}

// Round 3
// 366.311 us; speedup vs baseline: 1.1082x; 1.1082x over previous
//
#include <hip/hip_runtime.h>
#include <hip/hip_bf16.h>
#include <cstdint>
#include <cstddef>
#include <math.h>

#define D_ 1024
#define H_ 16
#define HD_ 64
#define T_ 2048
#define B_ 2
#define FF_ 4096
#define BT_ (B_*T_)   // 4096 rows
#define NT_ 32        // T_/64 kv tiles

typedef unsigned short u16;
typedef __attribute__((ext_vector_type(8))) __bf16 bf16x8;
typedef __attribute__((ext_vector_type(4))) float f32x4;

__device__ __forceinline__ u16 f2bf(float f) {
  unsigned u = __builtin_bit_cast(unsigned, f);
  u += 0x7FFFu + ((u >> 16) & 1u);
  return (u16)(u >> 16);
}

__device__ __forceinline__ void gload16(const void* g, void* l) {
  __builtin_amdgcn_global_load_lds((__attribute__((address_space(1))) void*)g,
                                   (__attribute__((address_space(3))) void*)l, 16, 0, 0);
}

// ---------------- transpose + fp32->bf16 cast:  out[(z*C+c)*R + r] = in[z*R*C + r*C + c]
__global__ __launch_bounds__(256) void transpose_w(const float* __restrict__ in,
                                                   u16* __restrict__ out, int R, int C) {
  __shared__ float tile[32][33];
  const int z = blockIdx.z;
  const float* inz = in + (size_t)z * R * C;
  const int x = blockIdx.x * 32 + threadIdx.x;
  const int y0 = blockIdx.y * 32 + threadIdx.y;
  #pragma unroll
  for (int j = 0; j < 32; j += 8)
    tile[threadIdx.y + j][threadIdx.x] = inz[(size_t)(y0 + j) * C + x];
  __syncthreads();
  const int orr = blockIdx.y * 32 + threadIdx.x;
  const int oc0 = blockIdx.x * 32 + threadIdx.y;
  u16* outz = out + (size_t)z * C * R;
  #pragma unroll
  for (int j = 0; j < 32; j += 8)
    outz[(size_t)(oc0 + j) * R + orr] = f2bf(tile[threadIdx.x][threadIdx.y + j]);
}

// ---------------- LayerNorm (fp32 in -> bf16 out), one row (D=1024) per block of 256
__global__ __launch_bounds__(256) void ln_rows(const float* __restrict__ x,
    const float* __restrict__ g, const float* __restrict__ bb, u16* __restrict__ out) {
  const int row = blockIdx.x, tid = threadIdx.x;
  const float4 v = ((const float4*)(x + (size_t)row * D_))[tid];
  float s = v.x + v.y + v.z + v.w;
  float sq = v.x*v.x + v.y*v.y + v.z*v.z + v.w*v.w;
  #pragma unroll
  for (int m = 1; m < 64; m <<= 1) { s += __shfl_xor(s, m); sq += __shfl_xor(sq, m); }
  __shared__ float ss[4], qs[4];
  if ((tid & 63) == 0) { ss[tid >> 6] = s; qs[tid >> 6] = sq; }
  __syncthreads();
  s  = ss[0] + ss[1] + ss[2] + ss[3];
  sq = qs[0] + qs[1] + qs[2] + qs[3];
  const float mean = s * (1.f / D_);
  const float var  = sq * (1.f / D_) - mean * mean;
  const float rstd = rsqrtf(var + 1e-5f);
  const float4 gv = ((const float4*)g)[tid];
  const float4 bv = ((const float4*)bb)[tid];
  u16 o[4];
  o[0] = f2bf((v.x - mean) * rstd * gv.x + bv.x);
  o[1] = f2bf((v.y - mean) * rstd * gv.y + bv.y);
  o[2] = f2bf((v.z - mean) * rstd * gv.z + bv.z);
  o[3] = f2bf((v.w - mean) * rstd * gv.w + bv.w);
  *(ushort4*)(out + (size_t)row * D_ + tid * 4) = *(ushort4*)o;
}

// ---------------- GEMM: C[M,N] = act(A[M,K] * Bt[N,K]^T + bias) (+resid)
// m97 structure + T1 XCD-aware block swizzle (all launches have nwg%8==0).
template<int ACT, int BIAS, int RESID, int OUTBF>
__global__ __launch_bounds__(256) void gemm_bt(
    const u16* __restrict__ A, const u16* __restrict__ Bt,
    const float* __restrict__ bias, const float* resid,
    void* Cout, int M, int N, int K) {
  __shared__ __attribute__((aligned(16))) u16 As[128 * 32];
  __shared__ __attribute__((aligned(16))) u16 Bs[128 * 32];
  const int tid = threadIdx.x;
  const int wid = tid >> 6, lane = tid & 63;
  // XCD swizzle: contiguous logical chunk per XCD
  const int gx = gridDim.x;
  const int nwg = gx * gridDim.y;
  const int orig = blockIdx.y * gx + blockIdx.x;
  const int cpx = nwg >> 3;
  const int swz = (orig & 7) * cpx + (orig >> 3);
  const int bm = (swz / gx) * 128, bn = (swz % gx) * 128;
  const int wm = (wid >> 1) * 64, wn = (wid & 1) * 64;

  f32x4 acc[4][4] = {};

  const u16* Ag = A + (size_t)(bm + wid * 32 + (lane >> 2)) * K + (lane & 3) * 8;
  const u16* Bg = Bt + (size_t)(bn + wid * 32 + (lane >> 2)) * K + (lane & 3) * 8;
  u16* AsW = As + (wid * 32) * 32;
  u16* BsW = Bs + (wid * 32) * 32;
  const int ro = (lane & 15) * 32 + (lane >> 4) * 8;

  for (int k0 = 0; k0 < K; k0 += 32) {
    gload16(Ag + k0,                 AsW);
    gload16(Ag + k0 + (size_t)16 * K, AsW + 16 * 32);
    gload16(Bg + k0,                 BsW);
    gload16(Bg + k0 + (size_t)16 * K, BsW + 16 * 32);
    __syncthreads();
    bf16x8 af[4], bfr[4];
    #pragma unroll
    for (int i = 0; i < 4; i++) af[i]  = *(const bf16x8*)(As + (wm + i * 16) * 32 + ro);
    #pragma unroll
    for (int i = 0; i < 4; i++) bfr[i] = *(const bf16x8*)(Bs + (wn + i * 16) * 32 + ro);
    #pragma unroll
    for (int mi = 0; mi < 4; mi++)
      #pragma unroll
      for (int ni = 0; ni < 4; ni++)
        acc[mi][ni] = __builtin_amdgcn_mfma_f32_16x16x32_bf16(af[mi], bfr[ni], acc[mi][ni], 0, 0, 0);
    __syncthreads();
  }

  const int r0 = bm + wm + ((lane >> 4) << 2);
  const int c0 = bn + wn + (lane & 15);
  #pragma unroll
  for (int mi = 0; mi < 4; mi++) {
    #pragma unroll
    for (int ni = 0; ni < 4; ni++) {
      #pragma unroll
      for (int r = 0; r < 4; r++) {
        float v = acc[mi][ni][r];
        const int rr = r0 + mi * 16 + r;
        const int cc = c0 + ni * 16;
        if (BIAS) v += bias[cc];
        if (ACT == 1) v = 0.5f * v * (1.0f + erff(v * 0.70710678118f));
        if (RESID) v += resid[(size_t)rr * N + cc];
        if (OUTBF) ((u16*)Cout)[(size_t)rr * N + cc] = f2bf(v);
        else       ((float*)Cout)[(size_t)rr * N + cc] = v;
      }
    }
  }
}

// ---------------- repack qkv [bt, 3*D] -> q,k [bh, T, 64] and v^T [bh, 64, T]
__global__ __launch_bounds__(256) void repack_qkv(const u16* __restrict__ qkv,
    u16* __restrict__ q, u16* __restrict__ k, u16* __restrict__ vt) {
  const int t0 = blockIdx.x * 64, bh = blockIdx.y;
  const int b = bh >> 4, h = bh & 15;
  const int tid = threadIdx.x;
  const int c = (tid & 7) * 8;
  __shared__ __attribute__((aligned(16))) u16 vs[64][72];
  #pragma unroll
  for (int p = 0; p < 2; p++) {
    const int tl = p * 32 + (tid >> 3);
    const size_t inrow = ((size_t)b * T_ + t0 + tl) * 3072 + h * 64;
    bf16x8 qv = *(const bf16x8*)(qkv + inrow + c);
    bf16x8 kv = *(const bf16x8*)(qkv + inrow + 1024 + c);
    bf16x8 vv = *(const bf16x8*)(qkv + inrow + 2048 + c);
    *(bf16x8*)(q + ((size_t)bh * T_ + t0 + tl) * HD_ + c) = qv;
    *(bf16x8*)(k + ((size_t)bh * T_ + t0 + tl) * HD_ + c) = kv;
    *(bf16x8*)&vs[tl][c] = vv;
  }
  __syncthreads();
  const int d = tid >> 2, tc = (tid & 3) * 16;
  alignas(16) u16 tmp[16];
  #pragma unroll
  for (int j = 0; j < 16; j++) tmp[j] = vs[tc + j][d];
  *(bf16x8*)(vt + ((size_t)bh * HD_ + d) * T_ + t0 + tc)     = *(bf16x8*)&tmp[0];
  *(bf16x8*)(vt + ((size_t)bh * HD_ + d) * T_ + t0 + tc + 8) = *(bf16x8*)&tmp[8];
}

// ---------------- flash attention v2:
// 64 q-rows/tile, each block processes paired tiles (x, 31-x) for load balance.
// K/V double-buffered in LDS via global_load_lds (linear dest, XOR-swizzled source),
// one barrier per KV tile, log2-space online softmax, setprio around MFMA.
__global__ __launch_bounds__(256) void attn_fwd(
    const u16* __restrict__ q, const u16* __restrict__ k,
    const u16* __restrict__ vt, u16* __restrict__ out) {
  __shared__ __attribute__((aligned(16))) u16 Qs[64][72];
  __shared__ __attribute__((aligned(16))) u16 Ps[64][72];
  __shared__ __attribute__((aligned(16))) u16 Kb[2][64 * 64];
  __shared__ __attribute__((aligned(16))) u16 Vb[2][64 * 64];

  const int bh = blockIdx.y;
  const int b = bh >> 4, h = bh & 15;
  const int tid = threadIdx.x, wid = tid >> 6, lane = tid & 63;
  const u16* kh = k  + (size_t)bh * T_ * HD_;
  const u16* vh = vt + (size_t)bh * HD_ * T_;

  const int frow = lane & 15;          // fragment row / output col
  const int hi   = lane >> 4;          // 0..3 k-chunk group
  const int fk   = hi * 8;
  const int rowb = hi * 4;             // C-frag row base
  const int colb = frow;
  const int cst  = (tid & 7) * 8;

  // staging lane geometry (global source pre-swizzled, LDS dest linear)
  const int srl = lane >> 3;           // 0..7 row within 8-row stripe
  const int scs = (lane & 7) ^ srl;    // swizzled 16B chunk

  const float SCL2 = 0.18033688011112042f;  // 0.125 * log2(e)

  const int qts[2] = { (int)blockIdx.x, NT_ - 1 - (int)blockIdx.x };

  for (int qi = 0; qi < 2; ++qi) {
    const int qt = qts[qi];
    const int q0 = qt * 64;

    __syncthreads();   // Qs/Ps WAR safety across paired tiles
    #pragma unroll
    for (int p = 0; p < 2; p++) {
      const int t = p * 32 + (tid >> 3);
      *(bf16x8*)&Qs[t][cst] = *(const bf16x8*)(q + ((size_t)bh * T_ + q0 + t) * HD_ + cst);
    }
    __syncthreads();
    bf16x8 aq[2];
    aq[0] = *(const bf16x8*)&Qs[wid * 16 + frow][fk];
    aq[1] = *(const bf16x8*)&Qs[wid * 16 + frow][32 + fk];

    float m2[4]  = {-3e38f, -3e38f, -3e38f, -3e38f};
    float l_r[4] = {0.f, 0.f, 0.f, 0.f};
    f32x4 acc_o[4] = {};

    // prologue: stage kt=0 into buffer 0
    int cur = 0;
    {
      #pragma unroll
      for (int j = 0; j < 2; ++j) {
        const int row = wid * 16 + j * 8 + srl;
        gload16(kh + (size_t)(0 * 64 + row) * HD_ + scs * 8, &Kb[0][(wid * 16 + j * 8) * 64]);
        gload16(vh + (size_t)row * T_ + 0 * 64 + scs * 8,    &Vb[0][(wid * 16 + j * 8) * 64]);
      }
    }
    __syncthreads();

    for (int kt = 0; kt <= qt; ++kt) {
      // prefetch next KV tile into the other buffer (in flight across this tile's compute)
      if (kt < qt) {
        const int nx = cur ^ 1, ktn = kt + 1;
        #pragma unroll
        for (int j = 0; j < 2; ++j) {
          const int row = wid * 16 + j * 8 + srl;
          gload16(kh + (size_t)(ktn * 64 + row) * HD_ + scs * 8, &Kb[nx][(wid * 16 + j * 8) * 64]);
          gload16(vh + (size_t)row * T_ + ktn * 64 + scs * 8,    &Vb[nx][(wid * 16 + j * 8) * 64]);
        }
      }

      const u16* Kc = &Kb[cur][0];
      const u16* Vc = &Vb[cur][0];

      // ---- QK^T (swizzled ds_read_b128)
      float p2[4][4];
      __builtin_amdgcn_s_setprio(1);
      #pragma unroll
      for (int ni = 0; ni < 4; ni++) {
        f32x4 s = {};
        #pragma unroll
        for (int ks = 0; ks < 2; ks++) {
          const int row = ni * 16 + frow;
          const int ch  = ks * 4 + hi;
          bf16x8 bk = *(const bf16x8*)(Kc + row * 64 + ((ch ^ (row & 7)) << 3));
          s = __builtin_amdgcn_mfma_f32_16x16x32_bf16(aq[ks], bk, s, 0, 0, 0);
        }
        #pragma unroll
        for (int r = 0; r < 4; r++) {
          const bool msk = (kt == qt) && (ni * 16 + colb) > (wid * 16 + rowb + r);
          p2[ni][r] = msk ? -3e38f : s[r] * SCL2;
        }
      }
      __builtin_amdgcn_s_setprio(0);

      // ---- online softmax in log2 space
      #pragma unroll
      for (int r = 0; r < 4; r++) {
        float rm = fmaxf(fmaxf(p2[0][r], p2[1][r]), fmaxf(p2[2][r], p2[3][r]));
        rm = fmaxf(rm, __shfl_xor(rm, 1));
        rm = fmaxf(rm, __shfl_xor(rm, 2));
        rm = fmaxf(rm, __shfl_xor(rm, 4));
        rm = fmaxf(rm, __shfl_xor(rm, 8));
        const float mnew = fmaxf(m2[r], rm);
        const float corr = exp2f(m2[r] - mnew);
        m2[r] = mnew;
        float rs = 0.f;
        #pragma unroll
        for (int ni = 0; ni < 4; ni++) { float e = exp2f(p2[ni][r] - mnew); p2[ni][r] = e; rs += e; }
        rs += __shfl_xor(rs, 1); rs += __shfl_xor(rs, 2);
        rs += __shfl_xor(rs, 4); rs += __shfl_xor(rs, 8);
        l_r[r] = l_r[r] * corr + rs;
        #pragma unroll
        for (int ni = 0; ni < 4; ni++) acc_o[ni][r] *= corr;
      }

      // ---- P -> LDS (per-wave private rows), reload as A-frag
      #pragma unroll
      for (int ni = 0; ni < 4; ni++)
        #pragma unroll
        for (int r = 0; r < 4; r++)
          Ps[wid * 16 + rowb + r][ni * 16 + colb] = f2bf(p2[ni][r]);
      bf16x8 ap[2];
      ap[0] = *(const bf16x8*)&Ps[wid * 16 + frow][fk];
      ap[1] = *(const bf16x8*)&Ps[wid * 16 + frow][32 + fk];

      // ---- PV
      __builtin_amdgcn_s_setprio(1);
      #pragma unroll
      for (int ni = 0; ni < 4; ni++) {
        #pragma unroll
        for (int ks = 0; ks < 2; ks++) {
          const int row = ni * 16 + frow;
          const int ch  = ks * 4 + hi;
          bf16x8 bv = *(const bf16x8*)(Vc + row * 64 + ((ch ^ (row & 7)) << 3));
          acc_o[ni] = __builtin_amdgcn_mfma_f32_16x16x32_bf16(ap[ks], bv, acc_o[ni], 0, 0, 0);
        }
      }
      __builtin_amdgcn_s_setprio(0);

      __syncthreads();   // drains vmcnt: prefetched tile ready; all waves done with cur
      cur ^= 1;
    }

    // ---- epilogue: normalize and write
    #pragma unroll
    for (int r = 0; r < 4; r++) l_r[r] = 1.0f / l_r[r];
    #pragma unroll
    for (int ni = 0; ni < 4; ni++)
      #pragma unroll
      for (int r = 0; r < 4; r++) {
        const float ov = acc_o[ni][r] * l_r[r];
        const size_t row = (size_t)b * T_ + q0 + wid * 16 + rowb + r;
        out[row * D_ + h * HD_ + ni * 16 + colb] = f2bf(ov);
      }
  }
}

extern "C" void kernel_launch(void* const* d_in, const int* in_sizes, int n_in,
                              void* d_out, int out_size, void* d_ws, size_t ws_size,
                              hipStream_t stream) {
  (void)in_sizes; (void)n_in; (void)out_size; (void)ws_size;
  const float* x      = (const float*)d_in[0];
  const float* wq     = (const float*)d_in[1];
  const float* wk     = (const float*)d_in[2];
  const float* wv     = (const float*)d_in[3];
  const float* w_proj = (const float*)d_in[4];
  const float* b_proj = (const float*)d_in[5];
  const float* ln1_g  = (const float*)d_in[6];
  const float* ln1_b  = (const float*)d_in[7];
  const float* ln2_g  = (const float*)d_in[8];
  const float* ln2_b  = (const float*)d_in[9];
  const float* w1     = (const float*)d_in[10];
  const float* b1     = (const float*)d_in[11];
  const float* w2     = (const float*)d_in[12];
  const float* b2     = (const float*)d_in[13];

  uint8_t* ws = (uint8_t*)d_ws;
  const size_t MB = 1024 * 1024;
  u16* wqkv_t = (u16*)(ws + 0);        // [3072,1024]
  u16* wproj_t = (u16*)(ws + 6 * MB);  // [1024,1024]
  u16* w1t  = (u16*)(ws + 8 * MB);     // [4096,1024]
  u16* w2t  = (u16*)(ws + 16 * MB);    // [1024,4096]
  u16* hbuf = (u16*)(ws + 24 * MB);    // [4096,1024]
  u16* qkv  = (u16*)(ws + 32 * MB);    // [4096,3072]
  u16* qb   = (u16*)(ws + 56 * MB);    // [32,2048,64]
  u16* kb   = (u16*)(ws + 64 * MB);
  u16* vtb  = (u16*)(ws + 72 * MB);    // [32,64,2048]
  u16* aout = (u16*)(ws + 80 * MB);    // [4096,1024]
  u16* h2   = (u16*)(ws + 88 * MB);    // [4096,1024]
  u16* ff1  = (u16*)(ws + 96 * MB);    // [4096,4096]
  float* xout = (float*)d_out;

  const dim3 tb(32, 8);
  transpose_w<<<dim3(HD_/32, D_/32, H_), tb, 0, stream>>>(wq, wqkv_t, D_, HD_);
  transpose_w<<<dim3(HD_/32, D_/32, H_), tb, 0, stream>>>(wk, wqkv_t + (size_t)D_*D_, D_, HD_);
  transpose_w<<<dim3(HD_/32, D_/32, H_), tb, 0, stream>>>(wv, wqkv_t + 2*(size_t)D_*D_, D_, HD_);
  transpose_w<<<dim3(D_/32, D_/32, 1),  tb, 0, stream>>>(w_proj, wproj_t, D_, D_);
  transpose_w<<<dim3(FF_/32, D_/32, 1), tb, 0, stream>>>(w1, w1t, D_, FF_);
  transpose_w<<<dim3(D_/32, FF_/32, 1), tb, 0, stream>>>(w2, w2t, FF_, D_);

  ln_rows<<<BT_, 256, 0, stream>>>(x, ln1_g, ln1_b, hbuf);

  gemm_bt<0,0,0,1><<<dim3(3072/128, BT_/128), 256, 0, stream>>>(
      hbuf, wqkv_t, nullptr, nullptr, qkv, BT_, 3072, D_);

  repack_qkv<<<dim3(T_/64, B_*H_), 256, 0, stream>>>(qkv, qb, kb, vtb);

  attn_fwd<<<dim3(NT_/2, B_*H_), 256, 0, stream>>>(qb, kb, vtb, aout);

  gemm_bt<0,1,1,0><<<dim3(D_/128, BT_/128), 256, 0, stream>>>(
      aout, wproj_t, b_proj, x, xout, BT_, D_, D_);

  ln_rows<<<BT_, 256, 0, stream>>>(xout, ln2_g, ln2_b, h2);

  gemm_bt<1,1,0,1><<<dim3(FF_/128, BT_/128), 256, 0, stream>>>(
      h2, w1t, b1, nullptr, ff1, BT_, FF_, D_);

  gemm_bt<0,1,1,0><<<dim3(D_/128, BT_/128), 256, 0, stream>>>(
      ff1, w2t, b2, xout, xout, BT_, D_, FF_);
}

// Round 4
// 333.382 us; speedup vs baseline: 1.2177x; 1.0988x over previous
//
#include <hip/hip_runtime.h>
#include <hip/hip_bf16.h>
#include <cstdint>
#include <cstddef>
#include <math.h>

#define D_ 1024
#define H_ 16
#define HD_ 64
#define T_ 2048
#define B_ 2
#define FF_ 4096
#define BT_ (B_*T_)   // 4096 rows
#define NT_ 32        // T_/64 kv tiles

typedef unsigned short u16;
typedef __attribute__((ext_vector_type(8))) __bf16 bf16x8;
typedef __attribute__((ext_vector_type(4))) float f32x4;

__device__ __forceinline__ u16 f2bf(float f) {
  unsigned u = __builtin_bit_cast(unsigned, f);
  u += 0x7FFFu + ((u >> 16) & 1u);
  return (u16)(u >> 16);
}

__device__ __forceinline__ void gload16(const void* g, void* l) {
  __builtin_amdgcn_global_load_lds((__attribute__((address_space(1))) void*)g,
                                   (__attribute__((address_space(3))) void*)l, 16, 0, 0);
}

// ---------------- transpose + fp32->bf16 cast:  out[(z*C+c)*R + r] = in[z*R*C + r*C + c]
__global__ __launch_bounds__(256) void transpose_w(const float* __restrict__ in,
                                                   u16* __restrict__ out, int R, int C) {
  __shared__ float tile[32][33];
  const int z = blockIdx.z;
  const float* inz = in + (size_t)z * R * C;
  const int x = blockIdx.x * 32 + threadIdx.x;
  const int y0 = blockIdx.y * 32 + threadIdx.y;
  #pragma unroll
  for (int j = 0; j < 32; j += 8)
    tile[threadIdx.y + j][threadIdx.x] = inz[(size_t)(y0 + j) * C + x];
  __syncthreads();
  const int orr = blockIdx.y * 32 + threadIdx.x;
  const int oc0 = blockIdx.x * 32 + threadIdx.y;
  u16* outz = out + (size_t)z * C * R;
  #pragma unroll
  for (int j = 0; j < 32; j += 8)
    outz[(size_t)(oc0 + j) * R + orr] = f2bf(tile[threadIdx.x][threadIdx.y + j]);
}

// ---------------- LayerNorm (fp32 in -> bf16 out), one row (D=1024) per block of 256
__global__ __launch_bounds__(256) void ln_rows(const float* __restrict__ x,
    const float* __restrict__ g, const float* __restrict__ bb, u16* __restrict__ out) {
  const int row = blockIdx.x, tid = threadIdx.x;
  const float4 v = ((const float4*)(x + (size_t)row * D_))[tid];
  float s = v.x + v.y + v.z + v.w;
  float sq = v.x*v.x + v.y*v.y + v.z*v.z + v.w*v.w;
  #pragma unroll
  for (int m = 1; m < 64; m <<= 1) { s += __shfl_xor(s, m); sq += __shfl_xor(sq, m); }
  __shared__ float ss[4], qs[4];
  if ((tid & 63) == 0) { ss[tid >> 6] = s; qs[tid >> 6] = sq; }
  __syncthreads();
  s  = ss[0] + ss[1] + ss[2] + ss[3];
  sq = qs[0] + qs[1] + qs[2] + qs[3];
  const float mean = s * (1.f / D_);
  const float var  = sq * (1.f / D_) - mean * mean;
  const float rstd = rsqrtf(var + 1e-5f);
  const float4 gv = ((const float4*)g)[tid];
  const float4 bv = ((const float4*)bb)[tid];
  u16 o[4];
  o[0] = f2bf((v.x - mean) * rstd * gv.x + bv.x);
  o[1] = f2bf((v.y - mean) * rstd * gv.y + bv.y);
  o[2] = f2bf((v.z - mean) * rstd * gv.z + bv.z);
  o[3] = f2bf((v.w - mean) * rstd * gv.w + bv.w);
  *(ushort4*)(out + (size_t)row * D_ + tid * 4) = *(ushort4*)o;
}

// ---------------- GEMM: C[M,N] = act(A[M,K] * Bt[N,K]^T + bias) (+resid)
// m97 structure + T1 XCD swizzle. PARTIAL: split-K over blockIdx.z, fp32 partials,
// no epilogue (reduce_parts fuses bias/resid).
template<int ACT, int BIAS, int RESID, int OUTBF, int PARTIAL>
__global__ __launch_bounds__(256) void gemm_bt(
    const u16* __restrict__ A, const u16* __restrict__ Bt,
    const float* __restrict__ bias, const float* resid,
    void* Cout, int M, int N, int K, int Kper) {
  __shared__ __attribute__((aligned(16))) u16 As[128 * 32];
  __shared__ __attribute__((aligned(16))) u16 Bs[128 * 32];
  const int tid = threadIdx.x;
  const int wid = tid >> 6, lane = tid & 63;
  const int gx = gridDim.x;
  const int nwg = gx * gridDim.y;
  const int orig = blockIdx.y * gx + blockIdx.x;
  const int cpx = nwg >> 3;
  const int swz = (orig & 7) * cpx + (orig >> 3);
  const int bm = (swz / gx) * 128, bn = (swz % gx) * 128;
  const int wm = (wid >> 1) * 64, wn = (wid & 1) * 64;
  const int z = PARTIAL ? blockIdx.z : 0;
  const int koff = z * Kper;

  f32x4 acc[4][4] = {};

  const u16* Ag = A + (size_t)(bm + wid * 32 + (lane >> 2)) * K + koff + (lane & 3) * 8;
  const u16* Bg = Bt + (size_t)(bn + wid * 32 + (lane >> 2)) * K + koff + (lane & 3) * 8;
  u16* AsW = As + (wid * 32) * 32;
  u16* BsW = Bs + (wid * 32) * 32;
  const int ro = (lane & 15) * 32 + (lane >> 4) * 8;

  for (int k0 = 0; k0 < Kper; k0 += 32) {
    gload16(Ag + k0,                 AsW);
    gload16(Ag + k0 + (size_t)16 * K, AsW + 16 * 32);
    gload16(Bg + k0,                 BsW);
    gload16(Bg + k0 + (size_t)16 * K, BsW + 16 * 32);
    __syncthreads();
    bf16x8 af[4], bfr[4];
    #pragma unroll
    for (int i = 0; i < 4; i++) af[i]  = *(const bf16x8*)(As + (wm + i * 16) * 32 + ro);
    #pragma unroll
    for (int i = 0; i < 4; i++) bfr[i] = *(const bf16x8*)(Bs + (wn + i * 16) * 32 + ro);
    #pragma unroll
    for (int mi = 0; mi < 4; mi++)
      #pragma unroll
      for (int ni = 0; ni < 4; ni++)
        acc[mi][ni] = __builtin_amdgcn_mfma_f32_16x16x32_bf16(af[mi], bfr[ni], acc[mi][ni], 0, 0, 0);
    __syncthreads();
  }

  const int r0 = bm + wm + ((lane >> 4) << 2);
  const int c0 = bn + wn + (lane & 15);
  #pragma unroll
  for (int mi = 0; mi < 4; mi++) {
    #pragma unroll
    for (int ni = 0; ni < 4; ni++) {
      #pragma unroll
      for (int r = 0; r < 4; r++) {
        float v = acc[mi][ni][r];
        const int rr = r0 + mi * 16 + r;
        const int cc = c0 + ni * 16;
        if (PARTIAL) {
          ((float*)Cout)[((size_t)z * M + rr) * N + cc] = v;
        } else {
          if (BIAS) v += bias[cc];
          if (ACT == 1) v = 0.5f * v * (1.0f + erff(v * 0.70710678118f));
          if (RESID) v += resid[(size_t)rr * N + cc];
          if (OUTBF) ((u16*)Cout)[(size_t)rr * N + cc] = f2bf(v);
          else       ((float*)Cout)[(size_t)rr * N + cc] = v;
        }
      }
    }
  }
}

// ---------------- split-K reduce: out = sum(parts) + bias (+resid), fp32
template<int NPART>
__global__ __launch_bounds__(256) void reduce_parts(
    const float* __restrict__ parts, const float* __restrict__ bias,
    const float* __restrict__ resid, float* __restrict__ out, int MN, int N) {
  const int i4 = (blockIdx.x * 256 + threadIdx.x) * 4;
  if (i4 >= MN) return;
  float4 s = *(const float4*)(parts + i4);
  #pragma unroll
  for (int p = 1; p < NPART; p++) {
    const float4 t = *(const float4*)(parts + (size_t)p * MN + i4);
    s.x += t.x; s.y += t.y; s.z += t.z; s.w += t.w;
  }
  const float4 bv = *(const float4*)(bias + (i4 & (N - 1)));
  const float4 rv = *(const float4*)(resid + i4);
  s.x += bv.x + rv.x; s.y += bv.y + rv.y; s.z += bv.z + rv.z; s.w += bv.w + rv.w;
  *(float4*)(out + i4) = s;
}

// ---------------- repack qkv [bt, 3*D] -> q,k [bh, T, 64] and v^T [bh, 64, T]
__global__ __launch_bounds__(256) void repack_qkv(const u16* __restrict__ qkv,
    u16* __restrict__ q, u16* __restrict__ k, u16* __restrict__ vt) {
  const int t0 = blockIdx.x * 64, bh = blockIdx.y;
  const int b = bh >> 4, h = bh & 15;
  const int tid = threadIdx.x;
  const int c = (tid & 7) * 8;
  __shared__ __attribute__((aligned(16))) u16 vs[64][72];
  #pragma unroll
  for (int p = 0; p < 2; p++) {
    const int tl = p * 32 + (tid >> 3);
    const size_t inrow = ((size_t)b * T_ + t0 + tl) * 3072 + h * 64;
    bf16x8 qv = *(const bf16x8*)(qkv + inrow + c);
    bf16x8 kv = *(const bf16x8*)(qkv + inrow + 1024 + c);
    bf16x8 vv = *(const bf16x8*)(qkv + inrow + 2048 + c);
    *(bf16x8*)(q + ((size_t)bh * T_ + t0 + tl) * HD_ + c) = qv;
    *(bf16x8*)(k + ((size_t)bh * T_ + t0 + tl) * HD_ + c) = kv;
    *(bf16x8*)&vs[tl][c] = vv;
  }
  __syncthreads();
  const int d = tid >> 2, tc = (tid & 3) * 16;
  alignas(16) u16 tmp[16];
  #pragma unroll
  for (int j = 0; j < 16; j++) tmp[j] = vs[tc + j][d];
  *(bf16x8*)(vt + ((size_t)bh * HD_ + d) * T_ + t0 + tc)     = *(bf16x8*)&tmp[0];
  *(bf16x8*)(vt + ((size_t)bh * HD_ + d) * T_ + t0 + tc + 8) = *(bf16x8*)&tmp[8];
}

// ---------------- flash attention v2 (paired q-tiles, dbuf K/V, log2 softmax)
__global__ __launch_bounds__(256) void attn_fwd(
    const u16* __restrict__ q, const u16* __restrict__ k,
    const u16* __restrict__ vt, u16* __restrict__ out) {
  __shared__ __attribute__((aligned(16))) u16 Qs[64][72];
  __shared__ __attribute__((aligned(16))) u16 Ps[64][72];
  __shared__ __attribute__((aligned(16))) u16 Kb[2][64 * 64];
  __shared__ __attribute__((aligned(16))) u16 Vb[2][64 * 64];

  const int bh = blockIdx.y;
  const int b = bh >> 4, h = bh & 15;
  const int tid = threadIdx.x, wid = tid >> 6, lane = tid & 63;
  const u16* kh = k  + (size_t)bh * T_ * HD_;
  const u16* vh = vt + (size_t)bh * HD_ * T_;

  const int frow = lane & 15;
  const int hi   = lane >> 4;
  const int fk   = hi * 8;
  const int rowb = hi * 4;
  const int colb = frow;
  const int cst  = (tid & 7) * 8;

  const int srl = lane >> 3;
  const int scs = (lane & 7) ^ srl;

  const float SCL2 = 0.18033688011112042f;  // 0.125 * log2(e)

  const int qts[2] = { (int)blockIdx.x, NT_ - 1 - (int)blockIdx.x };

  for (int qi = 0; qi < 2; ++qi) {
    const int qt = qts[qi];
    const int q0 = qt * 64;

    __syncthreads();
    #pragma unroll
    for (int p = 0; p < 2; p++) {
      const int t = p * 32 + (tid >> 3);
      *(bf16x8*)&Qs[t][cst] = *(const bf16x8*)(q + ((size_t)bh * T_ + q0 + t) * HD_ + cst);
    }
    __syncthreads();
    bf16x8 aq[2];
    aq[0] = *(const bf16x8*)&Qs[wid * 16 + frow][fk];
    aq[1] = *(const bf16x8*)&Qs[wid * 16 + frow][32 + fk];

    float m2[4]  = {-3e38f, -3e38f, -3e38f, -3e38f};
    float l_r[4] = {0.f, 0.f, 0.f, 0.f};
    f32x4 acc_o[4] = {};

    int cur = 0;
    {
      #pragma unroll
      for (int j = 0; j < 2; ++j) {
        const int row = wid * 16 + j * 8 + srl;
        gload16(kh + (size_t)(0 * 64 + row) * HD_ + scs * 8, &Kb[0][(wid * 16 + j * 8) * 64]);
        gload16(vh + (size_t)row * T_ + 0 * 64 + scs * 8,    &Vb[0][(wid * 16 + j * 8) * 64]);
      }
    }
    __syncthreads();

    for (int kt = 0; kt <= qt; ++kt) {
      if (kt < qt) {
        const int nx = cur ^ 1, ktn = kt + 1;
        #pragma unroll
        for (int j = 0; j < 2; ++j) {
          const int row = wid * 16 + j * 8 + srl;
          gload16(kh + (size_t)(ktn * 64 + row) * HD_ + scs * 8, &Kb[nx][(wid * 16 + j * 8) * 64]);
          gload16(vh + (size_t)row * T_ + ktn * 64 + scs * 8,    &Vb[nx][(wid * 16 + j * 8) * 64]);
        }
      }

      const u16* Kc = &Kb[cur][0];
      const u16* Vc = &Vb[cur][0];

      float p2[4][4];
      __builtin_amdgcn_s_setprio(1);
      #pragma unroll
      for (int ni = 0; ni < 4; ni++) {
        f32x4 s = {};
        #pragma unroll
        for (int ks = 0; ks < 2; ks++) {
          const int row = ni * 16 + frow;
          const int ch  = ks * 4 + hi;
          bf16x8 bk = *(const bf16x8*)(Kc + row * 64 + ((ch ^ (row & 7)) << 3));
          s = __builtin_amdgcn_mfma_f32_16x16x32_bf16(aq[ks], bk, s, 0, 0, 0);
        }
        #pragma unroll
        for (int r = 0; r < 4; r++) {
          const bool msk = (kt == qt) && (ni * 16 + colb) > (wid * 16 + rowb + r);
          p2[ni][r] = msk ? -3e38f : s[r] * SCL2;
        }
      }
      __builtin_amdgcn_s_setprio(0);

      #pragma unroll
      for (int r = 0; r < 4; r++) {
        float rm = fmaxf(fmaxf(p2[0][r], p2[1][r]), fmaxf(p2[2][r], p2[3][r]));
        rm = fmaxf(rm, __shfl_xor(rm, 1));
        rm = fmaxf(rm, __shfl_xor(rm, 2));
        rm = fmaxf(rm, __shfl_xor(rm, 4));
        rm = fmaxf(rm, __shfl_xor(rm, 8));
        const float mnew = fmaxf(m2[r], rm);
        const float corr = exp2f(m2[r] - mnew);
        m2[r] = mnew;
        float rs = 0.f;
        #pragma unroll
        for (int ni = 0; ni < 4; ni++) { float e = exp2f(p2[ni][r] - mnew); p2[ni][r] = e; rs += e; }
        rs += __shfl_xor(rs, 1); rs += __shfl_xor(rs, 2);
        rs += __shfl_xor(rs, 4); rs += __shfl_xor(rs, 8);
        l_r[r] = l_r[r] * corr + rs;
        #pragma unroll
        for (int ni = 0; ni < 4; ni++) acc_o[ni][r] *= corr;
      }

      #pragma unroll
      for (int ni = 0; ni < 4; ni++)
        #pragma unroll
        for (int r = 0; r < 4; r++)
          Ps[wid * 16 + rowb + r][ni * 16 + colb] = f2bf(p2[ni][r]);
      bf16x8 ap[2];
      ap[0] = *(const bf16x8*)&Ps[wid * 16 + frow][fk];
      ap[1] = *(const bf16x8*)&Ps[wid * 16 + frow][32 + fk];

      __builtin_amdgcn_s_setprio(1);
      #pragma unroll
      for (int ni = 0; ni < 4; ni++) {
        #pragma unroll
        for (int ks = 0; ks < 2; ks++) {
          const int row = ni * 16 + frow;
          const int ch  = ks * 4 + hi;
          bf16x8 bv = *(const bf16x8*)(Vc + row * 64 + ((ch ^ (row & 7)) << 3));
          acc_o[ni] = __builtin_amdgcn_mfma_f32_16x16x32_bf16(ap[ks], bv, acc_o[ni], 0, 0, 0);
        }
      }
      __builtin_amdgcn_s_setprio(0);

      __syncthreads();
      cur ^= 1;
    }

    #pragma unroll
    for (int r = 0; r < 4; r++) l_r[r] = 1.0f / l_r[r];
    #pragma unroll
    for (int ni = 0; ni < 4; ni++)
      #pragma unroll
      for (int r = 0; r < 4; r++) {
        const float ov = acc_o[ni][r] * l_r[r];
        const size_t row = (size_t)b * T_ + q0 + wid * 16 + rowb + r;
        out[row * D_ + h * HD_ + ni * 16 + colb] = f2bf(ov);
      }
  }
}

extern "C" void kernel_launch(void* const* d_in, const int* in_sizes, int n_in,
                              void* d_out, int out_size, void* d_ws, size_t ws_size,
                              hipStream_t stream) {
  (void)in_sizes; (void)n_in; (void)out_size; (void)ws_size;
  const float* x      = (const float*)d_in[0];
  const float* wq     = (const float*)d_in[1];
  const float* wk     = (const float*)d_in[2];
  const float* wv     = (const float*)d_in[3];
  const float* w_proj = (const float*)d_in[4];
  const float* b_proj = (const float*)d_in[5];
  const float* ln1_g  = (const float*)d_in[6];
  const float* ln1_b  = (const float*)d_in[7];
  const float* ln2_g  = (const float*)d_in[8];
  const float* ln2_b  = (const float*)d_in[9];
  const float* w1     = (const float*)d_in[10];
  const float* b1     = (const float*)d_in[11];
  const float* w2     = (const float*)d_in[12];
  const float* b2     = (const float*)d_in[13];

  uint8_t* ws = (uint8_t*)d_ws;
  const size_t MB = 1024 * 1024;
  u16* wqkv_t = (u16*)(ws + 0);        // [3072,1024]
  u16* wproj_t = (u16*)(ws + 6 * MB);  // [1024,1024]
  u16* w1t  = (u16*)(ws + 8 * MB);     // [4096,1024]
  u16* w2t  = (u16*)(ws + 16 * MB);    // [1024,4096]
  u16* hbuf = (u16*)(ws + 24 * MB);    // [4096,1024]
  u16* qkv  = (u16*)(ws + 32 * MB);    // [4096,3072]  (dead after repack)
  u16* qb   = (u16*)(ws + 56 * MB);    // [32,2048,64] (dead after attn)
  u16* kb   = (u16*)(ws + 64 * MB);    // (dead after attn)
  u16* vtb  = (u16*)(ws + 72 * MB);    // (dead after attn)
  u16* aout = (u16*)(ws + 80 * MB);    // [4096,1024]
  u16* h2   = (u16*)(ws + 88 * MB);    // [4096,1024]
  u16* ff1  = (u16*)(ws + 96 * MB);    // [4096,4096]
  // split-K partials: sequential reuse of the 32..96 MB region
  float* pparts = (float*)(ws + 32 * MB);  // proj: 2 x [4096,1024] fp32 = 32 MB
  float* fparts = (float*)(ws + 32 * MB);  // ff2:  4 x [4096,1024] fp32 = 64 MB
  float* xout = (float*)d_out;

  const dim3 tb(32, 8);
  transpose_w<<<dim3(HD_/32, D_/32, H_), tb, 0, stream>>>(wq, wqkv_t, D_, HD_);
  transpose_w<<<dim3(HD_/32, D_/32, H_), tb, 0, stream>>>(wk, wqkv_t + (size_t)D_*D_, D_, HD_);
  transpose_w<<<dim3(HD_/32, D_/32, H_), tb, 0, stream>>>(wv, wqkv_t + 2*(size_t)D_*D_, D_, HD_);
  transpose_w<<<dim3(D_/32, D_/32, 1),  tb, 0, stream>>>(w_proj, wproj_t, D_, D_);
  transpose_w<<<dim3(FF_/32, D_/32, 1), tb, 0, stream>>>(w1, w1t, D_, FF_);
  transpose_w<<<dim3(D_/32, FF_/32, 1), tb, 0, stream>>>(w2, w2t, FF_, D_);

  ln_rows<<<BT_, 256, 0, stream>>>(x, ln1_g, ln1_b, hbuf);

  gemm_bt<0,0,0,1,0><<<dim3(3072/128, BT_/128), 256, 0, stream>>>(
      hbuf, wqkv_t, nullptr, nullptr, qkv, BT_, 3072, D_, D_);

  repack_qkv<<<dim3(T_/64, B_*H_), 256, 0, stream>>>(qkv, qb, kb, vtb);

  attn_fwd<<<dim3(NT_/2, B_*H_), 256, 0, stream>>>(qb, kb, vtb, aout);

  // proj: split-K=2 partials + fused reduce (bias + x residual) -> xout (fp32)
  gemm_bt<0,0,0,0,1><<<dim3(D_/128, BT_/128, 2), 256, 0, stream>>>(
      aout, wproj_t, nullptr, nullptr, pparts, BT_, D_, D_, D_/2);
  reduce_parts<2><<<(BT_*D_)/1024, 256, 0, stream>>>(
      pparts, b_proj, x, xout, BT_*D_, D_);

  ln_rows<<<BT_, 256, 0, stream>>>(xout, ln2_g, ln2_b, h2);

  gemm_bt<1,1,0,1,0><<<dim3(FF_/128, BT_/128), 256, 0, stream>>>(
      h2, w1t, b1, nullptr, ff1, BT_, FF_, D_, D_);

  // ff2: split-K=4 partials + fused reduce (bias + xout residual) -> xout in place
  gemm_bt<0,0,0,0,1><<<dim3(D_/128, BT_/128, 4), 256, 0, stream>>>(
      ff1, w2t, nullptr, nullptr, fparts, BT_, D_, FF_, FF_/4);
  reduce_parts<4><<<(BT_*D_)/1024, 256, 0, stream>>>(
      fparts, b2, xout, xout, BT_*D_, D_);
}

// Round 5
// 322.639 us; speedup vs baseline: 1.2582x; 1.0333x over previous
//
#include <hip/hip_runtime.h>
#include <hip/hip_bf16.h>
#include <cstdint>
#include <cstddef>
#include <math.h>

#define D_ 1024
#define H_ 16
#define HD_ 64
#define T_ 2048
#define B_ 2
#define FF_ 4096
#define BT_ (B_*T_)   // 4096 rows
#define NT_ 32        // T_/64 kv tiles

typedef unsigned short u16;
typedef __attribute__((ext_vector_type(8))) __bf16 bf16x8;
typedef __attribute__((ext_vector_type(8))) u16 u16x8;
typedef __attribute__((ext_vector_type(4))) float f32x4;

__device__ __forceinline__ u16 f2bf(float f) {
  unsigned u = __builtin_bit_cast(unsigned, f);
  u += 0x7FFFu + ((u >> 16) & 1u);
  return (u16)(u >> 16);
}

__device__ __forceinline__ void gload16(const void* g, void* l) {
  __builtin_amdgcn_global_load_lds((__attribute__((address_space(1))) void*)g,
                                   (__attribute__((address_space(3))) void*)l, 16, 0, 0);
}

// ---------------- transpose + fp32->bf16 cast:  out[(z*C+c)*R + r] = in[z*R*C + r*C + c]
__global__ __launch_bounds__(256) void transpose_w(const float* __restrict__ in,
                                                   u16* __restrict__ out, int R, int C) {
  __shared__ float tile[32][33];
  const int z = blockIdx.z;
  const float* inz = in + (size_t)z * R * C;
  const int x = blockIdx.x * 32 + threadIdx.x;
  const int y0 = blockIdx.y * 32 + threadIdx.y;
  #pragma unroll
  for (int j = 0; j < 32; j += 8)
    tile[threadIdx.y + j][threadIdx.x] = inz[(size_t)(y0 + j) * C + x];
  __syncthreads();
  const int orr = blockIdx.y * 32 + threadIdx.x;
  const int oc0 = blockIdx.x * 32 + threadIdx.y;
  u16* outz = out + (size_t)z * C * R;
  #pragma unroll
  for (int j = 0; j < 32; j += 8)
    outz[(size_t)(oc0 + j) * R + orr] = f2bf(tile[threadIdx.x][threadIdx.y + j]);
}

// ---------------- LayerNorm (fp32 in -> bf16 out), one row (D=1024) per block of 256
__global__ __launch_bounds__(256) void ln_rows(const float* __restrict__ x,
    const float* __restrict__ g, const float* __restrict__ bb, u16* __restrict__ out) {
  const int row = blockIdx.x, tid = threadIdx.x;
  const float4 v = ((const float4*)(x + (size_t)row * D_))[tid];
  float s = v.x + v.y + v.z + v.w;
  float sq = v.x*v.x + v.y*v.y + v.z*v.z + v.w*v.w;
  #pragma unroll
  for (int m = 1; m < 64; m <<= 1) { s += __shfl_xor(s, m); sq += __shfl_xor(sq, m); }
  __shared__ float ss[4], qs[4];
  if ((tid & 63) == 0) { ss[tid >> 6] = s; qs[tid >> 6] = sq; }
  __syncthreads();
  s  = ss[0] + ss[1] + ss[2] + ss[3];
  sq = qs[0] + qs[1] + qs[2] + qs[3];
  const float mean = s * (1.f / D_);
  const float var  = sq * (1.f / D_) - mean * mean;
  const float rstd = rsqrtf(var + 1e-5f);
  const float4 gv = ((const float4*)g)[tid];
  const float4 bv = ((const float4*)bb)[tid];
  u16 o[4];
  o[0] = f2bf((v.x - mean) * rstd * gv.x + bv.x);
  o[1] = f2bf((v.y - mean) * rstd * gv.y + bv.y);
  o[2] = f2bf((v.z - mean) * rstd * gv.z + bv.z);
  o[3] = f2bf((v.w - mean) * rstd * gv.w + bv.w);
  *(ushort4*)(out + (size_t)row * D_ + tid * 4) = *(ushort4*)o;
}

// ---------------- GEMM: C[M,N] = act(A[M,K] * Bt[N,K]^T + bias) (+resid)
// m97 structure + T1 XCD swizzle. PARTIAL: split-K over blockIdx.z, fp32 partials.
template<int ACT, int BIAS, int RESID, int OUTBF, int PARTIAL>
__global__ __launch_bounds__(256) void gemm_bt(
    const u16* __restrict__ A, const u16* __restrict__ Bt,
    const float* __restrict__ bias, const float* resid,
    void* Cout, int M, int N, int K, int Kper) {
  __shared__ __attribute__((aligned(16))) u16 As[128 * 32];
  __shared__ __attribute__((aligned(16))) u16 Bs[128 * 32];
  const int tid = threadIdx.x;
  const int wid = tid >> 6, lane = tid & 63;
  const int gx = gridDim.x;
  const int nwg = gx * gridDim.y;
  const int orig = blockIdx.y * gx + blockIdx.x;
  const int cpx = nwg >> 3;
  const int swz = (orig & 7) * cpx + (orig >> 3);
  const int bm = (swz / gx) * 128, bn = (swz % gx) * 128;
  const int wm = (wid >> 1) * 64, wn = (wid & 1) * 64;
  const int z = PARTIAL ? blockIdx.z : 0;
  const int koff = z * Kper;

  f32x4 acc[4][4] = {};

  const u16* Ag = A + (size_t)(bm + wid * 32 + (lane >> 2)) * K + koff + (lane & 3) * 8;
  const u16* Bg = Bt + (size_t)(bn + wid * 32 + (lane >> 2)) * K + koff + (lane & 3) * 8;
  u16* AsW = As + (wid * 32) * 32;
  u16* BsW = Bs + (wid * 32) * 32;
  const int ro = (lane & 15) * 32 + (lane >> 4) * 8;

  for (int k0 = 0; k0 < Kper; k0 += 32) {
    gload16(Ag + k0,                 AsW);
    gload16(Ag + k0 + (size_t)16 * K, AsW + 16 * 32);
    gload16(Bg + k0,                 BsW);
    gload16(Bg + k0 + (size_t)16 * K, BsW + 16 * 32);
    __syncthreads();
    bf16x8 af[4], bfr[4];
    #pragma unroll
    for (int i = 0; i < 4; i++) af[i]  = *(const bf16x8*)(As + (wm + i * 16) * 32 + ro);
    #pragma unroll
    for (int i = 0; i < 4; i++) bfr[i] = *(const bf16x8*)(Bs + (wn + i * 16) * 32 + ro);
    #pragma unroll
    for (int mi = 0; mi < 4; mi++)
      #pragma unroll
      for (int ni = 0; ni < 4; ni++)
        acc[mi][ni] = __builtin_amdgcn_mfma_f32_16x16x32_bf16(af[mi], bfr[ni], acc[mi][ni], 0, 0, 0);
    __syncthreads();
  }

  const int r0 = bm + wm + ((lane >> 4) << 2);
  const int c0 = bn + wn + (lane & 15);
  #pragma unroll
  for (int mi = 0; mi < 4; mi++) {
    #pragma unroll
    for (int ni = 0; ni < 4; ni++) {
      #pragma unroll
      for (int r = 0; r < 4; r++) {
        float v = acc[mi][ni][r];
        const int rr = r0 + mi * 16 + r;
        const int cc = c0 + ni * 16;
        if (PARTIAL) {
          ((float*)Cout)[((size_t)z * M + rr) * N + cc] = v;
        } else {
          if (BIAS) v += bias[cc];
          if (ACT == 1) v = 0.5f * v * (1.0f + erff(v * 0.70710678118f));
          if (RESID) v += resid[(size_t)rr * N + cc];
          if (OUTBF) ((u16*)Cout)[(size_t)rr * N + cc] = f2bf(v);
          else       ((float*)Cout)[(size_t)rr * N + cc] = v;
        }
      }
    }
  }
}

// ---------------- split-K reduce: out = sum(parts) + bias (+resid), fp32
template<int NPART>
__global__ __launch_bounds__(256) void reduce_parts(
    const float* __restrict__ parts, const float* __restrict__ bias,
    const float* __restrict__ resid, float* __restrict__ out, int MN, int N) {
  const int i4 = (blockIdx.x * 256 + threadIdx.x) * 4;
  if (i4 >= MN) return;
  float4 s = *(const float4*)(parts + i4);
  #pragma unroll
  for (int p = 1; p < NPART; p++) {
    const float4 t = *(const float4*)(parts + (size_t)p * MN + i4);
    s.x += t.x; s.y += t.y; s.z += t.z; s.w += t.w;
  }
  const float4 bv = *(const float4*)(bias + (i4 & (N - 1)));
  const float4 rv = *(const float4*)(resid + i4);
  s.x += bv.x + rv.x; s.y += bv.y + rv.y; s.z += bv.z + rv.z; s.w += bv.w + rv.w;
  *(float4*)(out + i4) = s;
}

// ---------------- repack qkv [bt, 3*D] -> q,k [bh, T, 64] and v^T [bh, 64, T]
__global__ __launch_bounds__(256) void repack_qkv(const u16* __restrict__ qkv,
    u16* __restrict__ q, u16* __restrict__ k, u16* __restrict__ vt) {
  const int t0 = blockIdx.x * 64, bh = blockIdx.y;
  const int b = bh >> 4, h = bh & 15;
  const int tid = threadIdx.x;
  const int c = (tid & 7) * 8;
  __shared__ __attribute__((aligned(16))) u16 vs[64][72];
  #pragma unroll
  for (int p = 0; p < 2; p++) {
    const int tl = p * 32 + (tid >> 3);
    const size_t inrow = ((size_t)b * T_ + t0 + tl) * 3072 + h * 64;
    bf16x8 qv = *(const bf16x8*)(qkv + inrow + c);
    bf16x8 kv = *(const bf16x8*)(qkv + inrow + 1024 + c);
    bf16x8 vv = *(const bf16x8*)(qkv + inrow + 2048 + c);
    *(bf16x8*)(q + ((size_t)bh * T_ + t0 + tl) * HD_ + c) = qv;
    *(bf16x8*)(k + ((size_t)bh * T_ + t0 + tl) * HD_ + c) = kv;
    *(bf16x8*)&vs[tl][c] = vv;
  }
  __syncthreads();
  const int d = tid >> 2, tc = (tid & 3) * 16;
  alignas(16) u16 tmp[16];
  #pragma unroll
  for (int j = 0; j < 16; j++) tmp[j] = vs[tc + j][d];
  *(bf16x8*)(vt + ((size_t)bh * HD_ + d) * T_ + t0 + tc)     = *(bf16x8*)&tmp[0];
  *(bf16x8*)(vt + ((size_t)bh * HD_ + d) * T_ + t0 + tc + 8) = *(bf16x8*)&tmp[8];
}

// ---------------- flash attention v3:
// 1024 blocks, XCD-locality mapping (4 bh per XCD -> K/V L2-resident), longest-qt-first.
// Q direct to regs; Ps per-wave swizzled [16][64]; row-sum l via ones-column MFMA;
// defer-max (THR=8, log2 domain); LDS 40KB -> 4 blocks/CU.
__global__ __launch_bounds__(256) void attn_fwd(
    const u16* __restrict__ q, const u16* __restrict__ k,
    const u16* __restrict__ vt, u16* __restrict__ out) {
  __shared__ __attribute__((aligned(16))) u16 Ps[4][16 * 64];
  __shared__ __attribute__((aligned(16))) u16 Kb[2][64 * 64];
  __shared__ __attribute__((aligned(16))) u16 Vb[2][64 * 64];

  const int bid = blockIdx.x;
  const int xcd = bid & 7, j = bid >> 3;     // j = 0..127
  const int bh  = xcd + 8 * (j & 3);         // 4 bh per xcd -> 2MB K/V, L2-resident
  const int qt  = 31 - (j >> 2);             // large qt dispatched first
  const int b = bh >> 4, h = bh & 15;
  const int tid = threadIdx.x, wid = tid >> 6, lane = tid & 63;
  const u16* kh = k  + (size_t)bh * T_ * HD_;
  const u16* vh = vt + (size_t)bh * HD_ * T_;
  const int q0 = qt * 64;

  const int frow = lane & 15;
  const int hi   = lane >> 4;
  const int fk   = hi * 8;
  const int rowb = hi * 4;
  const int colb = frow;

  const int srl = lane >> 3;
  const int scs = (lane & 7) ^ srl;

  const float SCL2 = 0.18033688011112042f;  // 0.125 * log2(e)

  // Q straight from global (2 x 16B per lane, L2-resident)
  const u16* qrow = q + ((size_t)bh * T_ + q0 + wid * 16 + frow) * HD_;
  bf16x8 aq[2];
  aq[0] = *(const bf16x8*)(qrow + fk);
  aq[1] = *(const bf16x8*)(qrow + 32 + fk);

  // ones B-fragment: row 64 of extended V^T = 1 (frow==0 lanes), rest 0
  u16x8 onebits = (u16x8)((u16)0x3F80);
  bf16x8 b_one = (frow == 0) ? __builtin_bit_cast(bf16x8, onebits) : (bf16x8){};

  float m2[4] = {-3e38f, -3e38f, -3e38f, -3e38f};
  f32x4 acc_l = {};
  f32x4 acc_o[4] = {};

  u16* Pw = &Ps[wid][0];

  int cur = 0;
  #pragma unroll
  for (int jj = 0; jj < 2; ++jj) {
    const int row = wid * 16 + jj * 8 + srl;
    gload16(kh + (size_t)row * HD_ + scs * 8,  &Kb[0][(wid * 16 + jj * 8) * 64]);
    gload16(vh + (size_t)row * T_ + scs * 8,   &Vb[0][(wid * 16 + jj * 8) * 64]);
  }
  __syncthreads();

  for (int kt = 0; kt <= qt; ++kt) {
    if (kt < qt) {
      const int nx = cur ^ 1, ktn = kt + 1;
      #pragma unroll
      for (int jj = 0; jj < 2; ++jj) {
        const int row = wid * 16 + jj * 8 + srl;
        gload16(kh + (size_t)(ktn * 64 + row) * HD_ + scs * 8, &Kb[nx][(wid * 16 + jj * 8) * 64]);
        gload16(vh + (size_t)row * T_ + ktn * 64 + scs * 8,    &Vb[nx][(wid * 16 + jj * 8) * 64]);
      }
    }

    const u16* Kc = &Kb[cur][0];
    const u16* Vc = &Vb[cur][0];

    // ---- QK^T
    float p2[4][4];
    __builtin_amdgcn_s_setprio(1);
    #pragma unroll
    for (int ni = 0; ni < 4; ni++) {
      f32x4 s = {};
      #pragma unroll
      for (int ks = 0; ks < 2; ks++) {
        const int row = ni * 16 + frow;
        const int ch  = ks * 4 + hi;
        bf16x8 bk = *(const bf16x8*)(Kc + row * 64 + ((ch ^ (row & 7)) << 3));
        s = __builtin_amdgcn_mfma_f32_16x16x32_bf16(aq[ks], bk, s, 0, 0, 0);
      }
      #pragma unroll
      for (int r = 0; r < 4; r++) {
        const bool msk = (kt == qt) && (ni * 16 + colb) > (wid * 16 + rowb + r);
        p2[ni][r] = msk ? -3e38f : s[r] * SCL2;
      }
    }
    __builtin_amdgcn_s_setprio(0);

    // ---- row max (16-lane group reduce)
    float pmax[4];
    #pragma unroll
    for (int r = 0; r < 4; r++) {
      float rm = fmaxf(fmaxf(p2[0][r], p2[1][r]), fmaxf(p2[2][r], p2[3][r]));
      rm = fmaxf(rm, __shfl_xor(rm, 1));
      rm = fmaxf(rm, __shfl_xor(rm, 2));
      rm = fmaxf(rm, __shfl_xor(rm, 4));
      rm = fmaxf(rm, __shfl_xor(rm, 8));
      pmax[r] = rm;
    }
    // ---- defer-max: rescale only when max grew past THR=8 (log2 units)
    int ok = 1;
    #pragma unroll
    for (int r = 0; r < 4; r++) ok &= (pmax[r] <= m2[r] + 8.0f);
    if (!__all(ok)) {
      #pragma unroll
      for (int r = 0; r < 4; r++) {
        const float mnew = fmaxf(m2[r], pmax[r]);
        const float corr = exp2f(m2[r] - mnew);
        m2[r] = mnew;
        acc_l[r] *= corr;
        #pragma unroll
        for (int ni = 0; ni < 4; ni++) acc_o[ni][r] *= corr;
      }
    }
    #pragma unroll
    for (int ni = 0; ni < 4; ni++)
      #pragma unroll
      for (int r = 0; r < 4; r++) p2[ni][r] = exp2f(p2[ni][r] - m2[r]);

    // ---- P -> per-wave swizzled LDS, reload as A-frag
    #pragma unroll
    for (int ni = 0; ni < 4; ni++) {
      #pragma unroll
      for (int r = 0; r < 4; r++) {
        const int lr = rowb + r;
        const int ch = ni * 2 + (colb >> 3);
        Pw[lr * 64 + ((ch ^ (lr & 7)) << 3) + (colb & 7)] = f2bf(p2[ni][r]);
      }
    }
    bf16x8 ap[2];
    {
      const int c0 = (0 * 4 + hi) ^ (frow & 7);
      const int c1 = (1 * 4 + hi) ^ (frow & 7);
      ap[0] = *(const bf16x8*)(Pw + frow * 64 + (c0 << 3));
      ap[1] = *(const bf16x8*)(Pw + frow * 64 + (c1 << 3));
    }

    // ---- PV (+ ones-column for l)
    __builtin_amdgcn_s_setprio(1);
    #pragma unroll
    for (int ks = 0; ks < 2; ks++)
      acc_l = __builtin_amdgcn_mfma_f32_16x16x32_bf16(ap[ks], b_one, acc_l, 0, 0, 0);
    #pragma unroll
    for (int ni = 0; ni < 4; ni++) {
      #pragma unroll
      for (int ks = 0; ks < 2; ks++) {
        const int row = ni * 16 + frow;
        const int ch  = ks * 4 + hi;
        bf16x8 bv = *(const bf16x8*)(Vc + row * 64 + ((ch ^ (row & 7)) << 3));
        acc_o[ni] = __builtin_amdgcn_mfma_f32_16x16x32_bf16(ap[ks], bv, acc_o[ni], 0, 0, 0);
      }
    }
    __builtin_amdgcn_s_setprio(0);

    __syncthreads();
    cur ^= 1;
  }

  // ---- epilogue: broadcast l from frow==0 lane of each group, normalize, write
  float linv[4];
  #pragma unroll
  for (int r = 0; r < 4; r++) {
    const float lv = __shfl(acc_l[r], lane & 48);
    linv[r] = 1.0f / lv;
  }
  #pragma unroll
  for (int ni = 0; ni < 4; ni++)
    #pragma unroll
    for (int r = 0; r < 4; r++) {
      const float ov = acc_o[ni][r] * linv[r];
      const size_t row = (size_t)b * T_ + q0 + wid * 16 + rowb + r;
      out[row * D_ + h * HD_ + ni * 16 + colb] = f2bf(ov);
    }
}

extern "C" void kernel_launch(void* const* d_in, const int* in_sizes, int n_in,
                              void* d_out, int out_size, void* d_ws, size_t ws_size,
                              hipStream_t stream) {
  (void)in_sizes; (void)n_in; (void)out_size; (void)ws_size;
  const float* x      = (const float*)d_in[0];
  const float* wq     = (const float*)d_in[1];
  const float* wk     = (const float*)d_in[2];
  const float* wv     = (const float*)d_in[3];
  const float* w_proj = (const float*)d_in[4];
  const float* b_proj = (const float*)d_in[5];
  const float* ln1_g  = (const float*)d_in[6];
  const float* ln1_b  = (const float*)d_in[7];
  const float* ln2_g  = (const float*)d_in[8];
  const float* ln2_b  = (const float*)d_in[9];
  const float* w1     = (const float*)d_in[10];
  const float* b1     = (const float*)d_in[11];
  const float* w2     = (const float*)d_in[12];
  const float* b2     = (const float*)d_in[13];

  uint8_t* ws = (uint8_t*)d_ws;
  const size_t MB = 1024 * 1024;
  u16* wqkv_t = (u16*)(ws + 0);        // [3072,1024]
  u16* wproj_t = (u16*)(ws + 6 * MB);  // [1024,1024]
  u16* w1t  = (u16*)(ws + 8 * MB);     // [4096,1024]
  u16* w2t  = (u16*)(ws + 16 * MB);    // [1024,4096]
  u16* hbuf = (u16*)(ws + 24 * MB);    // [4096,1024]
  u16* qkv  = (u16*)(ws + 32 * MB);    // [4096,3072]  (dead after repack)
  u16* qb   = (u16*)(ws + 56 * MB);    // [32,2048,64] (dead after attn)
  u16* kb   = (u16*)(ws + 64 * MB);    // (dead after attn)
  u16* vtb  = (u16*)(ws + 72 * MB);    // (dead after attn)
  u16* aout = (u16*)(ws + 80 * MB);    // [4096,1024]
  u16* h2   = (u16*)(ws + 88 * MB);    // [4096,1024]
  u16* ff1  = (u16*)(ws + 96 * MB);    // [4096,4096]
  float* pparts = (float*)(ws + 32 * MB);  // proj: 2 x [4096,1024] fp32 = 32 MB
  float* fparts = (float*)(ws + 32 * MB);  // ff2:  4 x [4096,1024] fp32 = 64 MB
  float* xout = (float*)d_out;

  const dim3 tb(32, 8);
  transpose_w<<<dim3(HD_/32, D_/32, H_), tb, 0, stream>>>(wq, wqkv_t, D_, HD_);
  transpose_w<<<dim3(HD_/32, D_/32, H_), tb, 0, stream>>>(wk, wqkv_t + (size_t)D_*D_, D_, HD_);
  transpose_w<<<dim3(HD_/32, D_/32, H_), tb, 0, stream>>>(wv, wqkv_t + 2*(size_t)D_*D_, D_, HD_);
  transpose_w<<<dim3(D_/32, D_/32, 1),  tb, 0, stream>>>(w_proj, wproj_t, D_, D_);
  transpose_w<<<dim3(FF_/32, D_/32, 1), tb, 0, stream>>>(w1, w1t, D_, FF_);
  transpose_w<<<dim3(D_/32, FF_/32, 1), tb, 0, stream>>>(w2, w2t, FF_, D_);

  ln_rows<<<BT_, 256, 0, stream>>>(x, ln1_g, ln1_b, hbuf);

  gemm_bt<0,0,0,1,0><<<dim3(3072/128, BT_/128), 256, 0, stream>>>(
      hbuf, wqkv_t, nullptr, nullptr, qkv, BT_, 3072, D_, D_);

  repack_qkv<<<dim3(T_/64, B_*H_), 256, 0, stream>>>(qkv, qb, kb, vtb);

  attn_fwd<<<dim3(NT_ * B_ * H_), 256, 0, stream>>>(qb, kb, vtb, aout);

  // proj: split-K=2 partials + fused reduce (bias + x residual) -> xout (fp32)
  gemm_bt<0,0,0,0,1><<<dim3(D_/128, BT_/128, 2), 256, 0, stream>>>(
      aout, wproj_t, nullptr, nullptr, pparts, BT_, D_, D_, D_/2);
  reduce_parts<2><<<(BT_*D_)/1024, 256, 0, stream>>>(
      pparts, b_proj, x, xout, BT_*D_, D_);

  ln_rows<<<BT_, 256, 0, stream>>>(xout, ln2_g, ln2_b, h2);

  gemm_bt<1,1,0,1,0><<<dim3(FF_/128, BT_/128), 256, 0, stream>>>(
      h2, w1t, b1, nullptr, ff1, BT_, FF_, D_, D_);

  // ff2: split-K=4 partials + fused reduce (bias + xout residual) -> xout in place
  gemm_bt<0,0,0,0,1><<<dim3(D_/128, BT_/128, 4), 256, 0, stream>>>(
      ff1, w2t, nullptr, nullptr, fparts, BT_, D_, FF_, FF_/4);
  reduce_parts<4><<<(BT_*D_)/1024, 256, 0, stream>>>(
      fparts, b2, xout, xout, BT_*D_, D_);
}

// Round 6
// 300.783 us; speedup vs baseline: 1.3497x; 1.0727x over previous
//
#include <hip/hip_runtime.h>
#include <hip/hip_bf16.h>
#include <cstdint>
#include <cstddef>
#include <math.h>

#define D_ 1024
#define H_ 16
#define HD_ 64
#define T_ 2048
#define B_ 2
#define FF_ 4096
#define BT_ (B_*T_)   // 4096 rows
#define NT_ 32        // T_/64 kv tiles

typedef unsigned short u16;
typedef __attribute__((ext_vector_type(8))) __bf16 bf16x8;
typedef __attribute__((ext_vector_type(8))) u16 u16x8;
typedef __attribute__((ext_vector_type(4))) float f32x4;

__device__ __forceinline__ u16 f2bf(float f) {
  unsigned u = __builtin_bit_cast(unsigned, f);
  u += 0x7FFFu + ((u >> 16) & 1u);
  return (u16)(u >> 16);
}

__device__ __forceinline__ void gload16(const void* g, void* l) {
  __builtin_amdgcn_global_load_lds((__attribute__((address_space(1))) void*)g,
                                   (__attribute__((address_space(3))) void*)l, 16, 0, 0);
}

// ---------------- transpose + fp32->bf16 cast:  out[(z*C+c)*R + r] = in[z*R*C + r*C + c]
__global__ __launch_bounds__(256) void transpose_w(const float* __restrict__ in,
                                                   u16* __restrict__ out, int R, int C) {
  __shared__ float tile[32][33];
  const int z = blockIdx.z;
  const float* inz = in + (size_t)z * R * C;
  const int x = blockIdx.x * 32 + threadIdx.x;
  const int y0 = blockIdx.y * 32 + threadIdx.y;
  #pragma unroll
  for (int j = 0; j < 32; j += 8)
    tile[threadIdx.y + j][threadIdx.x] = inz[(size_t)(y0 + j) * C + x];
  __syncthreads();
  const int orr = blockIdx.y * 32 + threadIdx.x;
  const int oc0 = blockIdx.x * 32 + threadIdx.y;
  u16* outz = out + (size_t)z * C * R;
  #pragma unroll
  for (int j = 0; j < 32; j += 8)
    outz[(size_t)(oc0 + j) * R + orr] = f2bf(tile[threadIdx.x][threadIdx.y + j]);
}

// ---------------- LayerNorm (fp32 in -> bf16 out), one row (D=1024) per block of 256
__global__ __launch_bounds__(256) void ln_rows(const float* __restrict__ x,
    const float* __restrict__ g, const float* __restrict__ bb, u16* __restrict__ out) {
  const int row = blockIdx.x, tid = threadIdx.x;
  const float4 v = ((const float4*)(x + (size_t)row * D_))[tid];
  float s = v.x + v.y + v.z + v.w;
  float sq = v.x*v.x + v.y*v.y + v.z*v.z + v.w*v.w;
  #pragma unroll
  for (int m = 1; m < 64; m <<= 1) { s += __shfl_xor(s, m); sq += __shfl_xor(sq, m); }
  __shared__ float ss[4], qs[4];
  if ((tid & 63) == 0) { ss[tid >> 6] = s; qs[tid >> 6] = sq; }
  __syncthreads();
  s  = ss[0] + ss[1] + ss[2] + ss[3];
  sq = qs[0] + qs[1] + qs[2] + qs[3];
  const float mean = s * (1.f / D_);
  const float var  = sq * (1.f / D_) - mean * mean;
  const float rstd = rsqrtf(var + 1e-5f);
  const float4 gv = ((const float4*)g)[tid];
  const float4 bv = ((const float4*)bb)[tid];
  u16 o[4];
  o[0] = f2bf((v.x - mean) * rstd * gv.x + bv.x);
  o[1] = f2bf((v.y - mean) * rstd * gv.y + bv.y);
  o[2] = f2bf((v.z - mean) * rstd * gv.z + bv.z);
  o[3] = f2bf((v.w - mean) * rstd * gv.w + bv.w);
  *(ushort4*)(out + (size_t)row * D_ + tid * 4) = *(ushort4*)o;
}

// ---------------- GEMM: C[M,N] = act(A[M,K] * Bt[N,K]^T + bias) (+resid)
// m97 structure + T1 XCD swizzle + T3-min double-buffered prefetch pipeline:
// stage(next) issued BEFORE ds_read+MFMA(cur); ONE barrier per K-step.
template<int ACT, int BIAS, int RESID, int OUTBF, int PARTIAL>
__global__ __launch_bounds__(256) void gemm_bt(
    const u16* __restrict__ A, const u16* __restrict__ Bt,
    const float* __restrict__ bias, const float* resid,
    void* Cout, int M, int N, int K, int Kper) {
  __shared__ __attribute__((aligned(16))) u16 As[2][128 * 32];
  __shared__ __attribute__((aligned(16))) u16 Bs[2][128 * 32];
  const int tid = threadIdx.x;
  const int wid = tid >> 6, lane = tid & 63;
  const int gx = gridDim.x;
  const int nwg = gx * gridDim.y;
  const int orig = blockIdx.y * gx + blockIdx.x;
  const int cpx = nwg >> 3;
  const int swz = (orig & 7) * cpx + (orig >> 3);
  const int bm = (swz / gx) * 128, bn = (swz % gx) * 128;
  const int wm = (wid >> 1) * 64, wn = (wid & 1) * 64;
  const int z = PARTIAL ? blockIdx.z : 0;
  const int koff = z * Kper;

  f32x4 acc[4][4] = {};

  const u16* Ag = A + (size_t)(bm + wid * 32 + (lane >> 2)) * K + koff + (lane & 3) * 8;
  const u16* Bg = Bt + (size_t)(bn + wid * 32 + (lane >> 2)) * K + koff + (lane & 3) * 8;
  const int wofs = (wid * 32) * 32;
  const int ro = (lane & 15) * 32 + (lane >> 4) * 8;

  // prologue: stage k0=0 into buffer 0
  gload16(Ag,                  &As[0][wofs]);
  gload16(Ag + (size_t)16 * K, &As[0][wofs + 16 * 32]);
  gload16(Bg,                  &Bs[0][wofs]);
  gload16(Bg + (size_t)16 * K, &Bs[0][wofs + 16 * 32]);
  __syncthreads();

  int buf = 0;
  for (int k0 = 0; k0 < Kper; k0 += 32) {
    // prefetch next K-step into the other buffer (in flight across this step's MFMA)
    if (k0 + 32 < Kper) {
      const int nb = buf ^ 1;
      gload16(Ag + k0 + 32,                  &As[nb][wofs]);
      gload16(Ag + k0 + 32 + (size_t)16 * K, &As[nb][wofs + 16 * 32]);
      gload16(Bg + k0 + 32,                  &Bs[nb][wofs]);
      gload16(Bg + k0 + 32 + (size_t)16 * K, &Bs[nb][wofs + 16 * 32]);
    }
    bf16x8 af[4], bfr[4];
    #pragma unroll
    for (int i = 0; i < 4; i++) af[i]  = *(const bf16x8*)(&As[buf][(wm + i * 16) * 32 + ro]);
    #pragma unroll
    for (int i = 0; i < 4; i++) bfr[i] = *(const bf16x8*)(&Bs[buf][(wn + i * 16) * 32 + ro]);
    #pragma unroll
    for (int mi = 0; mi < 4; mi++)
      #pragma unroll
      for (int ni = 0; ni < 4; ni++)
        acc[mi][ni] = __builtin_amdgcn_mfma_f32_16x16x32_bf16(af[mi], bfr[ni], acc[mi][ni], 0, 0, 0);
    __syncthreads();   // drains vmcnt: prefetched tile ready; WAR-safe to overwrite buf next iter
    buf ^= 1;
  }

  const int r0 = bm + wm + ((lane >> 4) << 2);
  const int c0 = bn + wn + (lane & 15);
  #pragma unroll
  for (int mi = 0; mi < 4; mi++) {
    #pragma unroll
    for (int ni = 0; ni < 4; ni++) {
      #pragma unroll
      for (int r = 0; r < 4; r++) {
        float v = acc[mi][ni][r];
        const int rr = r0 + mi * 16 + r;
        const int cc = c0 + ni * 16;
        if (PARTIAL) {
          ((float*)Cout)[((size_t)z * M + rr) * N + cc] = v;
        } else {
          if (BIAS) v += bias[cc];
          if (ACT == 1) v = 0.5f * v * (1.0f + erff(v * 0.70710678118f));
          if (RESID) v += resid[(size_t)rr * N + cc];
          if (OUTBF) ((u16*)Cout)[(size_t)rr * N + cc] = f2bf(v);
          else       ((float*)Cout)[(size_t)rr * N + cc] = v;
        }
      }
    }
  }
}

// ---------------- split-K reduce: out = sum(parts) + bias (+resid), fp32
template<int NPART>
__global__ __launch_bounds__(256) void reduce_parts(
    const float* __restrict__ parts, const float* __restrict__ bias,
    const float* __restrict__ resid, float* __restrict__ out, int MN, int N) {
  const int i4 = (blockIdx.x * 256 + threadIdx.x) * 4;
  if (i4 >= MN) return;
  float4 s = *(const float4*)(parts + i4);
  #pragma unroll
  for (int p = 1; p < NPART; p++) {
    const float4 t = *(const float4*)(parts + (size_t)p * MN + i4);
    s.x += t.x; s.y += t.y; s.z += t.z; s.w += t.w;
  }
  const float4 bv = *(const float4*)(bias + (i4 & (N - 1)));
  const float4 rv = *(const float4*)(resid + i4);
  s.x += bv.x + rv.x; s.y += bv.y + rv.y; s.z += bv.z + rv.z; s.w += bv.w + rv.w;
  *(float4*)(out + i4) = s;
}

// ---------------- repack qkv [bt, 3*D] -> q,k [bh, T, 64] and v^T [bh, 64, T]
__global__ __launch_bounds__(256) void repack_qkv(const u16* __restrict__ qkv,
    u16* __restrict__ q, u16* __restrict__ k, u16* __restrict__ vt) {
  const int t0 = blockIdx.x * 64, bh = blockIdx.y;
  const int b = bh >> 4, h = bh & 15;
  const int tid = threadIdx.x;
  const int c = (tid & 7) * 8;
  __shared__ __attribute__((aligned(16))) u16 vs[64][72];
  #pragma unroll
  for (int p = 0; p < 2; p++) {
    const int tl = p * 32 + (tid >> 3);
    const size_t inrow = ((size_t)b * T_ + t0 + tl) * 3072 + h * 64;
    bf16x8 qv = *(const bf16x8*)(qkv + inrow + c);
    bf16x8 kv = *(const bf16x8*)(qkv + inrow + 1024 + c);
    bf16x8 vv = *(const bf16x8*)(qkv + inrow + 2048 + c);
    *(bf16x8*)(q + ((size_t)bh * T_ + t0 + tl) * HD_ + c) = qv;
    *(bf16x8*)(k + ((size_t)bh * T_ + t0 + tl) * HD_ + c) = kv;
    *(bf16x8*)&vs[tl][c] = vv;
  }
  __syncthreads();
  const int d = tid >> 2, tc = (tid & 3) * 16;
  alignas(16) u16 tmp[16];
  #pragma unroll
  for (int j = 0; j < 16; j++) tmp[j] = vs[tc + j][d];
  *(bf16x8*)(vt + ((size_t)bh * HD_ + d) * T_ + t0 + tc)     = *(bf16x8*)&tmp[0];
  *(bf16x8*)(vt + ((size_t)bh * HD_ + d) * T_ + t0 + tc + 8) = *(bf16x8*)&tmp[8];
}

// ---------------- flash attention v3 (XCD-locality, ones-column l, defer-max)
__global__ __launch_bounds__(256) void attn_fwd(
    const u16* __restrict__ q, const u16* __restrict__ k,
    const u16* __restrict__ vt, u16* __restrict__ out) {
  __shared__ __attribute__((aligned(16))) u16 Ps[4][16 * 64];
  __shared__ __attribute__((aligned(16))) u16 Kb[2][64 * 64];
  __shared__ __attribute__((aligned(16))) u16 Vb[2][64 * 64];

  const int bid = blockIdx.x;
  const int xcd = bid & 7, j = bid >> 3;     // j = 0..127
  const int bh  = xcd + 8 * (j & 3);         // 4 bh per xcd -> 2MB K/V, L2-resident
  const int qt  = 31 - (j >> 2);             // large qt dispatched first
  const int b = bh >> 4, h = bh & 15;
  const int tid = threadIdx.x, wid = tid >> 6, lane = tid & 63;
  const u16* kh = k  + (size_t)bh * T_ * HD_;
  const u16* vh = vt + (size_t)bh * HD_ * T_;
  const int q0 = qt * 64;

  const int frow = lane & 15;
  const int hi   = lane >> 4;
  const int fk   = hi * 8;
  const int rowb = hi * 4;
  const int colb = frow;

  const int srl = lane >> 3;
  const int scs = (lane & 7) ^ srl;

  const float SCL2 = 0.18033688011112042f;  // 0.125 * log2(e)

  const u16* qrow = q + ((size_t)bh * T_ + q0 + wid * 16 + frow) * HD_;
  bf16x8 aq[2];
  aq[0] = *(const bf16x8*)(qrow + fk);
  aq[1] = *(const bf16x8*)(qrow + 32 + fk);

  u16x8 onebits = (u16x8)((u16)0x3F80);
  bf16x8 b_one = (frow == 0) ? __builtin_bit_cast(bf16x8, onebits) : (bf16x8){};

  float m2[4] = {-3e38f, -3e38f, -3e38f, -3e38f};
  f32x4 acc_l = {};
  f32x4 acc_o[4] = {};

  u16* Pw = &Ps[wid][0];

  int cur = 0;
  #pragma unroll
  for (int jj = 0; jj < 2; ++jj) {
    const int row = wid * 16 + jj * 8 + srl;
    gload16(kh + (size_t)row * HD_ + scs * 8,  &Kb[0][(wid * 16 + jj * 8) * 64]);
    gload16(vh + (size_t)row * T_ + scs * 8,   &Vb[0][(wid * 16 + jj * 8) * 64]);
  }
  __syncthreads();

  for (int kt = 0; kt <= qt; ++kt) {
    if (kt < qt) {
      const int nx = cur ^ 1, ktn = kt + 1;
      #pragma unroll
      for (int jj = 0; jj < 2; ++jj) {
        const int row = wid * 16 + jj * 8 + srl;
        gload16(kh + (size_t)(ktn * 64 + row) * HD_ + scs * 8, &Kb[nx][(wid * 16 + jj * 8) * 64]);
        gload16(vh + (size_t)row * T_ + ktn * 64 + scs * 8,    &Vb[nx][(wid * 16 + jj * 8) * 64]);
      }
    }

    const u16* Kc = &Kb[cur][0];
    const u16* Vc = &Vb[cur][0];

    float p2[4][4];
    __builtin_amdgcn_s_setprio(1);
    #pragma unroll
    for (int ni = 0; ni < 4; ni++) {
      f32x4 s = {};
      #pragma unroll
      for (int ks = 0; ks < 2; ks++) {
        const int row = ni * 16 + frow;
        const int ch  = ks * 4 + hi;
        bf16x8 bk = *(const bf16x8*)(Kc + row * 64 + ((ch ^ (row & 7)) << 3));
        s = __builtin_amdgcn_mfma_f32_16x16x32_bf16(aq[ks], bk, s, 0, 0, 0);
      }
      #pragma unroll
      for (int r = 0; r < 4; r++) {
        const bool msk = (kt == qt) && (ni * 16 + colb) > (wid * 16 + rowb + r);
        p2[ni][r] = msk ? -3e38f : s[r] * SCL2;
      }
    }
    __builtin_amdgcn_s_setprio(0);

    float pmax[4];
    #pragma unroll
    for (int r = 0; r < 4; r++) {
      float rm = fmaxf(fmaxf(p2[0][r], p2[1][r]), fmaxf(p2[2][r], p2[3][r]));
      rm = fmaxf(rm, __shfl_xor(rm, 1));
      rm = fmaxf(rm, __shfl_xor(rm, 2));
      rm = fmaxf(rm, __shfl_xor(rm, 4));
      rm = fmaxf(rm, __shfl_xor(rm, 8));
      pmax[r] = rm;
    }
    int ok = 1;
    #pragma unroll
    for (int r = 0; r < 4; r++) ok &= (pmax[r] <= m2[r] + 8.0f);
    if (!__all(ok)) {
      #pragma unroll
      for (int r = 0; r < 4; r++) {
        const float mnew = fmaxf(m2[r], pmax[r]);
        const float corr = exp2f(m2[r] - mnew);
        m2[r] = mnew;
        acc_l[r] *= corr;
        #pragma unroll
        for (int ni = 0; ni < 4; ni++) acc_o[ni][r] *= corr;
      }
    }
    #pragma unroll
    for (int ni = 0; ni < 4; ni++)
      #pragma unroll
      for (int r = 0; r < 4; r++) p2[ni][r] = exp2f(p2[ni][r] - m2[r]);

    #pragma unroll
    for (int ni = 0; ni < 4; ni++) {
      #pragma unroll
      for (int r = 0; r < 4; r++) {
        const int lr = rowb + r;
        const int ch = ni * 2 + (colb >> 3);
        Pw[lr * 64 + ((ch ^ (lr & 7)) << 3) + (colb & 7)] = f2bf(p2[ni][r]);
      }
    }
    bf16x8 ap[2];
    {
      const int c0 = (0 * 4 + hi) ^ (frow & 7);
      const int c1 = (1 * 4 + hi) ^ (frow & 7);
      ap[0] = *(const bf16x8*)(Pw + frow * 64 + (c0 << 3));
      ap[1] = *(const bf16x8*)(Pw + frow * 64 + (c1 << 3));
    }

    __builtin_amdgcn_s_setprio(1);
    #pragma unroll
    for (int ks = 0; ks < 2; ks++)
      acc_l = __builtin_amdgcn_mfma_f32_16x16x32_bf16(ap[ks], b_one, acc_l, 0, 0, 0);
    #pragma unroll
    for (int ni = 0; ni < 4; ni++) {
      #pragma unroll
      for (int ks = 0; ks < 2; ks++) {
        const int row = ni * 16 + frow;
        const int ch  = ks * 4 + hi;
        bf16x8 bv = *(const bf16x8*)(Vc + row * 64 + ((ch ^ (row & 7)) << 3));
        acc_o[ni] = __builtin_amdgcn_mfma_f32_16x16x32_bf16(ap[ks], bv, acc_o[ni], 0, 0, 0);
      }
    }
    __builtin_amdgcn_s_setprio(0);

    __syncthreads();
    cur ^= 1;
  }

  float linv[4];
  #pragma unroll
  for (int r = 0; r < 4; r++) {
    const float lv = __shfl(acc_l[r], lane & 48);
    linv[r] = 1.0f / lv;
  }
  #pragma unroll
  for (int ni = 0; ni < 4; ni++)
    #pragma unroll
    for (int r = 0; r < 4; r++) {
      const float ov = acc_o[ni][r] * linv[r];
      const size_t row = (size_t)b * T_ + q0 + wid * 16 + rowb + r;
      out[row * D_ + h * HD_ + ni * 16 + colb] = f2bf(ov);
    }
}

extern "C" void kernel_launch(void* const* d_in, const int* in_sizes, int n_in,
                              void* d_out, int out_size, void* d_ws, size_t ws_size,
                              hipStream_t stream) {
  (void)in_sizes; (void)n_in; (void)out_size; (void)ws_size;
  const float* x      = (const float*)d_in[0];
  const float* wq     = (const float*)d_in[1];
  const float* wk     = (const float*)d_in[2];
  const float* wv     = (const float*)d_in[3];
  const float* w_proj = (const float*)d_in[4];
  const float* b_proj = (const float*)d_in[5];
  const float* ln1_g  = (const float*)d_in[6];
  const float* ln1_b  = (const float*)d_in[7];
  const float* ln2_g  = (const float*)d_in[8];
  const float* ln2_b  = (const float*)d_in[9];
  const float* w1     = (const float*)d_in[10];
  const float* b1     = (const float*)d_in[11];
  const float* w2     = (const float*)d_in[12];
  const float* b2     = (const float*)d_in[13];

  uint8_t* ws = (uint8_t*)d_ws;
  const size_t MB = 1024 * 1024;
  u16* wqkv_t = (u16*)(ws + 0);        // [3072,1024]
  u16* wproj_t = (u16*)(ws + 6 * MB);  // [1024,1024]
  u16* w1t  = (u16*)(ws + 8 * MB);     // [4096,1024]
  u16* w2t  = (u16*)(ws + 16 * MB);    // [1024,4096]
  u16* hbuf = (u16*)(ws + 24 * MB);    // [4096,1024]
  u16* qkv  = (u16*)(ws + 32 * MB);    // [4096,3072]  (dead after repack)
  u16* qb   = (u16*)(ws + 56 * MB);    // [32,2048,64] (dead after attn)
  u16* kb   = (u16*)(ws + 64 * MB);    // (dead after attn)
  u16* vtb  = (u16*)(ws + 72 * MB);    // (dead after attn)
  u16* aout = (u16*)(ws + 80 * MB);    // [4096,1024]
  u16* h2   = (u16*)(ws + 88 * MB);    // [4096,1024]
  u16* ff1  = (u16*)(ws + 96 * MB);    // [4096,4096]
  float* pparts = (float*)(ws + 32 * MB);  // proj: 2 x [4096,1024] fp32 = 32 MB
  float* fparts = (float*)(ws + 32 * MB);  // ff2:  4 x [4096,1024] fp32 = 64 MB
  float* xout = (float*)d_out;

  const dim3 tb(32, 8);
  transpose_w<<<dim3(HD_/32, D_/32, H_), tb, 0, stream>>>(wq, wqkv_t, D_, HD_);
  transpose_w<<<dim3(HD_/32, D_/32, H_), tb, 0, stream>>>(wk, wqkv_t + (size_t)D_*D_, D_, HD_);
  transpose_w<<<dim3(HD_/32, D_/32, H_), tb, 0, stream>>>(wv, wqkv_t + 2*(size_t)D_*D_, D_, HD_);
  transpose_w<<<dim3(D_/32, D_/32, 1),  tb, 0, stream>>>(w_proj, wproj_t, D_, D_);
  transpose_w<<<dim3(FF_/32, D_/32, 1), tb, 0, stream>>>(w1, w1t, D_, FF_);
  transpose_w<<<dim3(D_/32, FF_/32, 1), tb, 0, stream>>>(w2, w2t, FF_, D_);

  ln_rows<<<BT_, 256, 0, stream>>>(x, ln1_g, ln1_b, hbuf);

  gemm_bt<0,0,0,1,0><<<dim3(3072/128, BT_/128), 256, 0, stream>>>(
      hbuf, wqkv_t, nullptr, nullptr, qkv, BT_, 3072, D_, D_);

  repack_qkv<<<dim3(T_/64, B_*H_), 256, 0, stream>>>(qkv, qb, kb, vtb);

  attn_fwd<<<dim3(NT_ * B_ * H_), 256, 0, stream>>>(qb, kb, vtb, aout);

  // proj: split-K=2 partials + fused reduce (bias + x residual) -> xout (fp32)
  gemm_bt<0,0,0,0,1><<<dim3(D_/128, BT_/128, 2), 256, 0, stream>>>(
      aout, wproj_t, nullptr, nullptr, pparts, BT_, D_, D_, D_/2);
  reduce_parts<2><<<(BT_*D_)/1024, 256, 0, stream>>>(
      pparts, b_proj, x, xout, BT_*D_, D_);

  ln_rows<<<BT_, 256, 0, stream>>>(xout, ln2_g, ln2_b, h2);

  gemm_bt<1,1,0,1,0><<<dim3(FF_/128, BT_/128), 256, 0, stream>>>(
      h2, w1t, b1, nullptr, ff1, BT_, FF_, D_, D_);

  // ff2: split-K=4 partials + fused reduce (bias + xout residual) -> xout in place
  gemm_bt<0,0,0,0,1><<<dim3(D_/128, BT_/128, 4), 256, 0, stream>>>(
      ff1, w2t, nullptr, nullptr, fparts, BT_, D_, FF_, FF_/4);
  reduce_parts<4><<<(BT_*D_)/1024, 256, 0, stream>>>(
      fparts, b2, xout, xout, BT_*D_, D_);
}

// Round 7
// 297.345 us; speedup vs baseline: 1.3653x; 1.0116x over previous
//
#include <hip/hip_runtime.h>
#include <hip/hip_bf16.h>
#include <cstdint>
#include <cstddef>
#include <math.h>

#define D_ 1024
#define H_ 16
#define HD_ 64
#define T_ 2048
#define B_ 2
#define FF_ 4096
#define BT_ (B_*T_)   // 4096 rows
#define NT_ 32        // T_/64 kv tiles

typedef unsigned short u16;
typedef __attribute__((ext_vector_type(8))) __bf16 bf16x8;
typedef __attribute__((ext_vector_type(8))) u16 u16x8;
typedef __attribute__((ext_vector_type(4))) float f32x4;

__device__ __forceinline__ u16 f2bf(float f) {
  unsigned u = __builtin_bit_cast(unsigned, f);
  u += 0x7FFFu + ((u >> 16) & 1u);
  return (u16)(u >> 16);
}

__device__ __forceinline__ void gload16(const void* g, void* l) {
  __builtin_amdgcn_global_load_lds((__attribute__((address_space(1))) void*)g,
                                   (__attribute__((address_space(3))) void*)l, 16, 0, 0);
}

// ---------------- transpose + fp32->bf16 cast:  out[(z*C+c)*R + r] = in[z*R*C + r*C + c]
__global__ __launch_bounds__(256) void transpose_w(const float* __restrict__ in,
                                                   u16* __restrict__ out, int R, int C) {
  __shared__ float tile[32][33];
  const int z = blockIdx.z;
  const float* inz = in + (size_t)z * R * C;
  const int x = blockIdx.x * 32 + threadIdx.x;
  const int y0 = blockIdx.y * 32 + threadIdx.y;
  #pragma unroll
  for (int j = 0; j < 32; j += 8)
    tile[threadIdx.y + j][threadIdx.x] = inz[(size_t)(y0 + j) * C + x];
  __syncthreads();
  const int orr = blockIdx.y * 32 + threadIdx.x;
  const int oc0 = blockIdx.x * 32 + threadIdx.y;
  u16* outz = out + (size_t)z * C * R;
  #pragma unroll
  for (int j = 0; j < 32; j += 8)
    outz[(size_t)(oc0 + j) * R + orr] = f2bf(tile[threadIdx.x][threadIdx.y + j]);
}

// ---------------- LayerNorm (fp32 in -> bf16 out), one row (D=1024) per block of 256
__global__ __launch_bounds__(256) void ln_rows(const float* __restrict__ x,
    const float* __restrict__ g, const float* __restrict__ bb, u16* __restrict__ out) {
  const int row = blockIdx.x, tid = threadIdx.x;
  const float4 v = ((const float4*)(x + (size_t)row * D_))[tid];
  float s = v.x + v.y + v.z + v.w;
  float sq = v.x*v.x + v.y*v.y + v.z*v.z + v.w*v.w;
  #pragma unroll
  for (int m = 1; m < 64; m <<= 1) { s += __shfl_xor(s, m); sq += __shfl_xor(sq, m); }
  __shared__ float ss[4], qs[4];
  if ((tid & 63) == 0) { ss[tid >> 6] = s; qs[tid >> 6] = sq; }
  __syncthreads();
  s  = ss[0] + ss[1] + ss[2] + ss[3];
  sq = qs[0] + qs[1] + qs[2] + qs[3];
  const float mean = s * (1.f / D_);
  const float var  = sq * (1.f / D_) - mean * mean;
  const float rstd = rsqrtf(var + 1e-5f);
  const float4 gv = ((const float4*)g)[tid];
  const float4 bv = ((const float4*)bb)[tid];
  u16 o[4];
  o[0] = f2bf((v.x - mean) * rstd * gv.x + bv.x);
  o[1] = f2bf((v.y - mean) * rstd * gv.y + bv.y);
  o[2] = f2bf((v.z - mean) * rstd * gv.z + bv.z);
  o[3] = f2bf((v.w - mean) * rstd * gv.w + bv.w);
  *(ushort4*)(out + (size_t)row * D_ + tid * 4) = *(ushort4*)o;
}

// ---------------- GEMM 256x256, BK=64, 8 waves, counted-vmcnt pipeline + T2 swizzle.
// C[M,N] = act(A[M,K] * Bt[N,K]^T + bias); PARTIAL -> fp32 parts at z*M*N.
// Raw s_barrier (NO vmcnt drain) + s_waitcnt vmcnt(8): next tile's 8 loads stay
// in flight across the barrier; tile t's loads issued one full tile ahead.
template<int ACT, int BIAS, int OUTBF, int PARTIAL>
__global__ __launch_bounds__(512, 1) void gemm256(
    const u16* __restrict__ A, const u16* __restrict__ Bt,
    const float* __restrict__ bias, const float* resid,
    void* Cout, int M, int N, int K, int Kper) {
  // 2 dbuf x (256x64) x {A,B} bf16 = 128 KiB
  __shared__ __attribute__((aligned(16))) u16 LA[2][256 * 64];
  __shared__ __attribute__((aligned(16))) u16 LB[2][256 * 64];

  const int tid = threadIdx.x;
  const int wid = tid >> 6, lane = tid & 63;
  const int wr = wid >> 2, wc = wid & 3;       // wave -> 128x64 C block
  const int frow = lane & 15, hi = lane >> 4;  // fragment geometry

  const int gx = gridDim.x;
  const int nwg = gx * gridDim.y;
  const int orig = blockIdx.y * gx + blockIdx.x;
  const int cpx = nwg >> 3;
  const int swz = (orig & 7) * cpx + (orig >> 3);
  const int bm = (swz / gx) * 256, bn = (swz % gx) * 256;
  const int z = PARTIAL ? blockIdx.z : 0;
  const int koff = z * Kper;
  const int nt = Kper >> 6;

  const u16* Atile = A + (size_t)bm * K + koff;
  const u16* Btile = Bt + (size_t)bn * K + koff;

  // staging lane geometry: lane covers (row = 8*j..-block + lr, chunk lc),
  // global source pre-swizzled so linear LDS + swizzled read = st-swizzle
  const int lr = lane >> 3, lc = lane & 7;
  const int gch = lc ^ lr;

  f32x4 acc[8][4] = {};

  #define STAGE(kt, db)                                                          \
    {                                                                            \
      const u16* ga = Atile + (kt) * 64;                                         \
      const u16* gb = Btile + (kt) * 64;                                         \
      u16* la = &LA[db][0];                                                      \
      u16* lb = &LB[db][0];                                                      \
      _Pragma("unroll")                                                          \
      for (int j = 0; j < 4; j++) {                                              \
        const int rw = j * 64 + wid * 8;                                         \
        gload16(ga + (size_t)(rw + lr) * K + gch * 8, la + rw * 64);             \
        gload16(gb + (size_t)(rw + lr) * K + gch * 8, lb + rw * 64);             \
      }                                                                          \
    }

  STAGE(0, 0);

  for (int t = 0; t < nt; ++t) {
    if (t + 1 < nt) {
      STAGE(t + 1, (t + 1) & 1);
      asm volatile("s_waitcnt vmcnt(8)" ::: "memory");   // tile t landed; t+1 in flight
    } else {
      asm volatile("s_waitcnt vmcnt(0)" ::: "memory");
    }
    __builtin_amdgcn_s_barrier();

    const u16* Ab = &LA[t & 1][0];
    const u16* Bb = &LB[t & 1][0];

    bf16x8 bfr[4][2];
    #pragma unroll
    for (int ni = 0; ni < 4; ni++)
      #pragma unroll
      for (int ks = 0; ks < 2; ks++) {
        const int row = wc * 64 + ni * 16 + frow;
        bfr[ni][ks] = *(const bf16x8*)(Bb + row * 64 + (((ks * 4 + hi) ^ (row & 7)) << 3));
      }
    #pragma unroll
    for (int q = 0; q < 4; q++) {
      bf16x8 af[2][2];
      #pragma unroll
      for (int m2 = 0; m2 < 2; m2++)
        #pragma unroll
        for (int ks = 0; ks < 2; ks++) {
          const int row = wr * 128 + (q * 2 + m2) * 16 + frow;
          af[m2][ks] = *(const bf16x8*)(Ab + row * 64 + (((ks * 4 + hi) ^ (row & 7)) << 3));
        }
      __builtin_amdgcn_s_setprio(1);
      #pragma unroll
      for (int m2 = 0; m2 < 2; m2++)
        #pragma unroll
        for (int ni = 0; ni < 4; ni++)
          #pragma unroll
          for (int ks = 0; ks < 2; ks++)
            acc[q * 2 + m2][ni] =
                __builtin_amdgcn_mfma_f32_16x16x32_bf16(af[m2][ks], bfr[ni][ks],
                                                        acc[q * 2 + m2][ni], 0, 0, 0);
      __builtin_amdgcn_s_setprio(0);
    }
    __builtin_amdgcn_s_barrier();   // all waves done reading buf before it's re-staged
  }
  #undef STAGE

  const int r0 = bm + wr * 128 + hi * 4;
  const int c0 = bn + wc * 64 + frow;
  #pragma unroll
  for (int mi = 0; mi < 8; mi++) {
    #pragma unroll
    for (int ni = 0; ni < 4; ni++) {
      #pragma unroll
      for (int r = 0; r < 4; r++) {
        float v = acc[mi][ni][r];
        const int rr = r0 + mi * 16 + r;
        const int cc = c0 + ni * 16;
        if (PARTIAL) {
          ((float*)Cout)[((size_t)z * M + rr) * N + cc] = v;
        } else {
          if (BIAS) v += bias[cc];
          if (ACT == 1) v = 0.5f * v * (1.0f + erff(v * 0.70710678118f));
          if (resid) v += resid[(size_t)rr * N + cc];
          if (OUTBF) ((u16*)Cout)[(size_t)rr * N + cc] = f2bf(v);
          else       ((float*)Cout)[(size_t)rr * N + cc] = v;
        }
      }
    }
  }
}

// ---------------- split-K reduce: out = sum(parts) + bias (+resid), fp32
template<int NPART>
__global__ __launch_bounds__(256) void reduce_parts(
    const float* __restrict__ parts, const float* __restrict__ bias,
    const float* __restrict__ resid, float* __restrict__ out, int MN, int N) {
  const int i4 = (blockIdx.x * 256 + threadIdx.x) * 4;
  if (i4 >= MN) return;
  float4 s = *(const float4*)(parts + i4);
  #pragma unroll
  for (int p = 1; p < NPART; p++) {
    const float4 t = *(const float4*)(parts + (size_t)p * MN + i4);
    s.x += t.x; s.y += t.y; s.z += t.z; s.w += t.w;
  }
  const float4 bv = *(const float4*)(bias + (i4 & (N - 1)));
  const float4 rv = *(const float4*)(resid + i4);
  s.x += bv.x + rv.x; s.y += bv.y + rv.y; s.z += bv.z + rv.z; s.w += bv.w + rv.w;
  *(float4*)(out + i4) = s;
}

// ---------------- repack qkv [bt, 3*D] -> q,k [bh, T, 64] and v^T [bh, 64, T]
__global__ __launch_bounds__(256) void repack_qkv(const u16* __restrict__ qkv,
    u16* __restrict__ q, u16* __restrict__ k, u16* __restrict__ vt) {
  const int t0 = blockIdx.x * 64, bh = blockIdx.y;
  const int b = bh >> 4, h = bh & 15;
  const int tid = threadIdx.x;
  const int c = (tid & 7) * 8;
  __shared__ __attribute__((aligned(16))) u16 vs[64][72];
  #pragma unroll
  for (int p = 0; p < 2; p++) {
    const int tl = p * 32 + (tid >> 3);
    const size_t inrow = ((size_t)b * T_ + t0 + tl) * 3072 + h * 64;
    bf16x8 qv = *(const bf16x8*)(qkv + inrow + c);
    bf16x8 kv = *(const bf16x8*)(qkv + inrow + 1024 + c);
    bf16x8 vv = *(const bf16x8*)(qkv + inrow + 2048 + c);
    *(bf16x8*)(q + ((size_t)bh * T_ + t0 + tl) * HD_ + c) = qv;
    *(bf16x8*)(k + ((size_t)bh * T_ + t0 + tl) * HD_ + c) = kv;
    *(bf16x8*)&vs[tl][c] = vv;
  }
  __syncthreads();
  const int d = tid >> 2, tc = (tid & 3) * 16;
  alignas(16) u16 tmp[16];
  #pragma unroll
  for (int j = 0; j < 16; j++) tmp[j] = vs[tc + j][d];
  *(bf16x8*)(vt + ((size_t)bh * HD_ + d) * T_ + t0 + tc)     = *(bf16x8*)&tmp[0];
  *(bf16x8*)(vt + ((size_t)bh * HD_ + d) * T_ + t0 + tc + 8) = *(bf16x8*)&tmp[8];
}

// ---------------- flash attention v3 (XCD-locality, ones-column l, defer-max)
__global__ __launch_bounds__(256) void attn_fwd(
    const u16* __restrict__ q, const u16* __restrict__ k,
    const u16* __restrict__ vt, u16* __restrict__ out) {
  __shared__ __attribute__((aligned(16))) u16 Ps[4][16 * 64];
  __shared__ __attribute__((aligned(16))) u16 Kb[2][64 * 64];
  __shared__ __attribute__((aligned(16))) u16 Vb[2][64 * 64];

  const int bid = blockIdx.x;
  const int xcd = bid & 7, j = bid >> 3;     // j = 0..127
  const int bh  = xcd + 8 * (j & 3);         // 4 bh per xcd -> 2MB K/V, L2-resident
  const int qt  = 31 - (j >> 2);             // large qt dispatched first
  const int b = bh >> 4, h = bh & 15;
  const int tid = threadIdx.x, wid = tid >> 6, lane = tid & 63;
  const u16* kh = k  + (size_t)bh * T_ * HD_;
  const u16* vh = vt + (size_t)bh * HD_ * T_;
  const int q0 = qt * 64;

  const int frow = lane & 15;
  const int hi   = lane >> 4;
  const int fk   = hi * 8;
  const int rowb = hi * 4;
  const int colb = frow;

  const int srl = lane >> 3;
  const int scs = (lane & 7) ^ srl;

  const float SCL2 = 0.18033688011112042f;  // 0.125 * log2(e)

  const u16* qrow = q + ((size_t)bh * T_ + q0 + wid * 16 + frow) * HD_;
  bf16x8 aq[2];
  aq[0] = *(const bf16x8*)(qrow + fk);
  aq[1] = *(const bf16x8*)(qrow + 32 + fk);

  u16x8 onebits = (u16x8)((u16)0x3F80);
  bf16x8 b_one = (frow == 0) ? __builtin_bit_cast(bf16x8, onebits) : (bf16x8){};

  float m2[4] = {-3e38f, -3e38f, -3e38f, -3e38f};
  f32x4 acc_l = {};
  f32x4 acc_o[4] = {};

  u16* Pw = &Ps[wid][0];

  int cur = 0;
  #pragma unroll
  for (int jj = 0; jj < 2; ++jj) {
    const int row = wid * 16 + jj * 8 + srl;
    gload16(kh + (size_t)row * HD_ + scs * 8,  &Kb[0][(wid * 16 + jj * 8) * 64]);
    gload16(vh + (size_t)row * T_ + scs * 8,   &Vb[0][(wid * 16 + jj * 8) * 64]);
  }
  __syncthreads();

  for (int kt = 0; kt <= qt; ++kt) {
    if (kt < qt) {
      const int nx = cur ^ 1, ktn = kt + 1;
      #pragma unroll
      for (int jj = 0; jj < 2; ++jj) {
        const int row = wid * 16 + jj * 8 + srl;
        gload16(kh + (size_t)(ktn * 64 + row) * HD_ + scs * 8, &Kb[nx][(wid * 16 + jj * 8) * 64]);
        gload16(vh + (size_t)row * T_ + ktn * 64 + scs * 8,    &Vb[nx][(wid * 16 + jj * 8) * 64]);
      }
    }

    const u16* Kc = &Kb[cur][0];
    const u16* Vc = &Vb[cur][0];

    float p2[4][4];
    __builtin_amdgcn_s_setprio(1);
    #pragma unroll
    for (int ni = 0; ni < 4; ni++) {
      f32x4 s = {};
      #pragma unroll
      for (int ks = 0; ks < 2; ks++) {
        const int row = ni * 16 + frow;
        const int ch  = ks * 4 + hi;
        bf16x8 bk = *(const bf16x8*)(Kc + row * 64 + ((ch ^ (row & 7)) << 3));
        s = __builtin_amdgcn_mfma_f32_16x16x32_bf16(aq[ks], bk, s, 0, 0, 0);
      }
      #pragma unroll
      for (int r = 0; r < 4; r++) {
        const bool msk = (kt == qt) && (ni * 16 + colb) > (wid * 16 + rowb + r);
        p2[ni][r] = msk ? -3e38f : s[r] * SCL2;
      }
    }
    __builtin_amdgcn_s_setprio(0);

    float pmax[4];
    #pragma unroll
    for (int r = 0; r < 4; r++) {
      float rm = fmaxf(fmaxf(p2[0][r], p2[1][r]), fmaxf(p2[2][r], p2[3][r]));
      rm = fmaxf(rm, __shfl_xor(rm, 1));
      rm = fmaxf(rm, __shfl_xor(rm, 2));
      rm = fmaxf(rm, __shfl_xor(rm, 4));
      rm = fmaxf(rm, __shfl_xor(rm, 8));
      pmax[r] = rm;
    }
    int ok = 1;
    #pragma unroll
    for (int r = 0; r < 4; r++) ok &= (pmax[r] <= m2[r] + 8.0f);
    if (!__all(ok)) {
      #pragma unroll
      for (int r = 0; r < 4; r++) {
        const float mnew = fmaxf(m2[r], pmax[r]);
        const float corr = exp2f(m2[r] - mnew);
        m2[r] = mnew;
        acc_l[r] *= corr;
        #pragma unroll
        for (int ni = 0; ni < 4; ni++) acc_o[ni][r] *= corr;
      }
    }
    #pragma unroll
    for (int ni = 0; ni < 4; ni++)
      #pragma unroll
      for (int r = 0; r < 4; r++) p2[ni][r] = exp2f(p2[ni][r] - m2[r]);

    #pragma unroll
    for (int ni = 0; ni < 4; ni++) {
      #pragma unroll
      for (int r = 0; r < 4; r++) {
        const int lrw = rowb + r;
        const int ch = ni * 2 + (colb >> 3);
        Pw[lrw * 64 + ((ch ^ (lrw & 7)) << 3) + (colb & 7)] = f2bf(p2[ni][r]);
      }
    }
    bf16x8 ap[2];
    {
      const int c0 = (0 * 4 + hi) ^ (frow & 7);
      const int c1 = (1 * 4 + hi) ^ (frow & 7);
      ap[0] = *(const bf16x8*)(Pw + frow * 64 + (c0 << 3));
      ap[1] = *(const bf16x8*)(Pw + frow * 64 + (c1 << 3));
    }

    __builtin_amdgcn_s_setprio(1);
    #pragma unroll
    for (int ks = 0; ks < 2; ks++)
      acc_l = __builtin_amdgcn_mfma_f32_16x16x32_bf16(ap[ks], b_one, acc_l, 0, 0, 0);
    #pragma unroll
    for (int ni = 0; ni < 4; ni++) {
      #pragma unroll
      for (int ks = 0; ks < 2; ks++) {
        const int row = ni * 16 + frow;
        const int ch  = ks * 4 + hi;
        bf16x8 bv = *(const bf16x8*)(Vc + row * 64 + ((ch ^ (row & 7)) << 3));
        acc_o[ni] = __builtin_amdgcn_mfma_f32_16x16x32_bf16(ap[ks], bv, acc_o[ni], 0, 0, 0);
      }
    }
    __builtin_amdgcn_s_setprio(0);

    __syncthreads();
    cur ^= 1;
  }

  float linv[4];
  #pragma unroll
  for (int r = 0; r < 4; r++) {
    const float lv = __shfl(acc_l[r], lane & 48);
    linv[r] = 1.0f / lv;
  }
  #pragma unroll
  for (int ni = 0; ni < 4; ni++)
    #pragma unroll
    for (int r = 0; r < 4; r++) {
      const float ov = acc_o[ni][r] * linv[r];
      const size_t row = (size_t)b * T_ + q0 + wid * 16 + rowb + r;
      out[row * D_ + h * HD_ + ni * 16 + colb] = f2bf(ov);
    }
}

extern "C" void kernel_launch(void* const* d_in, const int* in_sizes, int n_in,
                              void* d_out, int out_size, void* d_ws, size_t ws_size,
                              hipStream_t stream) {
  (void)in_sizes; (void)n_in; (void)out_size; (void)ws_size;
  const float* x      = (const float*)d_in[0];
  const float* wq     = (const float*)d_in[1];
  const float* wk     = (const float*)d_in[2];
  const float* wv     = (const float*)d_in[3];
  const float* w_proj = (const float*)d_in[4];
  const float* b_proj = (const float*)d_in[5];
  const float* ln1_g  = (const float*)d_in[6];
  const float* ln1_b  = (const float*)d_in[7];
  const float* ln2_g  = (const float*)d_in[8];
  const float* ln2_b  = (const float*)d_in[9];
  const float* w1     = (const float*)d_in[10];
  const float* b1     = (const float*)d_in[11];
  const float* w2     = (const float*)d_in[12];
  const float* b2     = (const float*)d_in[13];

  uint8_t* ws = (uint8_t*)d_ws;
  const size_t MB = 1024 * 1024;
  u16* wqkv_t = (u16*)(ws + 0);        // [3072,1024]
  u16* wproj_t = (u16*)(ws + 6 * MB);  // [1024,1024]
  u16* w1t  = (u16*)(ws + 8 * MB);     // [4096,1024]
  u16* w2t  = (u16*)(ws + 16 * MB);    // [1024,4096]
  u16* hbuf = (u16*)(ws + 24 * MB);    // [4096,1024]
  u16* qkv  = (u16*)(ws + 32 * MB);    // [4096,3072]  (dead after repack)
  u16* qb   = (u16*)(ws + 56 * MB);    // [32,2048,64] (dead after attn)
  u16* kb   = (u16*)(ws + 64 * MB);    // (dead after attn)
  u16* vtb  = (u16*)(ws + 72 * MB);    // (dead after attn)
  u16* aout = (u16*)(ws + 80 * MB);    // [4096,1024]
  u16* h2   = (u16*)(ws + 88 * MB);    // [4096,1024]
  u16* ff1  = (u16*)(ws + 96 * MB);    // [4096,4096]
  float* pparts = (float*)(ws + 32 * MB);  // proj: 2 x [4096,1024] fp32 = 32 MB
  float* fparts = (float*)(ws + 32 * MB);  // ff2:  4 x [4096,1024] fp32 = 64 MB
  float* xout = (float*)d_out;

  const dim3 tb(32, 8);
  transpose_w<<<dim3(HD_/32, D_/32, H_), tb, 0, stream>>>(wq, wqkv_t, D_, HD_);
  transpose_w<<<dim3(HD_/32, D_/32, H_), tb, 0, stream>>>(wk, wqkv_t + (size_t)D_*D_, D_, HD_);
  transpose_w<<<dim3(HD_/32, D_/32, H_), tb, 0, stream>>>(wv, wqkv_t + 2*(size_t)D_*D_, D_, HD_);
  transpose_w<<<dim3(D_/32, D_/32, 1),  tb, 0, stream>>>(w_proj, wproj_t, D_, D_);
  transpose_w<<<dim3(FF_/32, D_/32, 1), tb, 0, stream>>>(w1, w1t, D_, FF_);
  transpose_w<<<dim3(D_/32, FF_/32, 1), tb, 0, stream>>>(w2, w2t, FF_, D_);

  ln_rows<<<BT_, 256, 0, stream>>>(x, ln1_g, ln1_b, hbuf);

  // QKV: [4096,1024] x [3072,1024]^T -> bf16 [4096,3072]
  gemm256<0,0,1,0><<<dim3(3072/256, BT_/256), 512, 0, stream>>>(
      hbuf, wqkv_t, nullptr, nullptr, qkv, BT_, 3072, D_, D_);

  repack_qkv<<<dim3(T_/64, B_*H_), 256, 0, stream>>>(qkv, qb, kb, vtb);

  attn_fwd<<<dim3(NT_ * B_ * H_), 256, 0, stream>>>(qb, kb, vtb, aout);

  // proj: split-K=2 partials + fused reduce (bias + x residual) -> xout (fp32)
  gemm256<0,0,0,1><<<dim3(D_/256, BT_/256, 2), 512, 0, stream>>>(
      aout, wproj_t, nullptr, nullptr, pparts, BT_, D_, D_, D_/2);
  reduce_parts<2><<<(BT_*D_)/1024, 256, 0, stream>>>(
      pparts, b_proj, x, xout, BT_*D_, D_);

  ln_rows<<<BT_, 256, 0, stream>>>(xout, ln2_g, ln2_b, h2);

  // FF1: [4096,1024] x [4096,1024]^T -> GELU -> bf16 [4096,4096]
  gemm256<1,1,1,0><<<dim3(FF_/256, BT_/256), 512, 0, stream>>>(
      h2, w1t, b1, nullptr, ff1, BT_, FF_, D_, D_);

  // FF2: split-K=4 partials + fused reduce (bias + xout residual) -> xout in place
  gemm256<0,0,0,1><<<dim3(D_/256, BT_/256, 4), 512, 0, stream>>>(
      ff1, w2t, nullptr, nullptr, fparts, BT_, D_, FF_, FF_/4);
  reduce_parts<4><<<(BT_*D_)/1024, 256, 0, stream>>>(
      fparts, b2, xout, xout, BT_*D_, D_);
}

// Round 8
// 290.817 us; speedup vs baseline: 1.3959x; 1.0224x over previous
//
#include <hip/hip_runtime.h>
#include <hip/hip_bf16.h>
#include <cstdint>
#include <cstddef>
#include <math.h>

#define D_ 1024
#define H_ 16
#define HD_ 64
#define T_ 2048
#define B_ 2
#define FF_ 4096
#define BT_ (B_*T_)   // 4096 rows
#define NT_ 32        // T_/64 kv tiles

typedef unsigned short u16;
typedef __attribute__((ext_vector_type(8))) __bf16 bf16x8;
typedef __attribute__((ext_vector_type(8))) u16 u16x8;
typedef __attribute__((ext_vector_type(4))) float f32x4;

__device__ __forceinline__ u16 f2bf(float f) {
  unsigned u = __builtin_bit_cast(unsigned, f);
  u += 0x7FFFu + ((u >> 16) & 1u);
  return (u16)(u >> 16);
}

__device__ __forceinline__ unsigned cvt_pk_bf16(float a, float b) {
  unsigned r;
  asm("v_cvt_pk_bf16_f32 %0, %1, %2" : "=v"(r) : "v"(a), "v"(b));
  return r;
}

__device__ __forceinline__ void gload16(const void* g, void* l) {
  __builtin_amdgcn_global_load_lds((__attribute__((address_space(1))) void*)g,
                                   (__attribute__((address_space(3))) void*)l, 16, 0, 0);
}

// ---------------- transpose + fp32->bf16 cast:  out[(z*C+c)*R + r] = in[z*R*C + r*C + c]
__global__ __launch_bounds__(256) void transpose_w(const float* __restrict__ in,
                                                   u16* __restrict__ out, int R, int C) {
  __shared__ float tile[32][33];
  const int z = blockIdx.z;
  const float* inz = in + (size_t)z * R * C;
  const int x = blockIdx.x * 32 + threadIdx.x;
  const int y0 = blockIdx.y * 32 + threadIdx.y;
  #pragma unroll
  for (int j = 0; j < 32; j += 8)
    tile[threadIdx.y + j][threadIdx.x] = inz[(size_t)(y0 + j) * C + x];
  __syncthreads();
  const int orr = blockIdx.y * 32 + threadIdx.x;
  const int oc0 = blockIdx.x * 32 + threadIdx.y;
  u16* outz = out + (size_t)z * C * R;
  #pragma unroll
  for (int j = 0; j < 32; j += 8)
    outz[(size_t)(oc0 + j) * R + orr] = f2bf(tile[threadIdx.x][threadIdx.y + j]);
}

// ---------------- LayerNorm (fp32 in -> bf16 out), one row (D=1024) per block of 256
__global__ __launch_bounds__(256) void ln_rows(const float* __restrict__ x,
    const float* __restrict__ g, const float* __restrict__ bb, u16* __restrict__ out) {
  const int row = blockIdx.x, tid = threadIdx.x;
  const float4 v = ((const float4*)(x + (size_t)row * D_))[tid];
  float s = v.x + v.y + v.z + v.w;
  float sq = v.x*v.x + v.y*v.y + v.z*v.z + v.w*v.w;
  #pragma unroll
  for (int m = 1; m < 64; m <<= 1) { s += __shfl_xor(s, m); sq += __shfl_xor(sq, m); }
  __shared__ float ss[4], qs[4];
  if ((tid & 63) == 0) { ss[tid >> 6] = s; qs[tid >> 6] = sq; }
  __syncthreads();
  s  = ss[0] + ss[1] + ss[2] + ss[3];
  sq = qs[0] + qs[1] + qs[2] + qs[3];
  const float mean = s * (1.f / D_);
  const float var  = sq * (1.f / D_) - mean * mean;
  const float rstd = rsqrtf(var + 1e-5f);
  const float4 gv = ((const float4*)g)[tid];
  const float4 bv = ((const float4*)bb)[tid];
  u16 o[4];
  o[0] = f2bf((v.x - mean) * rstd * gv.x + bv.x);
  o[1] = f2bf((v.y - mean) * rstd * gv.y + bv.y);
  o[2] = f2bf((v.z - mean) * rstd * gv.z + bv.z);
  o[3] = f2bf((v.w - mean) * rstd * gv.w + bv.w);
  *(ushort4*)(out + (size_t)row * D_ + tid * 4) = *(ushort4*)o;
}

// ---------------- GEMM 256x256, BK=64, 8 waves, counted-vmcnt pipeline + T2 swizzle.
template<int ACT, int BIAS, int OUTBF, int PARTIAL>
__global__ __launch_bounds__(512, 1) void gemm256(
    const u16* __restrict__ A, const u16* __restrict__ Bt,
    const float* __restrict__ bias, const float* resid,
    void* Cout, int M, int N, int K, int Kper) {
  __shared__ __attribute__((aligned(16))) u16 LA[2][256 * 64];
  __shared__ __attribute__((aligned(16))) u16 LB[2][256 * 64];

  const int tid = threadIdx.x;
  const int wid = tid >> 6, lane = tid & 63;
  const int wr = wid >> 2, wc = wid & 3;
  const int frow = lane & 15, hi = lane >> 4;

  const int gx = gridDim.x;
  const int nwg = gx * gridDim.y;
  const int orig = blockIdx.y * gx + blockIdx.x;
  const int cpx = nwg >> 3;
  const int swz = (orig & 7) * cpx + (orig >> 3);
  const int bm = (swz / gx) * 256, bn = (swz % gx) * 256;
  const int z = PARTIAL ? blockIdx.z : 0;
  const int koff = z * Kper;
  const int nt = Kper >> 6;

  const u16* Atile = A + (size_t)bm * K + koff;
  const u16* Btile = Bt + (size_t)bn * K + koff;

  const int lr = lane >> 3, lc = lane & 7;
  const int gch = lc ^ lr;

  f32x4 acc[8][4] = {};

  #define STAGE(kt, db)                                                          \
    {                                                                            \
      const u16* ga = Atile + (kt) * 64;                                         \
      const u16* gb = Btile + (kt) * 64;                                         \
      u16* la = &LA[db][0];                                                      \
      u16* lb = &LB[db][0];                                                      \
      _Pragma("unroll")                                                          \
      for (int j = 0; j < 4; j++) {                                              \
        const int rw = j * 64 + wid * 8;                                         \
        gload16(ga + (size_t)(rw + lr) * K + gch * 8, la + rw * 64);             \
        gload16(gb + (size_t)(rw + lr) * K + gch * 8, lb + rw * 64);             \
      }                                                                          \
    }

  STAGE(0, 0);

  for (int t = 0; t < nt; ++t) {
    if (t + 1 < nt) {
      STAGE(t + 1, (t + 1) & 1);
      asm volatile("s_waitcnt vmcnt(8)" ::: "memory");
    } else {
      asm volatile("s_waitcnt vmcnt(0)" ::: "memory");
    }
    __builtin_amdgcn_s_barrier();

    const u16* Ab = &LA[t & 1][0];
    const u16* Bb = &LB[t & 1][0];

    bf16x8 bfr[4][2];
    #pragma unroll
    for (int ni = 0; ni < 4; ni++)
      #pragma unroll
      for (int ks = 0; ks < 2; ks++) {
        const int row = wc * 64 + ni * 16 + frow;
        bfr[ni][ks] = *(const bf16x8*)(Bb + row * 64 + (((ks * 4 + hi) ^ (row & 7)) << 3));
      }
    #pragma unroll
    for (int q = 0; q < 4; q++) {
      bf16x8 af[2][2];
      #pragma unroll
      for (int m2 = 0; m2 < 2; m2++)
        #pragma unroll
        for (int ks = 0; ks < 2; ks++) {
          const int row = wr * 128 + (q * 2 + m2) * 16 + frow;
          af[m2][ks] = *(const bf16x8*)(Ab + row * 64 + (((ks * 4 + hi) ^ (row & 7)) << 3));
        }
      __builtin_amdgcn_s_setprio(1);
      #pragma unroll
      for (int m2 = 0; m2 < 2; m2++)
        #pragma unroll
        for (int ni = 0; ni < 4; ni++)
          #pragma unroll
          for (int ks = 0; ks < 2; ks++)
            acc[q * 2 + m2][ni] =
                __builtin_amdgcn_mfma_f32_16x16x32_bf16(af[m2][ks], bfr[ni][ks],
                                                        acc[q * 2 + m2][ni], 0, 0, 0);
      __builtin_amdgcn_s_setprio(0);
    }
    __builtin_amdgcn_s_barrier();
  }
  #undef STAGE

  const int r0 = bm + wr * 128 + hi * 4;
  const int c0 = bn + wc * 64 + frow;
  #pragma unroll
  for (int mi = 0; mi < 8; mi++) {
    #pragma unroll
    for (int ni = 0; ni < 4; ni++) {
      #pragma unroll
      for (int r = 0; r < 4; r++) {
        float v = acc[mi][ni][r];
        const int rr = r0 + mi * 16 + r;
        const int cc = c0 + ni * 16;
        if (PARTIAL) {
          ((float*)Cout)[((size_t)z * M + rr) * N + cc] = v;
        } else {
          if (BIAS) v += bias[cc];
          if (ACT == 1) v = 0.5f * v * (1.0f + erff(v * 0.70710678118f));
          if (resid) v += resid[(size_t)rr * N + cc];
          if (OUTBF) ((u16*)Cout)[(size_t)rr * N + cc] = f2bf(v);
          else       ((float*)Cout)[(size_t)rr * N + cc] = v;
        }
      }
    }
  }
}

// ---------------- split-K reduce: out = sum(parts) + bias (+resid), fp32
template<int NPART>
__global__ __launch_bounds__(256) void reduce_parts(
    const float* __restrict__ parts, const float* __restrict__ bias,
    const float* __restrict__ resid, float* __restrict__ out, int MN, int N) {
  const int i4 = (blockIdx.x * 256 + threadIdx.x) * 4;
  if (i4 >= MN) return;
  float4 s = *(const float4*)(parts + i4);
  #pragma unroll
  for (int p = 1; p < NPART; p++) {
    const float4 t = *(const float4*)(parts + (size_t)p * MN + i4);
    s.x += t.x; s.y += t.y; s.z += t.z; s.w += t.w;
  }
  const float4 bv = *(const float4*)(bias + (i4 & (N - 1)));
  const float4 rv = *(const float4*)(resid + i4);
  s.x += bv.x + rv.x; s.y += bv.y + rv.y; s.z += bv.z + rv.z; s.w += bv.w + rv.w;
  *(float4*)(out + i4) = s;
}

// ---------------- repack qkv [bt, 3*D] -> q(SCALED),k [bh, T, 64] and v^T [bh, 64, T]
// q is pre-scaled by 0.125*log2(e) so attention softmax runs in exp2 domain
// with no per-element scale-mul in the inner loop.
__global__ __launch_bounds__(256) void repack_qkv(const u16* __restrict__ qkv,
    u16* __restrict__ q, u16* __restrict__ k, u16* __restrict__ vt) {
  const int t0 = blockIdx.x * 64, bh = blockIdx.y;
  const int b = bh >> 4, h = bh & 15;
  const int tid = threadIdx.x;
  const int c = (tid & 7) * 8;
  __shared__ __attribute__((aligned(16))) u16 vs[64][72];
  #pragma unroll
  for (int p = 0; p < 2; p++) {
    const int tl = p * 32 + (tid >> 3);
    const size_t inrow = ((size_t)b * T_ + t0 + tl) * 3072 + h * 64;
    u16x8 qv = *(const u16x8*)(qkv + inrow + c);
    bf16x8 kv = *(const bf16x8*)(qkv + inrow + 1024 + c);
    bf16x8 vv = *(const bf16x8*)(qkv + inrow + 2048 + c);
    alignas(16) u16 qs[8];
    #pragma unroll
    for (int e = 0; e < 8; e++) {
      const float f = __builtin_bit_cast(float, ((unsigned)qv[e]) << 16) * 0.18033688011112042f;
      qs[e] = f2bf(f);
    }
    *(u16x8*)(q + ((size_t)bh * T_ + t0 + tl) * HD_ + c) = *(u16x8*)qs;
    *(bf16x8*)(k + ((size_t)bh * T_ + t0 + tl) * HD_ + c) = kv;
    *(bf16x8*)&vs[tl][c] = vv;
  }
  __syncthreads();
  const int d = tid >> 2, tc = (tid & 3) * 16;
  alignas(16) u16 tmp[16];
  #pragma unroll
  for (int j = 0; j < 16; j++) tmp[j] = vs[tc + j][d];
  *(bf16x8*)(vt + ((size_t)bh * HD_ + d) * T_ + t0 + tc)     = *(bf16x8*)&tmp[0];
  *(bf16x8*)(vt + ((size_t)bh * HD_ + d) * T_ + t0 + tc + 8) = *(bf16x8*)&tmp[8];
}

// ---------------- flash attention v4: equal-work paired q-tiles (qp, 31-qp),
// XCD-bh locality, ones-column l, defer-max, cvt_pk P conversion.
__global__ __launch_bounds__(256) void attn_fwd(
    const u16* __restrict__ q, const u16* __restrict__ k,
    const u16* __restrict__ vt, u16* __restrict__ out) {
  __shared__ __attribute__((aligned(16))) u16 Ps[4][16 * 64];
  __shared__ __attribute__((aligned(16))) u16 Kb[2][64 * 64];
  __shared__ __attribute__((aligned(16))) u16 Vb[2][64 * 64];

  const int bid = blockIdx.x;                // 512 blocks
  const int xcd = bid & 7, j = bid >> 3;     // j = 0..63
  const int bh  = xcd + 8 * (j & 3);         // 4 bh per xcd -> 2MB K/V, L2-resident
  const int qp  = j >> 2;                    // 0..15 -> this block does q-tiles {qp, 31-qp}
  const int b = bh >> 4, h = bh & 15;
  const int tid = threadIdx.x, wid = tid >> 6, lane = tid & 63;
  const u16* kh = k  + (size_t)bh * T_ * HD_;
  const u16* vh = vt + (size_t)bh * HD_ * T_;

  const int frow = lane & 15;
  const int hi   = lane >> 4;
  const int fk   = hi * 8;
  const int rowb = hi * 4;
  const int colb = frow;
  const int srl = lane >> 3;
  const int scs = (lane & 7) ^ srl;

  u16x8 onebits = (u16x8)((u16)0x3F80);
  bf16x8 b_one = (frow == 0) ? __builtin_bit_cast(bf16x8, onebits) : (bf16x8){};

  u16* Pw = &Ps[wid][0];

  for (int qi = 0; qi < 2; ++qi) {
    const int qt = qi ? (NT_ - 1 - qp) : qp;
    const int q0 = qt * 64;

    const u16* qrow = q + ((size_t)bh * T_ + q0 + wid * 16 + frow) * HD_;
    bf16x8 aq[2];
    aq[0] = *(const bf16x8*)(qrow + fk);
    aq[1] = *(const bf16x8*)(qrow + 32 + fk);

    float m2[4] = {-3e38f, -3e38f, -3e38f, -3e38f};
    f32x4 acc_l = {};
    f32x4 acc_o[4] = {};

    int cur = 0;
    #pragma unroll
    for (int jj = 0; jj < 2; ++jj) {
      const int row = wid * 16 + jj * 8 + srl;
      gload16(kh + (size_t)row * HD_ + scs * 8,  &Kb[0][(wid * 16 + jj * 8) * 64]);
      gload16(vh + (size_t)row * T_ + scs * 8,   &Vb[0][(wid * 16 + jj * 8) * 64]);
    }
    __syncthreads();

    for (int kt = 0; kt <= qt; ++kt) {
      if (kt < qt) {
        const int nx = cur ^ 1, ktn = kt + 1;
        #pragma unroll
        for (int jj = 0; jj < 2; ++jj) {
          const int row = wid * 16 + jj * 8 + srl;
          gload16(kh + (size_t)(ktn * 64 + row) * HD_ + scs * 8, &Kb[nx][(wid * 16 + jj * 8) * 64]);
          gload16(vh + (size_t)row * T_ + ktn * 64 + scs * 8,    &Vb[nx][(wid * 16 + jj * 8) * 64]);
        }
      }

      const u16* Kc = &Kb[cur][0];
      const u16* Vc = &Vb[cur][0];

      float p2[4][4];
      __builtin_amdgcn_s_setprio(1);
      #pragma unroll
      for (int ni = 0; ni < 4; ni++) {
        f32x4 s = {};
        #pragma unroll
        for (int ks = 0; ks < 2; ks++) {
          const int row = ni * 16 + frow;
          const int ch  = ks * 4 + hi;
          bf16x8 bk = *(const bf16x8*)(Kc + row * 64 + ((ch ^ (row & 7)) << 3));
          s = __builtin_amdgcn_mfma_f32_16x16x32_bf16(aq[ks], bk, s, 0, 0, 0);
        }
        #pragma unroll
        for (int r = 0; r < 4; r++) {
          const bool msk = (kt == qt) && (ni * 16 + colb) > (wid * 16 + rowb + r);
          p2[ni][r] = msk ? -3e38f : s[r];
        }
      }
      __builtin_amdgcn_s_setprio(0);

      float pmax[4];
      #pragma unroll
      for (int r = 0; r < 4; r++) {
        float rm = fmaxf(fmaxf(p2[0][r], p2[1][r]), fmaxf(p2[2][r], p2[3][r]));
        rm = fmaxf(rm, __shfl_xor(rm, 1));
        rm = fmaxf(rm, __shfl_xor(rm, 2));
        rm = fmaxf(rm, __shfl_xor(rm, 4));
        rm = fmaxf(rm, __shfl_xor(rm, 8));
        pmax[r] = rm;
      }
      int ok = 1;
      #pragma unroll
      for (int r = 0; r < 4; r++) ok &= (pmax[r] <= m2[r] + 8.0f);
      if (!__all(ok)) {
        #pragma unroll
        for (int r = 0; r < 4; r++) {
          const float mnew = fmaxf(m2[r], pmax[r]);
          const float corr = exp2f(m2[r] - mnew);
          m2[r] = mnew;
          acc_l[r] *= corr;
          #pragma unroll
          for (int ni = 0; ni < 4; ni++) acc_o[ni][r] *= corr;
        }
      }
      #pragma unroll
      for (int ni = 0; ni < 4; ni++)
        #pragma unroll
        for (int r = 0; r < 4; r++) p2[ni][r] = exp2f(p2[ni][r] - m2[r]);

      #pragma unroll
      for (int ni = 0; ni < 4; ni++) {
        #pragma unroll
        for (int r = 0; r < 4; r += 2) {
          const unsigned pk = cvt_pk_bf16(p2[ni][r], p2[ni][r + 1]);
          const int lr0 = rowb + r, lr1 = rowb + r + 1;
          const int ch = ni * 2 + (colb >> 3);
          Pw[lr0 * 64 + ((ch ^ (lr0 & 7)) << 3) + (colb & 7)] = (u16)pk;
          Pw[lr1 * 64 + ((ch ^ (lr1 & 7)) << 3) + (colb & 7)] = (u16)(pk >> 16);
        }
      }
      bf16x8 ap[2];
      {
        const int c0 = (0 * 4 + hi) ^ (frow & 7);
        const int c1 = (1 * 4 + hi) ^ (frow & 7);
        ap[0] = *(const bf16x8*)(Pw + frow * 64 + (c0 << 3));
        ap[1] = *(const bf16x8*)(Pw + frow * 64 + (c1 << 3));
      }

      __builtin_amdgcn_s_setprio(1);
      #pragma unroll
      for (int ks = 0; ks < 2; ks++)
        acc_l = __builtin_amdgcn_mfma_f32_16x16x32_bf16(ap[ks], b_one, acc_l, 0, 0, 0);
      #pragma unroll
      for (int ni = 0; ni < 4; ni++) {
        #pragma unroll
        for (int ks = 0; ks < 2; ks++) {
          const int row = ni * 16 + frow;
          const int ch  = ks * 4 + hi;
          bf16x8 bv = *(const bf16x8*)(Vc + row * 64 + ((ch ^ (row & 7)) << 3));
          acc_o[ni] = __builtin_amdgcn_mfma_f32_16x16x32_bf16(ap[ks], bv, acc_o[ni], 0, 0, 0);
        }
      }
      __builtin_amdgcn_s_setprio(0);

      __syncthreads();
      cur ^= 1;
    }

    float linv[4];
    #pragma unroll
    for (int r = 0; r < 4; r++) {
      const float lv = __shfl(acc_l[r], lane & 48);
      linv[r] = 1.0f / lv;
    }
    #pragma unroll
    for (int ni = 0; ni < 4; ni++)
      #pragma unroll
      for (int r = 0; r < 4; r++) {
        const float ov = acc_o[ni][r] * linv[r];
        const size_t row = (size_t)b * T_ + q0 + wid * 16 + rowb + r;
        out[row * D_ + h * HD_ + ni * 16 + colb] = f2bf(ov);
      }
  }
}

extern "C" void kernel_launch(void* const* d_in, const int* in_sizes, int n_in,
                              void* d_out, int out_size, void* d_ws, size_t ws_size,
                              hipStream_t stream) {
  (void)in_sizes; (void)n_in; (void)out_size; (void)ws_size;
  const float* x      = (const float*)d_in[0];
  const float* wq     = (const float*)d_in[1];
  const float* wk     = (const float*)d_in[2];
  const float* wv     = (const float*)d_in[3];
  const float* w_proj = (const float*)d_in[4];
  const float* b_proj = (const float*)d_in[5];
  const float* ln1_g  = (const float*)d_in[6];
  const float* ln1_b  = (const float*)d_in[7];
  const float* ln2_g  = (const float*)d_in[8];
  const float* ln2_b  = (const float*)d_in[9];
  const float* w1     = (const float*)d_in[10];
  const float* b1     = (const float*)d_in[11];
  const float* w2     = (const float*)d_in[12];
  const float* b2     = (const float*)d_in[13];

  uint8_t* ws = (uint8_t*)d_ws;
  const size_t MB = 1024 * 1024;
  u16* wqkv_t = (u16*)(ws + 0);        // [3072,1024]
  u16* wproj_t = (u16*)(ws + 6 * MB);  // [1024,1024]
  u16* w1t  = (u16*)(ws + 8 * MB);     // [4096,1024]
  u16* w2t  = (u16*)(ws + 16 * MB);    // [1024,4096]
  u16* hbuf = (u16*)(ws + 24 * MB);    // [4096,1024]
  u16* qkv  = (u16*)(ws + 32 * MB);    // [4096,3072]  (dead after repack)
  u16* qb   = (u16*)(ws + 56 * MB);    // [32,2048,64] (dead after attn)
  u16* kb   = (u16*)(ws + 64 * MB);    // (dead after attn)
  u16* vtb  = (u16*)(ws + 72 * MB);    // (dead after attn)
  u16* aout = (u16*)(ws + 80 * MB);    // [4096,1024]
  u16* h2   = (u16*)(ws + 88 * MB);    // [4096,1024]
  u16* ff1  = (u16*)(ws + 96 * MB);    // [4096,4096]
  float* pparts = (float*)(ws + 32 * MB);  // proj: 2 x [4096,1024] fp32 = 32 MB
  float* fparts = (float*)(ws + 32 * MB);  // ff2:  4 x [4096,1024] fp32 = 64 MB
  float* xout = (float*)d_out;

  const dim3 tb(32, 8);
  transpose_w<<<dim3(HD_/32, D_/32, H_), tb, 0, stream>>>(wq, wqkv_t, D_, HD_);
  transpose_w<<<dim3(HD_/32, D_/32, H_), tb, 0, stream>>>(wk, wqkv_t + (size_t)D_*D_, D_, HD_);
  transpose_w<<<dim3(HD_/32, D_/32, H_), tb, 0, stream>>>(wv, wqkv_t + 2*(size_t)D_*D_, D_, HD_);
  transpose_w<<<dim3(D_/32, D_/32, 1),  tb, 0, stream>>>(w_proj, wproj_t, D_, D_);
  transpose_w<<<dim3(FF_/32, D_/32, 1), tb, 0, stream>>>(w1, w1t, D_, FF_);
  transpose_w<<<dim3(D_/32, FF_/32, 1), tb, 0, stream>>>(w2, w2t, FF_, D_);

  ln_rows<<<BT_, 256, 0, stream>>>(x, ln1_g, ln1_b, hbuf);

  // QKV: [4096,1024] x [3072,1024]^T -> bf16 [4096,3072]
  gemm256<0,0,1,0><<<dim3(3072/256, BT_/256), 512, 0, stream>>>(
      hbuf, wqkv_t, nullptr, nullptr, qkv, BT_, 3072, D_, D_);

  repack_qkv<<<dim3(T_/64, B_*H_), 256, 0, stream>>>(qkv, qb, kb, vtb);

  attn_fwd<<<dim3(512), 256, 0, stream>>>(qb, kb, vtb, aout);

  // proj: split-K=2 partials + fused reduce (bias + x residual) -> xout (fp32)
  gemm256<0,0,0,1><<<dim3(D_/256, BT_/256, 2), 512, 0, stream>>>(
      aout, wproj_t, nullptr, nullptr, pparts, BT_, D_, D_, D_/2);
  reduce_parts<2><<<(BT_*D_)/1024, 256, 0, stream>>>(
      pparts, b_proj, x, xout, BT_*D_, D_);

  ln_rows<<<BT_, 256, 0, stream>>>(xout, ln2_g, ln2_b, h2);

  // FF1: [4096,1024] x [4096,1024]^T -> GELU -> bf16 [4096,4096]
  gemm256<1,1,1,0><<<dim3(FF_/256, BT_/256), 512, 0, stream>>>(
      h2, w1t, b1, nullptr, ff1, BT_, FF_, D_, D_);

  // FF2: split-K=4 partials + fused reduce (bias + xout residual) -> xout in place
  gemm256<0,0,0,1><<<dim3(D_/256, BT_/256, 4), 512, 0, stream>>>(
      ff1, w2t, nullptr, nullptr, fparts, BT_, D_, FF_, FF_/4);
  reduce_parts<4><<<(BT_*D_)/1024, 256, 0, stream>>>(
      fparts, b2, xout, xout, BT_*D_, D_);
}

// Round 9
// 276.478 us; speedup vs baseline: 1.4683x; 1.0519x over previous
//
#include <hip/hip_runtime.h>
#include <hip/hip_bf16.h>
#include <cstdint>
#include <cstddef>
#include <math.h>

#define D_ 1024
#define H_ 16
#define HD_ 64
#define T_ 2048
#define B_ 2
#define FF_ 4096
#define BT_ (B_*T_)   // 4096 rows
#define NT_ 32        // T_/64 kv tiles

typedef unsigned short u16;
typedef __attribute__((ext_vector_type(8))) __bf16 bf16x8;
typedef __attribute__((ext_vector_type(8))) u16 u16x8;
typedef __attribute__((ext_vector_type(4))) float f32x4;

__device__ __forceinline__ u16 f2bf(float f) {
  unsigned u = __builtin_bit_cast(unsigned, f);
  u += 0x7FFFu + ((u >> 16) & 1u);
  return (u16)(u >> 16);
}

__device__ __forceinline__ unsigned cvt_pk_bf16(float a, float b) {
  unsigned r;
  asm("v_cvt_pk_bf16_f32 %0, %1, %2" : "=v"(r) : "v"(a), "v"(b));
  return r;
}

__device__ __forceinline__ void gload16(const void* g, void* l) {
  __builtin_amdgcn_global_load_lds((__attribute__((address_space(1))) void*)g,
                                   (__attribute__((address_space(3))) void*)l, 16, 0, 0);
}

// ---------------- transpose + fp32->bf16 cast:  out[(z*C+c)*R + r] = in[z*R*C + r*C + c]
__global__ __launch_bounds__(256) void transpose_w(const float* __restrict__ in,
                                                   u16* __restrict__ out, int R, int C) {
  __shared__ float tile[32][33];
  const int z = blockIdx.z;
  const float* inz = in + (size_t)z * R * C;
  const int x = blockIdx.x * 32 + threadIdx.x;
  const int y0 = blockIdx.y * 32 + threadIdx.y;
  #pragma unroll
  for (int j = 0; j < 32; j += 8)
    tile[threadIdx.y + j][threadIdx.x] = inz[(size_t)(y0 + j) * C + x];
  __syncthreads();
  const int orr = blockIdx.y * 32 + threadIdx.x;
  const int oc0 = blockIdx.x * 32 + threadIdx.y;
  u16* outz = out + (size_t)z * C * R;
  #pragma unroll
  for (int j = 0; j < 32; j += 8)
    outz[(size_t)(oc0 + j) * R + orr] = f2bf(tile[threadIdx.x][threadIdx.y + j]);
}

// ---------------- LayerNorm (fp32 in -> bf16 out), one row (D=1024) per block of 256
__global__ __launch_bounds__(256) void ln_rows(const float* __restrict__ x,
    const float* __restrict__ g, const float* __restrict__ bb, u16* __restrict__ out) {
  const int row = blockIdx.x, tid = threadIdx.x;
  const float4 v = ((const float4*)(x + (size_t)row * D_))[tid];
  float s = v.x + v.y + v.z + v.w;
  float sq = v.x*v.x + v.y*v.y + v.z*v.z + v.w*v.w;
  #pragma unroll
  for (int m = 1; m < 64; m <<= 1) { s += __shfl_xor(s, m); sq += __shfl_xor(sq, m); }
  __shared__ float ss[4], qs[4];
  if ((tid & 63) == 0) { ss[tid >> 6] = s; qs[tid >> 6] = sq; }
  __syncthreads();
  s  = ss[0] + ss[1] + ss[2] + ss[3];
  sq = qs[0] + qs[1] + qs[2] + qs[3];
  const float mean = s * (1.f / D_);
  const float var  = sq * (1.f / D_) - mean * mean;
  const float rstd = rsqrtf(var + 1e-5f);
  const float4 gv = ((const float4*)g)[tid];
  const float4 bv = ((const float4*)bb)[tid];
  u16 o[4];
  o[0] = f2bf((v.x - mean) * rstd * gv.x + bv.x);
  o[1] = f2bf((v.y - mean) * rstd * gv.y + bv.y);
  o[2] = f2bf((v.z - mean) * rstd * gv.z + bv.z);
  o[3] = f2bf((v.w - mean) * rstd * gv.w + bv.w);
  *(ushort4*)(out + (size_t)row * D_ + tid * 4) = *(ushort4*)o;
}

// ---------------- GEMM 256x256, BK=64, 8 waves, counted-vmcnt pipeline + T2 swizzle.
template<int ACT, int BIAS, int OUTBF, int PARTIAL>
__global__ __launch_bounds__(512, 1) void gemm256(
    const u16* __restrict__ A, const u16* __restrict__ Bt,
    const float* __restrict__ bias, const float* resid,
    void* Cout, int M, int N, int K, int Kper) {
  __shared__ __attribute__((aligned(16))) u16 LA[2][256 * 64];
  __shared__ __attribute__((aligned(16))) u16 LB[2][256 * 64];

  const int tid = threadIdx.x;
  const int wid = tid >> 6, lane = tid & 63;
  const int wr = wid >> 2, wc = wid & 3;
  const int frow = lane & 15, hi = lane >> 4;

  const int gx = gridDim.x;
  const int nwg = gx * gridDim.y;
  const int orig = blockIdx.y * gx + blockIdx.x;
  const int cpx = nwg >> 3;
  const int swz = (orig & 7) * cpx + (orig >> 3);
  const int bm = (swz / gx) * 256, bn = (swz % gx) * 256;
  const int z = PARTIAL ? blockIdx.z : 0;
  const int koff = z * Kper;
  const int nt = Kper >> 6;

  const u16* Atile = A + (size_t)bm * K + koff;
  const u16* Btile = Bt + (size_t)bn * K + koff;

  const int lr = lane >> 3, lc = lane & 7;
  const int gch = lc ^ lr;

  f32x4 acc[8][4] = {};

  #define STAGE(kt, db)                                                          \
    {                                                                            \
      const u16* ga = Atile + (kt) * 64;                                         \
      const u16* gb = Btile + (kt) * 64;                                         \
      u16* la = &LA[db][0];                                                      \
      u16* lb = &LB[db][0];                                                      \
      _Pragma("unroll")                                                          \
      for (int j = 0; j < 4; j++) {                                              \
        const int rw = j * 64 + wid * 8;                                         \
        gload16(ga + (size_t)(rw + lr) * K + gch * 8, la + rw * 64);             \
        gload16(gb + (size_t)(rw + lr) * K + gch * 8, lb + rw * 64);             \
      }                                                                          \
    }

  STAGE(0, 0);

  for (int t = 0; t < nt; ++t) {
    if (t + 1 < nt) {
      STAGE(t + 1, (t + 1) & 1);
      asm volatile("s_waitcnt vmcnt(8)" ::: "memory");
    } else {
      asm volatile("s_waitcnt vmcnt(0)" ::: "memory");
    }
    __builtin_amdgcn_s_barrier();

    const u16* Ab = &LA[t & 1][0];
    const u16* Bb = &LB[t & 1][0];

    bf16x8 bfr[4][2];
    #pragma unroll
    for (int ni = 0; ni < 4; ni++)
      #pragma unroll
      for (int ks = 0; ks < 2; ks++) {
        const int row = wc * 64 + ni * 16 + frow;
        bfr[ni][ks] = *(const bf16x8*)(Bb + row * 64 + (((ks * 4 + hi) ^ (row & 7)) << 3));
      }
    #pragma unroll
    for (int q = 0; q < 4; q++) {
      bf16x8 af[2][2];
      #pragma unroll
      for (int m2 = 0; m2 < 2; m2++)
        #pragma unroll
        for (int ks = 0; ks < 2; ks++) {
          const int row = wr * 128 + (q * 2 + m2) * 16 + frow;
          af[m2][ks] = *(const bf16x8*)(Ab + row * 64 + (((ks * 4 + hi) ^ (row & 7)) << 3));
        }
      __builtin_amdgcn_s_setprio(1);
      #pragma unroll
      for (int m2 = 0; m2 < 2; m2++)
        #pragma unroll
        for (int ni = 0; ni < 4; ni++)
          #pragma unroll
          for (int ks = 0; ks < 2; ks++)
            acc[q * 2 + m2][ni] =
                __builtin_amdgcn_mfma_f32_16x16x32_bf16(af[m2][ks], bfr[ni][ks],
                                                        acc[q * 2 + m2][ni], 0, 0, 0);
      __builtin_amdgcn_s_setprio(0);
    }
    __builtin_amdgcn_s_barrier();
  }
  #undef STAGE

  const int r0 = bm + wr * 128 + hi * 4;
  const int c0 = bn + wc * 64 + frow;
  #pragma unroll
  for (int mi = 0; mi < 8; mi++) {
    #pragma unroll
    for (int ni = 0; ni < 4; ni++) {
      #pragma unroll
      for (int r = 0; r < 4; r++) {
        float v = acc[mi][ni][r];
        const int rr = r0 + mi * 16 + r;
        const int cc = c0 + ni * 16;
        if (PARTIAL) {
          ((float*)Cout)[((size_t)z * M + rr) * N + cc] = v;
        } else {
          if (BIAS) v += bias[cc];
          if (ACT == 1) v = 0.5f * v * (1.0f + erff(v * 0.70710678118f));
          if (resid) v += resid[(size_t)rr * N + cc];
          if (OUTBF) ((u16*)Cout)[(size_t)rr * N + cc] = f2bf(v);
          else       ((float*)Cout)[(size_t)rr * N + cc] = v;
        }
      }
    }
  }
}

// ---------------- split-K reduce: out = sum(parts) + bias (+resid), fp32
template<int NPART>
__global__ __launch_bounds__(256) void reduce_parts(
    const float* __restrict__ parts, const float* __restrict__ bias,
    const float* __restrict__ resid, float* __restrict__ out, int MN, int N) {
  const int i4 = (blockIdx.x * 256 + threadIdx.x) * 4;
  if (i4 >= MN) return;
  float4 s = *(const float4*)(parts + i4);
  #pragma unroll
  for (int p = 1; p < NPART; p++) {
    const float4 t = *(const float4*)(parts + (size_t)p * MN + i4);
    s.x += t.x; s.y += t.y; s.z += t.z; s.w += t.w;
  }
  const float4 bv = *(const float4*)(bias + (i4 & (N - 1)));
  const float4 rv = *(const float4*)(resid + i4);
  s.x += bv.x + rv.x; s.y += bv.y + rv.y; s.z += bv.z + rv.z; s.w += bv.w + rv.w;
  *(float4*)(out + i4) = s;
}

// ---------------- proj reduce (NPART=2) + bias + residual + LN2 fused.
// One 1024-col row per 256-thread block: writes xout (fp32) and h2 (bf16 LN).
__global__ __launch_bounds__(256) void reduce2_ln(
    const float* __restrict__ parts, const float* __restrict__ bias,
    const float* __restrict__ resid, const float* __restrict__ g,
    const float* __restrict__ bb, float* __restrict__ xout,
    u16* __restrict__ h2, int MN) {
  const int row = blockIdx.x, tid = threadIdx.x;
  const int i4 = row * D_ + tid * 4;
  float4 s = *(const float4*)(parts + i4);
  const float4 t = *(const float4*)(parts + (size_t)MN + i4);
  const float4 bv = *(const float4*)(bias + tid * 4);
  const float4 rv = *(const float4*)(resid + i4);
  s.x += t.x + bv.x + rv.x; s.y += t.y + bv.y + rv.y;
  s.z += t.z + bv.z + rv.z; s.w += t.w + bv.w + rv.w;
  *(float4*)(xout + i4) = s;
  float sm = s.x + s.y + s.z + s.w;
  float sq = s.x*s.x + s.y*s.y + s.z*s.z + s.w*s.w;
  #pragma unroll
  for (int m = 1; m < 64; m <<= 1) { sm += __shfl_xor(sm, m); sq += __shfl_xor(sq, m); }
  __shared__ float ss[4], qs[4];
  if ((tid & 63) == 0) { ss[tid >> 6] = sm; qs[tid >> 6] = sq; }
  __syncthreads();
  sm = ss[0] + ss[1] + ss[2] + ss[3];
  sq = qs[0] + qs[1] + qs[2] + qs[3];
  const float mean = sm * (1.f / D_);
  const float var  = sq * (1.f / D_) - mean * mean;
  const float rstd = rsqrtf(var + 1e-5f);
  const float4 gv = ((const float4*)g)[tid];
  const float4 b2v = ((const float4*)bb)[tid];
  u16 o[4];
  o[0] = f2bf((s.x - mean) * rstd * gv.x + b2v.x);
  o[1] = f2bf((s.y - mean) * rstd * gv.y + b2v.y);
  o[2] = f2bf((s.z - mean) * rstd * gv.z + b2v.z);
  o[3] = f2bf((s.w - mean) * rstd * gv.w + b2v.w);
  *(ushort4*)(h2 + (size_t)row * D_ + tid * 4) = *(ushort4*)o;
}

// ---------------- repack qkv [bt, 3*D] -> q(SCALED),k [bh, T, 64] and v^T [bh, 64, T]
__global__ __launch_bounds__(256) void repack_qkv(const u16* __restrict__ qkv,
    u16* __restrict__ q, u16* __restrict__ k, u16* __restrict__ vt) {
  const int t0 = blockIdx.x * 64, bh = blockIdx.y;
  const int b = bh >> 4, h = bh & 15;
  const int tid = threadIdx.x;
  const int c = (tid & 7) * 8;
  __shared__ __attribute__((aligned(16))) u16 vs[64][72];
  #pragma unroll
  for (int p = 0; p < 2; p++) {
    const int tl = p * 32 + (tid >> 3);
    const size_t inrow = ((size_t)b * T_ + t0 + tl) * 3072 + h * 64;
    u16x8 qv = *(const u16x8*)(qkv + inrow + c);
    bf16x8 kv = *(const bf16x8*)(qkv + inrow + 1024 + c);
    bf16x8 vv = *(const bf16x8*)(qkv + inrow + 2048 + c);
    alignas(16) u16 qs[8];
    #pragma unroll
    for (int e = 0; e < 8; e++) {
      const float f = __builtin_bit_cast(float, ((unsigned)qv[e]) << 16) * 0.18033688011112042f;
      qs[e] = f2bf(f);
    }
    *(u16x8*)(q + ((size_t)bh * T_ + t0 + tl) * HD_ + c) = *(u16x8*)qs;
    *(bf16x8*)(k + ((size_t)bh * T_ + t0 + tl) * HD_ + c) = kv;
    *(bf16x8*)&vs[tl][c] = vv;
  }
  __syncthreads();
  const int d = tid >> 2, tc = (tid & 3) * 16;
  alignas(16) u16 tmp[16];
  #pragma unroll
  for (int j = 0; j < 16; j++) tmp[j] = vs[tc + j][d];
  *(bf16x8*)(vt + ((size_t)bh * HD_ + d) * T_ + t0 + tc)     = *(bf16x8*)&tmp[0];
  *(bf16x8*)(vt + ((size_t)bh * HD_ + d) * T_ + t0 + tc + 8) = *(bf16x8*)&tmp[8];
}

// ---------------- flash attention v5: 8-wave blocks, QBLK=128 (wave owns 16 rows),
// LPT dispatch + XCD-bh locality, lazy row-max, ones-column l, defer-max.
__global__ __launch_bounds__(512) void attn_fwd(
    const u16* __restrict__ q, const u16* __restrict__ k,
    const u16* __restrict__ vt, u16* __restrict__ out) {
  __shared__ __attribute__((aligned(16))) u16 Ps[8][16 * 64];
  __shared__ __attribute__((aligned(16))) u16 Kb[2][64 * 64];
  __shared__ __attribute__((aligned(16))) u16 Vb[2][64 * 64];

  const int bid = blockIdx.x;                // 512 blocks
  const int xcd = bid & 7, j = bid >> 3;     // j = 0..63
  const int bh  = xcd + 8 * (j & 3);         // 4 bh per xcd -> 2MB K/V, L2-resident
  const int qb  = 15 - (j >> 2);             // 0..15, largest (most work) first
  const int b = bh >> 4, h = bh & 15;
  const int tid = threadIdx.x, wid = tid >> 6, lane = tid & 63;
  const u16* kh = k  + (size_t)bh * T_ * HD_;
  const u16* vh = vt + (size_t)bh * HD_ * T_;
  const int q0 = qb * 128;
  const int nkt = 2 * qb + 2;                // kv tiles for this q-block
  const int wlast = 2 * qb + (wid >> 2);     // last kv tile this wave has unmasked cols

  const int frow = lane & 15;
  const int hi   = lane >> 4;
  const int fk   = hi * 8;
  const int rowb = hi * 4;
  const int colb = frow;
  const int srow = tid >> 3;                 // staging row 0..63
  const int gch  = (tid & 7) ^ (srow & 7);   // pre-swizzled chunk

  u16x8 onebits = (u16x8)((u16)0x3F80);
  bf16x8 b_one = (frow == 0) ? __builtin_bit_cast(bf16x8, onebits) : (bf16x8){};

  u16* Pw = &Ps[wid][0];

  const u16* qrow = q + ((size_t)bh * T_ + q0 + wid * 16 + frow) * HD_;
  bf16x8 aq[2];
  aq[0] = *(const bf16x8*)(qrow + fk);
  aq[1] = *(const bf16x8*)(qrow + 32 + fk);

  float m2[4] = {-3e38f, -3e38f, -3e38f, -3e38f};
  f32x4 acc_l = {};
  f32x4 acc_o[4] = {};

  int cur = 0;
  gload16(kh + (size_t)srow * HD_ + gch * 8, &Kb[0][(wid * 8) * 64]);
  gload16(vh + (size_t)srow * T_ + gch * 8,  &Vb[0][(wid * 8) * 64]);
  __syncthreads();

  for (int kt = 0; kt < nkt; ++kt) {
    if (kt + 1 < nkt) {
      const int nx = cur ^ 1, ktn = kt + 1;
      gload16(kh + (size_t)(ktn * 64 + srow) * HD_ + gch * 8, &Kb[nx][(wid * 8) * 64]);
      gload16(vh + (size_t)srow * T_ + ktn * 64 + gch * 8,    &Vb[nx][(wid * 8) * 64]);
    }

    if (kt <= wlast) {   // wave-uniform: skip fully-masked diagonal tiles
      const u16* Kc = &Kb[cur][0];
      const u16* Vc = &Vb[cur][0];

      // ---- QK^T (q pre-scaled by 0.125*log2e)
      float p2[4][4];
      __builtin_amdgcn_s_setprio(1);
      #pragma unroll
      for (int ni = 0; ni < 4; ni++) {
        f32x4 s = {};
        #pragma unroll
        for (int ks = 0; ks < 2; ks++) {
          const int row = ni * 16 + frow;
          const int ch  = ks * 4 + hi;
          bf16x8 bk = *(const bf16x8*)(Kc + row * 64 + ((ch ^ (row & 7)) << 3));
          s = __builtin_amdgcn_mfma_f32_16x16x32_bf16(aq[ks], bk, s, 0, 0, 0);
        }
        #pragma unroll
        for (int r = 0; r < 4; r++) p2[ni][r] = s[r];
      }
      __builtin_amdgcn_s_setprio(0);

      if (kt >= nkt - 2) {  // mask only near the diagonal
        #pragma unroll
        for (int ni = 0; ni < 4; ni++)
          #pragma unroll
          for (int r = 0; r < 4; r++) {
            const bool msk = (kt * 64 + ni * 16 + colb) > (q0 + wid * 16 + rowb + r);
            if (msk) p2[ni][r] = -3e38f;
          }
      }

      // ---- lazy row max: local check, shuffles only on rescale events
      float lmax[4];
      #pragma unroll
      for (int r = 0; r < 4; r++)
        lmax[r] = fmaxf(fmaxf(p2[0][r], p2[1][r]), fmaxf(p2[2][r], p2[3][r]));
      int ok = 1;
      #pragma unroll
      for (int r = 0; r < 4; r++) ok &= (lmax[r] <= m2[r] + 8.0f);
      if (!__all(ok)) {
        #pragma unroll
        for (int r = 0; r < 4; r++) {
          float rm = lmax[r];
          rm = fmaxf(rm, __shfl_xor(rm, 1));
          rm = fmaxf(rm, __shfl_xor(rm, 2));
          rm = fmaxf(rm, __shfl_xor(rm, 4));
          rm = fmaxf(rm, __shfl_xor(rm, 8));
          const float mnew = fmaxf(m2[r], rm);
          const float corr = exp2f(m2[r] - mnew);
          m2[r] = mnew;
          acc_l[r] *= corr;
          #pragma unroll
          for (int ni = 0; ni < 4; ni++) acc_o[ni][r] *= corr;
        }
      }
      #pragma unroll
      for (int ni = 0; ni < 4; ni++)
        #pragma unroll
        for (int r = 0; r < 4; r++) p2[ni][r] = exp2f(p2[ni][r] - m2[r]);

      // ---- P -> per-wave swizzled LDS (cvt_pk), reload as A-frag
      #pragma unroll
      for (int ni = 0; ni < 4; ni++) {
        #pragma unroll
        for (int r = 0; r < 4; r += 2) {
          const unsigned pk = cvt_pk_bf16(p2[ni][r], p2[ni][r + 1]);
          const int lr0 = rowb + r, lr1 = rowb + r + 1;
          const int ch = ni * 2 + (colb >> 3);
          Pw[lr0 * 64 + ((ch ^ (lr0 & 7)) << 3) + (colb & 7)] = (u16)pk;
          Pw[lr1 * 64 + ((ch ^ (lr1 & 7)) << 3) + (colb & 7)] = (u16)(pk >> 16);
        }
      }
      bf16x8 ap[2];
      {
        const int c0 = (0 * 4 + hi) ^ (frow & 7);
        const int c1 = (1 * 4 + hi) ^ (frow & 7);
        ap[0] = *(const bf16x8*)(Pw + frow * 64 + (c0 << 3));
        ap[1] = *(const bf16x8*)(Pw + frow * 64 + (c1 << 3));
      }

      // ---- PV (+ ones-column for l)
      __builtin_amdgcn_s_setprio(1);
      #pragma unroll
      for (int ks = 0; ks < 2; ks++)
        acc_l = __builtin_amdgcn_mfma_f32_16x16x32_bf16(ap[ks], b_one, acc_l, 0, 0, 0);
      #pragma unroll
      for (int ni = 0; ni < 4; ni++) {
        #pragma unroll
        for (int ks = 0; ks < 2; ks++) {
          const int row = ni * 16 + frow;
          const int ch  = ks * 4 + hi;
          bf16x8 bv = *(const bf16x8*)(Vc + row * 64 + ((ch ^ (row & 7)) << 3));
          acc_o[ni] = __builtin_amdgcn_mfma_f32_16x16x32_bf16(ap[ks], bv, acc_o[ni], 0, 0, 0);
        }
      }
      __builtin_amdgcn_s_setprio(0);
    }

    __syncthreads();
    cur ^= 1;
  }

  float linv[4];
  #pragma unroll
  for (int r = 0; r < 4; r++) {
    const float lv = __shfl(acc_l[r], lane & 48);
    linv[r] = 1.0f / lv;
  }
  #pragma unroll
  for (int ni = 0; ni < 4; ni++)
    #pragma unroll
    for (int r = 0; r < 4; r++) {
      const float ov = acc_o[ni][r] * linv[r];
      const size_t row = (size_t)b * T_ + q0 + wid * 16 + rowb + r;
      out[row * D_ + h * HD_ + ni * 16 + colb] = f2bf(ov);
    }
}

extern "C" void kernel_launch(void* const* d_in, const int* in_sizes, int n_in,
                              void* d_out, int out_size, void* d_ws, size_t ws_size,
                              hipStream_t stream) {
  (void)in_sizes; (void)n_in; (void)out_size; (void)ws_size;
  const float* x      = (const float*)d_in[0];
  const float* wq     = (const float*)d_in[1];
  const float* wk     = (const float*)d_in[2];
  const float* wv     = (const float*)d_in[3];
  const float* w_proj = (const float*)d_in[4];
  const float* b_proj = (const float*)d_in[5];
  const float* ln1_g  = (const float*)d_in[6];
  const float* ln1_b  = (const float*)d_in[7];
  const float* ln2_g  = (const float*)d_in[8];
  const float* ln2_b  = (const float*)d_in[9];
  const float* w1     = (const float*)d_in[10];
  const float* b1     = (const float*)d_in[11];
  const float* w2     = (const float*)d_in[12];
  const float* b2     = (const float*)d_in[13];

  uint8_t* ws = (uint8_t*)d_ws;
  const size_t MB = 1024 * 1024;
  u16* wqkv_t = (u16*)(ws + 0);        // [3072,1024]
  u16* wproj_t = (u16*)(ws + 6 * MB);  // [1024,1024]
  u16* w1t  = (u16*)(ws + 8 * MB);     // [4096,1024]
  u16* w2t  = (u16*)(ws + 16 * MB);    // [1024,4096]
  u16* hbuf = (u16*)(ws + 24 * MB);    // [4096,1024]
  u16* qkv  = (u16*)(ws + 32 * MB);    // [4096,3072]  (dead after repack)
  u16* qb   = (u16*)(ws + 56 * MB);    // [32,2048,64] (dead after attn)
  u16* kb   = (u16*)(ws + 64 * MB);    // (dead after attn)
  u16* vtb  = (u16*)(ws + 72 * MB);    // (dead after attn)
  u16* aout = (u16*)(ws + 80 * MB);    // [4096,1024]
  u16* h2   = (u16*)(ws + 88 * MB);    // [4096,1024]
  u16* ff1  = (u16*)(ws + 96 * MB);    // [4096,4096]
  float* pparts = (float*)(ws + 32 * MB);  // proj: 2 x [4096,1024] fp32 = 32 MB
  float* fparts = (float*)(ws + 32 * MB);  // ff2:  4 x [4096,1024] fp32 = 64 MB
  float* xout = (float*)d_out;

  const dim3 tb(32, 8);
  transpose_w<<<dim3(HD_/32, D_/32, H_), tb, 0, stream>>>(wq, wqkv_t, D_, HD_);
  transpose_w<<<dim3(HD_/32, D_/32, H_), tb, 0, stream>>>(wk, wqkv_t + (size_t)D_*D_, D_, HD_);
  transpose_w<<<dim3(HD_/32, D_/32, H_), tb, 0, stream>>>(wv, wqkv_t + 2*(size_t)D_*D_, D_, HD_);
  transpose_w<<<dim3(D_/32, D_/32, 1),  tb, 0, stream>>>(w_proj, wproj_t, D_, D_);
  transpose_w<<<dim3(FF_/32, D_/32, 1), tb, 0, stream>>>(w1, w1t, D_, FF_);
  transpose_w<<<dim3(D_/32, FF_/32, 1), tb, 0, stream>>>(w2, w2t, FF_, D_);

  ln_rows<<<BT_, 256, 0, stream>>>(x, ln1_g, ln1_b, hbuf);

  // QKV: [4096,1024] x [3072,1024]^T -> bf16 [4096,3072]
  gemm256<0,0,1,0><<<dim3(3072/256, BT_/256), 512, 0, stream>>>(
      hbuf, wqkv_t, nullptr, nullptr, qkv, BT_, 3072, D_, D_);

  repack_qkv<<<dim3(T_/64, B_*H_), 256, 0, stream>>>(qkv, qb, kb, vtb);

  attn_fwd<<<dim3(512), 512, 0, stream>>>(qb, kb, vtb, aout);

  // proj: split-K=2 partials, then fused reduce + bias + x-residual + LN2
  gemm256<0,0,0,1><<<dim3(D_/256, BT_/256, 2), 512, 0, stream>>>(
      aout, wproj_t, nullptr, nullptr, pparts, BT_, D_, D_, D_/2);
  reduce2_ln<<<BT_, 256, 0, stream>>>(
      pparts, b_proj, x, ln2_g, ln2_b, xout, h2, BT_*D_);

  // FF1: [4096,1024] x [4096,1024]^T -> GELU -> bf16 [4096,4096]
  gemm256<1,1,1,0><<<dim3(FF_/256, BT_/256), 512, 0, stream>>>(
      h2, w1t, b1, nullptr, ff1, BT_, FF_, D_, D_);

  // FF2: split-K=4 partials + fused reduce (bias + xout residual) -> xout in place
  gemm256<0,0,0,1><<<dim3(D_/256, BT_/256, 4), 512, 0, stream>>>(
      ff1, w2t, nullptr, nullptr, fparts, BT_, D_, FF_, FF_/4);
  reduce_parts<4><<<(BT_*D_)/1024, 256, 0, stream>>>(
      fparts, b2, xout, xout, BT_*D_, D_);
}

// Round 10
// 267.104 us; speedup vs baseline: 1.5199x; 1.0351x over previous
//
#include <hip/hip_runtime.h>
#include <hip/hip_bf16.h>
#include <cstdint>
#include <cstddef>
#include <math.h>

#define D_ 1024
#define H_ 16
#define HD_ 64
#define T_ 2048
#define B_ 2
#define FF_ 4096
#define BT_ (B_*T_)   // 4096 rows
#define NT_ 32        // T_/64 kv tiles

typedef unsigned short u16;
typedef __attribute__((ext_vector_type(8))) __bf16 bf16x8;
typedef __attribute__((ext_vector_type(8))) u16 u16x8;
typedef __attribute__((ext_vector_type(4))) float f32x4;

__device__ __forceinline__ u16 f2bf(float f) {
  unsigned u = __builtin_bit_cast(unsigned, f);
  u += 0x7FFFu + ((u >> 16) & 1u);
  return (u16)(u >> 16);
}

__device__ __forceinline__ unsigned cvt_pk_bf16(float a, float b) {
  unsigned r;
  asm("v_cvt_pk_bf16_f32 %0, %1, %2" : "=v"(r) : "v"(a), "v"(b));
  return r;
}

__device__ __forceinline__ void gload16(const void* g, void* l) {
  __builtin_amdgcn_global_load_lds((__attribute__((address_space(1))) void*)g,
                                   (__attribute__((address_space(3))) void*)l, 16, 0, 0);
}

// ---------------- transpose + fp32->bf16 cast:  out[(z*C+c)*R + r] = in[z*R*C + r*C + c]
__global__ __launch_bounds__(256) void transpose_w(const float* __restrict__ in,
                                                   u16* __restrict__ out, int R, int C) {
  __shared__ float tile[32][33];
  const int z = blockIdx.z;
  const float* inz = in + (size_t)z * R * C;
  const int x = blockIdx.x * 32 + threadIdx.x;
  const int y0 = blockIdx.y * 32 + threadIdx.y;
  #pragma unroll
  for (int j = 0; j < 32; j += 8)
    tile[threadIdx.y + j][threadIdx.x] = inz[(size_t)(y0 + j) * C + x];
  __syncthreads();
  const int orr = blockIdx.y * 32 + threadIdx.x;
  const int oc0 = blockIdx.x * 32 + threadIdx.y;
  u16* outz = out + (size_t)z * C * R;
  #pragma unroll
  for (int j = 0; j < 32; j += 8)
    outz[(size_t)(oc0 + j) * R + orr] = f2bf(tile[threadIdx.x][threadIdx.y + j]);
}

// ---------------- LayerNorm (fp32 in -> bf16 out), one row (D=1024) per block of 256
__global__ __launch_bounds__(256) void ln_rows(const float* __restrict__ x,
    const float* __restrict__ g, const float* __restrict__ bb, u16* __restrict__ out) {
  const int row = blockIdx.x, tid = threadIdx.x;
  const float4 v = ((const float4*)(x + (size_t)row * D_))[tid];
  float s = v.x + v.y + v.z + v.w;
  float sq = v.x*v.x + v.y*v.y + v.z*v.z + v.w*v.w;
  #pragma unroll
  for (int m = 1; m < 64; m <<= 1) { s += __shfl_xor(s, m); sq += __shfl_xor(sq, m); }
  __shared__ float ss[4], qs[4];
  if ((tid & 63) == 0) { ss[tid >> 6] = s; qs[tid >> 6] = sq; }
  __syncthreads();
  s  = ss[0] + ss[1] + ss[2] + ss[3];
  sq = qs[0] + qs[1] + qs[2] + qs[3];
  const float mean = s * (1.f / D_);
  const float var  = sq * (1.f / D_) - mean * mean;
  const float rstd = rsqrtf(var + 1e-5f);
  const float4 gv = ((const float4*)g)[tid];
  const float4 bv = ((const float4*)bb)[tid];
  u16 o[4];
  o[0] = f2bf((v.x - mean) * rstd * gv.x + bv.x);
  o[1] = f2bf((v.y - mean) * rstd * gv.y + bv.y);
  o[2] = f2bf((v.z - mean) * rstd * gv.z + bv.z);
  o[3] = f2bf((v.w - mean) * rstd * gv.w + bv.w);
  *(ushort4*)(out + (size_t)row * D_ + tid * 4) = *(ushort4*)o;
}

// ---------------- GEMM 256x256, BK=64, 8 waves, 4-phase/K-tile interleave (T3+T4):
// phase p: {ds_read A-quadrant p (B at p0, held in regs) | stage 1 half-unit of kt+1
//           | barrier | lgkmcnt(0) | 16 MFMA | counted vmcnt | barrier}.
// Stage order per kt+1: p0->B rows 0-127, p1->B rows 128-255, p2->A loc rows 0-63
// (both halves), p3->A loc rows 64-127. B is consumed at p0 (regs); A-quadrant q is
// consumed at phase q. vmcnt(4) at p1-end guarantees the A(q23) unit (staged at
// prev p3) landed before p2/p3 reads; vmcnt(2) at p3-end guarantees B+A(q01) of the
// next tile (staged p0..p2) landed before next p0/p1 reads. Never vmcnt(0) in loop.
template<int ACT, int BIAS, int OUTBF, int PARTIAL>
__global__ __launch_bounds__(512, 1) void gemm256(
    const u16* __restrict__ A, const u16* __restrict__ Bt,
    const float* __restrict__ bias, const float* resid,
    void* Cout, int M, int N, int K, int Kper) {
  __shared__ __attribute__((aligned(16))) u16 LA[2][256 * 64];
  __shared__ __attribute__((aligned(16))) u16 LB[2][256 * 64];

  const int tid = threadIdx.x;
  const int wid = tid >> 6, lane = tid & 63;
  const int wr = wid >> 2, wc = wid & 3;       // wave -> 128x64 C block
  const int frow = lane & 15, hi = lane >> 4;

  const int gx = gridDim.x;
  const int nwg = gx * gridDim.y;
  const int orig = blockIdx.y * gx + blockIdx.x;
  const int cpx = nwg >> 3;
  const int swz = (orig & 7) * cpx + (orig >> 3);
  const int bm = (swz / gx) * 256, bn = (swz % gx) * 256;
  const int z = PARTIAL ? blockIdx.z : 0;
  const int koff = z * Kper;
  const int nt = Kper >> 6;

  const u16* Atile = A + (size_t)bm * K + koff;
  const u16* Btile = Bt + (size_t)bn * K + koff;

  // staging lane geometry: pre-swizzled global chunk, linear LDS dest
  const int srow = tid >> 3;                  // 0..63
  const int gch  = (tid & 7) ^ (srow & 7);

  f32x4 acc[8][4] = {};

  // stage B half h (rows h*128..h*128+127) of k-tile kt -> LB[db]
  auto stageB = [&](int kt, int h, int db) {
    #pragma unroll
    for (int j = 0; j < 2; j++) {
      const int rl = h * 128 + j * 64;
      gload16(Btile + (size_t)(rl + srow) * K + (size_t)kt * 64 + gch * 8,
              &LB[db][(rl + wid * 8) * 64]);
    }
  };
  // stage A unit u (loc rows u*64..u*64+63 of BOTH 128-row halves) -> LA[db]
  auto stageA = [&](int kt, int u, int db) {
    #pragma unroll
    for (int j = 0; j < 2; j++) {
      const int rl = j * 128 + u * 64;
      gload16(Atile + (size_t)(rl + srow) * K + (size_t)kt * 64 + gch * 8,
              &LA[db][(rl + wid * 8) * 64]);
    }
  };

  // prologue: kt0 fully staged; vmcnt(2) -> B0,B1,A(q01) landed, A(q23) may fly
  stageB(0, 0, 0); stageB(0, 1, 0); stageA(0, 0, 0); stageA(0, 1, 0);
  asm volatile("s_waitcnt vmcnt(2)" ::: "memory");
  __builtin_amdgcn_s_barrier();

  for (int kt = 0; kt < nt; ++kt) {
    const int db = kt & 1;
    const u16* Ab = &LA[db][0];
    const u16* Bb = &LB[db][0];
    bf16x8 bfr[4][2];
    #pragma unroll
    for (int p = 0; p < 4; ++p) {
      if (p == 0) {
        #pragma unroll
        for (int ni = 0; ni < 4; ni++)
          #pragma unroll
          for (int ks = 0; ks < 2; ks++) {
            const int row = wc * 64 + ni * 16 + frow;
            bfr[ni][ks] = *(const bf16x8*)(Bb + row * 64 + (((ks * 4 + hi) ^ (row & 7)) << 3));
          }
      }
      bf16x8 af[2][2];
      #pragma unroll
      for (int m2 = 0; m2 < 2; m2++)
        #pragma unroll
        for (int ks = 0; ks < 2; ks++) {
          const int row = wr * 128 + (p * 2 + m2) * 16 + frow;
          af[m2][ks] = *(const bf16x8*)(Ab + row * 64 + (((ks * 4 + hi) ^ (row & 7)) << 3));
        }
      if (kt + 1 < nt) {
        if      (p == 0) stageB(kt + 1, 0, db ^ 1);
        else if (p == 1) stageB(kt + 1, 1, db ^ 1);
        else if (p == 2) stageA(kt + 1, 0, db ^ 1);
        else             stageA(kt + 1, 1, db ^ 1);
      }
      __builtin_amdgcn_s_barrier();
      asm volatile("s_waitcnt lgkmcnt(0)" ::: "memory");
      __builtin_amdgcn_sched_barrier(0);
      __builtin_amdgcn_s_setprio(1);
      #pragma unroll
      for (int m2 = 0; m2 < 2; m2++)
        #pragma unroll
        for (int ni = 0; ni < 4; ni++)
          #pragma unroll
          for (int ks = 0; ks < 2; ks++)
            acc[p * 2 + m2][ni] =
                __builtin_amdgcn_mfma_f32_16x16x32_bf16(af[m2][ks], bfr[ni][ks],
                                                        acc[p * 2 + m2][ni], 0, 0, 0);
      __builtin_amdgcn_s_setprio(0);
      if (p == 1) asm volatile("s_waitcnt vmcnt(4)" ::: "memory");
      if (p == 3) asm volatile("s_waitcnt vmcnt(2)" ::: "memory");
      __builtin_amdgcn_s_barrier();
    }
  }

  const int r0 = bm + wr * 128 + hi * 4;
  const int c0 = bn + wc * 64 + frow;
  #pragma unroll
  for (int mi = 0; mi < 8; mi++) {
    #pragma unroll
    for (int ni = 0; ni < 4; ni++) {
      #pragma unroll
      for (int r = 0; r < 4; r++) {
        float v = acc[mi][ni][r];
        const int rr = r0 + mi * 16 + r;
        const int cc = c0 + ni * 16;
        if (PARTIAL) {
          ((float*)Cout)[((size_t)z * M + rr) * N + cc] = v;
        } else {
          if (BIAS) v += bias[cc];
          if (ACT == 1) v = 0.5f * v * (1.0f + erff(v * 0.70710678118f));
          if (resid) v += resid[(size_t)rr * N + cc];
          if (OUTBF) ((u16*)Cout)[(size_t)rr * N + cc] = f2bf(v);
          else       ((float*)Cout)[(size_t)rr * N + cc] = v;
        }
      }
    }
  }
}

// ---------------- split-K reduce: out = sum(parts) + bias (+resid), fp32
template<int NPART>
__global__ __launch_bounds__(256) void reduce_parts(
    const float* __restrict__ parts, const float* __restrict__ bias,
    const float* __restrict__ resid, float* __restrict__ out, int MN, int N) {
  const int i4 = (blockIdx.x * 256 + threadIdx.x) * 4;
  if (i4 >= MN) return;
  float4 s = *(const float4*)(parts + i4);
  #pragma unroll
  for (int p = 1; p < NPART; p++) {
    const float4 t = *(const float4*)(parts + (size_t)p * MN + i4);
    s.x += t.x; s.y += t.y; s.z += t.z; s.w += t.w;
  }
  const float4 bv = *(const float4*)(bias + (i4 & (N - 1)));
  const float4 rv = *(const float4*)(resid + i4);
  s.x += bv.x + rv.x; s.y += bv.y + rv.y; s.z += bv.z + rv.z; s.w += bv.w + rv.w;
  *(float4*)(out + i4) = s;
}

// ---------------- proj reduce (NPART=2) + bias + residual + LN2 fused.
__global__ __launch_bounds__(256) void reduce2_ln(
    const float* __restrict__ parts, const float* __restrict__ bias,
    const float* __restrict__ resid, const float* __restrict__ g,
    const float* __restrict__ bb, float* __restrict__ xout,
    u16* __restrict__ h2, int MN) {
  const int row = blockIdx.x, tid = threadIdx.x;
  const int i4 = row * D_ + tid * 4;
  float4 s = *(const float4*)(parts + i4);
  const float4 t = *(const float4*)(parts + (size_t)MN + i4);
  const float4 bv = *(const float4*)(bias + tid * 4);
  const float4 rv = *(const float4*)(resid + i4);
  s.x += t.x + bv.x + rv.x; s.y += t.y + bv.y + rv.y;
  s.z += t.z + bv.z + rv.z; s.w += t.w + bv.w + rv.w;
  *(float4*)(xout + i4) = s;
  float sm = s.x + s.y + s.z + s.w;
  float sq = s.x*s.x + s.y*s.y + s.z*s.z + s.w*s.w;
  #pragma unroll
  for (int m = 1; m < 64; m <<= 1) { sm += __shfl_xor(sm, m); sq += __shfl_xor(sq, m); }
  __shared__ float ss[4], qs[4];
  if ((tid & 63) == 0) { ss[tid >> 6] = sm; qs[tid >> 6] = sq; }
  __syncthreads();
  sm = ss[0] + ss[1] + ss[2] + ss[3];
  sq = qs[0] + qs[1] + qs[2] + qs[3];
  const float mean = sm * (1.f / D_);
  const float var  = sq * (1.f / D_) - mean * mean;
  const float rstd = rsqrtf(var + 1e-5f);
  const float4 gv = ((const float4*)g)[tid];
  const float4 b2v = ((const float4*)bb)[tid];
  u16 o[4];
  o[0] = f2bf((s.x - mean) * rstd * gv.x + b2v.x);
  o[1] = f2bf((s.y - mean) * rstd * gv.y + b2v.y);
  o[2] = f2bf((s.z - mean) * rstd * gv.z + b2v.z);
  o[3] = f2bf((s.w - mean) * rstd * gv.w + b2v.w);
  *(ushort4*)(h2 + (size_t)row * D_ + tid * 4) = *(ushort4*)o;
}

// ---------------- repack qkv [bt, 3*D] -> q(SCALED),k [bh, T, 64] and v^T [bh, 64, T]
__global__ __launch_bounds__(256) void repack_qkv(const u16* __restrict__ qkv,
    u16* __restrict__ q, u16* __restrict__ k, u16* __restrict__ vt) {
  const int t0 = blockIdx.x * 64, bh = blockIdx.y;
  const int b = bh >> 4, h = bh & 15;
  const int tid = threadIdx.x;
  const int c = (tid & 7) * 8;
  __shared__ __attribute__((aligned(16))) u16 vs[64][72];
  #pragma unroll
  for (int p = 0; p < 2; p++) {
    const int tl = p * 32 + (tid >> 3);
    const size_t inrow = ((size_t)b * T_ + t0 + tl) * 3072 + h * 64;
    u16x8 qv = *(const u16x8*)(qkv + inrow + c);
    bf16x8 kv = *(const bf16x8*)(qkv + inrow + 1024 + c);
    bf16x8 vv = *(const bf16x8*)(qkv + inrow + 2048 + c);
    alignas(16) u16 qs[8];
    #pragma unroll
    for (int e = 0; e < 8; e++) {
      const float f = __builtin_bit_cast(float, ((unsigned)qv[e]) << 16) * 0.18033688011112042f;
      qs[e] = f2bf(f);
    }
    *(u16x8*)(q + ((size_t)bh * T_ + t0 + tl) * HD_ + c) = *(u16x8*)qs;
    *(bf16x8*)(k + ((size_t)bh * T_ + t0 + tl) * HD_ + c) = kv;
    *(bf16x8*)&vs[tl][c] = vv;
  }
  __syncthreads();
  const int d = tid >> 2, tc = (tid & 3) * 16;
  alignas(16) u16 tmp[16];
  #pragma unroll
  for (int j = 0; j < 16; j++) tmp[j] = vs[tc + j][d];
  *(bf16x8*)(vt + ((size_t)bh * HD_ + d) * T_ + t0 + tc)     = *(bf16x8*)&tmp[0];
  *(bf16x8*)(vt + ((size_t)bh * HD_ + d) * T_ + t0 + tc + 8) = *(bf16x8*)&tmp[8];
}

// ---------------- flash attention v5: 8-wave blocks, QBLK=128 (wave owns 16 rows),
// LPT dispatch + XCD-bh locality, lazy row-max, ones-column l, defer-max.
__global__ __launch_bounds__(512) void attn_fwd(
    const u16* __restrict__ q, const u16* __restrict__ k,
    const u16* __restrict__ vt, u16* __restrict__ out) {
  __shared__ __attribute__((aligned(16))) u16 Ps[8][16 * 64];
  __shared__ __attribute__((aligned(16))) u16 Kb[2][64 * 64];
  __shared__ __attribute__((aligned(16))) u16 Vb[2][64 * 64];

  const int bid = blockIdx.x;                // 512 blocks
  const int xcd = bid & 7, j = bid >> 3;     // j = 0..63
  const int bh  = xcd + 8 * (j & 3);         // 4 bh per xcd -> 2MB K/V, L2-resident
  const int qb  = 15 - (j >> 2);             // 0..15, largest (most work) first
  const int b = bh >> 4, h = bh & 15;
  const int tid = threadIdx.x, wid = tid >> 6, lane = tid & 63;
  const u16* kh = k  + (size_t)bh * T_ * HD_;
  const u16* vh = vt + (size_t)bh * HD_ * T_;
  const int q0 = qb * 128;
  const int nkt = 2 * qb + 2;                // kv tiles for this q-block
  const int wlast = 2 * qb + (wid >> 2);     // last kv tile this wave has unmasked cols

  const int frow = lane & 15;
  const int hi   = lane >> 4;
  const int fk   = hi * 8;
  const int rowb = hi * 4;
  const int colb = frow;
  const int srow = tid >> 3;                 // staging row 0..63
  const int gch  = (tid & 7) ^ (srow & 7);   // pre-swizzled chunk

  u16x8 onebits = (u16x8)((u16)0x3F80);
  bf16x8 b_one = (frow == 0) ? __builtin_bit_cast(bf16x8, onebits) : (bf16x8){};

  u16* Pw = &Ps[wid][0];

  const u16* qrow = q + ((size_t)bh * T_ + q0 + wid * 16 + frow) * HD_;
  bf16x8 aq[2];
  aq[0] = *(const bf16x8*)(qrow + fk);
  aq[1] = *(const bf16x8*)(qrow + 32 + fk);

  float m2[4] = {-3e38f, -3e38f, -3e38f, -3e38f};
  f32x4 acc_l = {};
  f32x4 acc_o[4] = {};

  int cur = 0;
  gload16(kh + (size_t)srow * HD_ + gch * 8, &Kb[0][(wid * 8) * 64]);
  gload16(vh + (size_t)srow * T_ + gch * 8,  &Vb[0][(wid * 8) * 64]);
  __syncthreads();

  for (int kt = 0; kt < nkt; ++kt) {
    if (kt + 1 < nkt) {
      const int nx = cur ^ 1, ktn = kt + 1;
      gload16(kh + (size_t)(ktn * 64 + srow) * HD_ + gch * 8, &Kb[nx][(wid * 8) * 64]);
      gload16(vh + (size_t)srow * T_ + ktn * 64 + gch * 8,    &Vb[nx][(wid * 8) * 64]);
    }

    if (kt <= wlast) {   // wave-uniform: skip fully-masked diagonal tiles
      const u16* Kc = &Kb[cur][0];
      const u16* Vc = &Vb[cur][0];

      // ---- QK^T (q pre-scaled by 0.125*log2e)
      float p2[4][4];
      __builtin_amdgcn_s_setprio(1);
      #pragma unroll
      for (int ni = 0; ni < 4; ni++) {
        f32x4 s = {};
        #pragma unroll
        for (int ks = 0; ks < 2; ks++) {
          const int row = ni * 16 + frow;
          const int ch  = ks * 4 + hi;
          bf16x8 bk = *(const bf16x8*)(Kc + row * 64 + ((ch ^ (row & 7)) << 3));
          s = __builtin_amdgcn_mfma_f32_16x16x32_bf16(aq[ks], bk, s, 0, 0, 0);
        }
        #pragma unroll
        for (int r = 0; r < 4; r++) p2[ni][r] = s[r];
      }
      __builtin_amdgcn_s_setprio(0);

      if (kt >= nkt - 2) {  // mask only near the diagonal
        #pragma unroll
        for (int ni = 0; ni < 4; ni++)
          #pragma unroll
          for (int r = 0; r < 4; r++) {
            const bool msk = (kt * 64 + ni * 16 + colb) > (q0 + wid * 16 + rowb + r);
            if (msk) p2[ni][r] = -3e38f;
          }
      }

      // ---- lazy row max: local check, shuffles only on rescale events
      float lmax[4];
      #pragma unroll
      for (int r = 0; r < 4; r++)
        lmax[r] = fmaxf(fmaxf(p2[0][r], p2[1][r]), fmaxf(p2[2][r], p2[3][r]));
      int ok = 1;
      #pragma unroll
      for (int r = 0; r < 4; r++) ok &= (lmax[r] <= m2[r] + 8.0f);
      if (!__all(ok)) {
        #pragma unroll
        for (int r = 0; r < 4; r++) {
          float rm = lmax[r];
          rm = fmaxf(rm, __shfl_xor(rm, 1));
          rm = fmaxf(rm, __shfl_xor(rm, 2));
          rm = fmaxf(rm, __shfl_xor(rm, 4));
          rm = fmaxf(rm, __shfl_xor(rm, 8));
          const float mnew = fmaxf(m2[r], rm);
          const float corr = exp2f(m2[r] - mnew);
          m2[r] = mnew;
          acc_l[r] *= corr;
          #pragma unroll
          for (int ni = 0; ni < 4; ni++) acc_o[ni][r] *= corr;
        }
      }
      #pragma unroll
      for (int ni = 0; ni < 4; ni++)
        #pragma unroll
        for (int r = 0; r < 4; r++) p2[ni][r] = exp2f(p2[ni][r] - m2[r]);

      // ---- P -> per-wave swizzled LDS (cvt_pk), reload as A-frag
      #pragma unroll
      for (int ni = 0; ni < 4; ni++) {
        #pragma unroll
        for (int r = 0; r < 4; r += 2) {
          const unsigned pk = cvt_pk_bf16(p2[ni][r], p2[ni][r + 1]);
          const int lr0 = rowb + r, lr1 = rowb + r + 1;
          const int ch = ni * 2 + (colb >> 3);
          Pw[lr0 * 64 + ((ch ^ (lr0 & 7)) << 3) + (colb & 7)] = (u16)pk;
          Pw[lr1 * 64 + ((ch ^ (lr1 & 7)) << 3) + (colb & 7)] = (u16)(pk >> 16);
        }
      }
      bf16x8 ap[2];
      {
        const int c0 = (0 * 4 + hi) ^ (frow & 7);
        const int c1 = (1 * 4 + hi) ^ (frow & 7);
        ap[0] = *(const bf16x8*)(Pw + frow * 64 + (c0 << 3));
        ap[1] = *(const bf16x8*)(Pw + frow * 64 + (c1 << 3));
      }

      // ---- PV (+ ones-column for l)
      __builtin_amdgcn_s_setprio(1);
      #pragma unroll
      for (int ks = 0; ks < 2; ks++)
        acc_l = __builtin_amdgcn_mfma_f32_16x16x32_bf16(ap[ks], b_one, acc_l, 0, 0, 0);
      #pragma unroll
      for (int ni = 0; ni < 4; ni++) {
        #pragma unroll
        for (int ks = 0; ks < 2; ks++) {
          const int row = ni * 16 + frow;
          const int ch  = ks * 4 + hi;
          bf16x8 bv = *(const bf16x8*)(Vc + row * 64 + ((ch ^ (row & 7)) << 3));
          acc_o[ni] = __builtin_amdgcn_mfma_f32_16x16x32_bf16(ap[ks], bv, acc_o[ni], 0, 0, 0);
        }
      }
      __builtin_amdgcn_s_setprio(0);
    }

    __syncthreads();
    cur ^= 1;
  }

  float linv[4];
  #pragma unroll
  for (int r = 0; r < 4; r++) {
    const float lv = __shfl(acc_l[r], lane & 48);
    linv[r] = 1.0f / lv;
  }
  #pragma unroll
  for (int ni = 0; ni < 4; ni++)
    #pragma unroll
    for (int r = 0; r < 4; r++) {
      const float ov = acc_o[ni][r] * linv[r];
      const size_t row = (size_t)b * T_ + q0 + wid * 16 + rowb + r;
      out[row * D_ + h * HD_ + ni * 16 + colb] = f2bf(ov);
    }
}

extern "C" void kernel_launch(void* const* d_in, const int* in_sizes, int n_in,
                              void* d_out, int out_size, void* d_ws, size_t ws_size,
                              hipStream_t stream) {
  (void)in_sizes; (void)n_in; (void)out_size; (void)ws_size;
  const float* x      = (const float*)d_in[0];
  const float* wq     = (const float*)d_in[1];
  const float* wk     = (const float*)d_in[2];
  const float* wv     = (const float*)d_in[3];
  const float* w_proj = (const float*)d_in[4];
  const float* b_proj = (const float*)d_in[5];
  const float* ln1_g  = (const float*)d_in[6];
  const float* ln1_b  = (const float*)d_in[7];
  const float* ln2_g  = (const float*)d_in[8];
  const float* ln2_b  = (const float*)d_in[9];
  const float* w1     = (const float*)d_in[10];
  const float* b1     = (const float*)d_in[11];
  const float* w2     = (const float*)d_in[12];
  const float* b2     = (const float*)d_in[13];

  uint8_t* ws = (uint8_t*)d_ws;
  const size_t MB = 1024 * 1024;
  u16* wqkv_t = (u16*)(ws + 0);        // [3072,1024]
  u16* wproj_t = (u16*)(ws + 6 * MB);  // [1024,1024]
  u16* w1t  = (u16*)(ws + 8 * MB);     // [4096,1024]
  u16* w2t  = (u16*)(ws + 16 * MB);    // [1024,4096]
  u16* hbuf = (u16*)(ws + 24 * MB);    // [4096,1024]
  u16* qkv  = (u16*)(ws + 32 * MB);    // [4096,3072]  (dead after repack)
  u16* qb   = (u16*)(ws + 56 * MB);    // [32,2048,64] (dead after attn)
  u16* kb   = (u16*)(ws + 64 * MB);    // (dead after attn)
  u16* vtb  = (u16*)(ws + 72 * MB);    // (dead after attn)
  u16* aout = (u16*)(ws + 80 * MB);    // [4096,1024]
  u16* h2   = (u16*)(ws + 88 * MB);    // [4096,1024]
  u16* ff1  = (u16*)(ws + 96 * MB);    // [4096,4096]
  float* pparts = (float*)(ws + 32 * MB);  // proj: 2 x [4096,1024] fp32 = 32 MB
  float* fparts = (float*)(ws + 32 * MB);  // ff2:  4 x [4096,1024] fp32 = 64 MB
  float* xout = (float*)d_out;

  const dim3 tb(32, 8);
  transpose_w<<<dim3(HD_/32, D_/32, H_), tb, 0, stream>>>(wq, wqkv_t, D_, HD_);
  transpose_w<<<dim3(HD_/32, D_/32, H_), tb, 0, stream>>>(wk, wqkv_t + (size_t)D_*D_, D_, HD_);
  transpose_w<<<dim3(HD_/32, D_/32, H_), tb, 0, stream>>>(wv, wqkv_t + 2*(size_t)D_*D_, D_, HD_);
  transpose_w<<<dim3(D_/32, D_/32, 1),  tb, 0, stream>>>(w_proj, wproj_t, D_, D_);
  transpose_w<<<dim3(FF_/32, D_/32, 1), tb, 0, stream>>>(w1, w1t, D_, FF_);
  transpose_w<<<dim3(D_/32, FF_/32, 1), tb, 0, stream>>>(w2, w2t, FF_, D_);

  ln_rows<<<BT_, 256, 0, stream>>>(x, ln1_g, ln1_b, hbuf);

  // QKV: [4096,1024] x [3072,1024]^T -> bf16 [4096,3072]
  gemm256<0,0,1,0><<<dim3(3072/256, BT_/256), 512, 0, stream>>>(
      hbuf, wqkv_t, nullptr, nullptr, qkv, BT_, 3072, D_, D_);

  repack_qkv<<<dim3(T_/64, B_*H_), 256, 0, stream>>>(qkv, qb, kb, vtb);

  attn_fwd<<<dim3(512), 512, 0, stream>>>(qb, kb, vtb, aout);

  // proj: split-K=2 partials, then fused reduce + bias + x-residual + LN2
  gemm256<0,0,0,1><<<dim3(D_/256, BT_/256, 2), 512, 0, stream>>>(
      aout, wproj_t, nullptr, nullptr, pparts, BT_, D_, D_, D_/2);
  reduce2_ln<<<BT_, 256, 0, stream>>>(
      pparts, b_proj, x, ln2_g, ln2_b, xout, h2, BT_*D_);

  // FF1: [4096,1024] x [4096,1024]^T -> GELU -> bf16 [4096,4096]
  gemm256<1,1,1,0><<<dim3(FF_/256, BT_/256), 512, 0, stream>>>(
      h2, w1t, b1, nullptr, ff1, BT_, FF_, D_, D_);

  // FF2: split-K=4 partials + fused reduce (bias + xout residual) -> xout in place
  gemm256<0,0,0,1><<<dim3(D_/256, BT_/256, 4), 512, 0, stream>>>(
      ff1, w2t, nullptr, nullptr, fparts, BT_, D_, FF_, FF_/4);
  reduce_parts<4><<<(BT_*D_)/1024, 256, 0, stream>>>(
      fparts, b2, xout, xout, BT_*D_, D_);
}

// Round 11
// 259.311 us; speedup vs baseline: 1.5655x; 1.0301x over previous
//
#include <hip/hip_runtime.h>
#include <hip/hip_bf16.h>
#include <cstdint>
#include <cstddef>
#include <math.h>

#define D_ 1024
#define H_ 16
#define HD_ 64
#define T_ 2048
#define B_ 2
#define FF_ 4096
#define BT_ (B_*T_)   // 4096 rows
#define NT_ 32        // T_/64 kv tiles

typedef unsigned short u16;
typedef __attribute__((ext_vector_type(8))) __bf16 bf16x8;
typedef __attribute__((ext_vector_type(8))) u16 u16x8;
typedef __attribute__((ext_vector_type(4))) float f32x4;

__device__ __forceinline__ u16 f2bf(float f) {
  unsigned u = __builtin_bit_cast(unsigned, f);
  u += 0x7FFFu + ((u >> 16) & 1u);
  return (u16)(u >> 16);
}

__device__ __forceinline__ unsigned cvt_pk_bf16(float a, float b) {
  unsigned r;
  asm("v_cvt_pk_bf16_f32 %0, %1, %2" : "=v"(r) : "v"(a), "v"(b));
  return r;
}

__device__ __forceinline__ void gload16(const void* g, void* l) {
  __builtin_amdgcn_global_load_lds((__attribute__((address_space(1))) void*)g,
                                   (__attribute__((address_space(3))) void*)l, 16, 0, 0);
}

// ---------------- fused transpose + fp32->bf16 cast of ALL weights (1 launch)
__global__ __launch_bounds__(256) void transpose_all(
    const float* __restrict__ wq, const float* __restrict__ wk,
    const float* __restrict__ wv, const float* __restrict__ w_proj,
    const float* __restrict__ w1, const float* __restrict__ w2,
    u16* __restrict__ wqkv_t, u16* __restrict__ wproj_t,
    u16* __restrict__ w1t, u16* __restrict__ w2t) {
  __shared__ float tile[32][33];
  const int bid = blockIdx.x;
  const float* in; u16* out; int R, C, tx, ty;
  if (bid < 3072) {          // wq/wk/wv: [16][1024][64] each
    const int w = bid >> 10, rem = bid & 1023;
    const int z = rem >> 6, t = rem & 63;
    tx = t & 1; ty = t >> 1;               // x: HD/32=2, y: D/32=32
    R = D_; C = HD_;
    in  = (w == 0 ? wq : w == 1 ? wk : wv) + (size_t)z * R * C;
    out = wqkv_t + (size_t)w * D_ * D_ + (size_t)z * C * R;
  } else if (bid < 4096) {   // w_proj [1024][1024]
    const int t = bid - 3072;
    tx = t & 31; ty = t >> 5;
    R = D_; C = D_; in = w_proj; out = wproj_t;
  } else if (bid < 8192) {   // w1 [1024][4096]
    const int t = bid - 4096;
    tx = t & 127; ty = t >> 7;
    R = D_; C = FF_; in = w1; out = w1t;
  } else {                   // w2 [4096][1024]
    const int t = bid - 8192;
    tx = t & 31; ty = t >> 5;
    R = FF_; C = D_; in = w2; out = w2t;
  }
  const int x = tx * 32 + threadIdx.x;
  const int y0 = ty * 32 + threadIdx.y;
  #pragma unroll
  for (int j = 0; j < 32; j += 8)
    tile[threadIdx.y + j][threadIdx.x] = in[(size_t)(y0 + j) * C + x];
  __syncthreads();
  const int orr = ty * 32 + threadIdx.x;
  const int oc0 = tx * 32 + threadIdx.y;
  #pragma unroll
  for (int j = 0; j < 32; j += 8)
    out[(size_t)(oc0 + j) * R + orr] = f2bf(tile[threadIdx.x][threadIdx.y + j]);
}

// ---------------- LayerNorm (fp32 in -> bf16 out), one row (D=1024) per block of 256
__global__ __launch_bounds__(256) void ln_rows(const float* __restrict__ x,
    const float* __restrict__ g, const float* __restrict__ bb, u16* __restrict__ out) {
  const int row = blockIdx.x, tid = threadIdx.x;
  const float4 v = ((const float4*)(x + (size_t)row * D_))[tid];
  float s = v.x + v.y + v.z + v.w;
  float sq = v.x*v.x + v.y*v.y + v.z*v.z + v.w*v.w;
  #pragma unroll
  for (int m = 1; m < 64; m <<= 1) { s += __shfl_xor(s, m); sq += __shfl_xor(sq, m); }
  __shared__ float ss[4], qs[4];
  if ((tid & 63) == 0) { ss[tid >> 6] = s; qs[tid >> 6] = sq; }
  __syncthreads();
  s  = ss[0] + ss[1] + ss[2] + ss[3];
  sq = qs[0] + qs[1] + qs[2] + qs[3];
  const float mean = s * (1.f / D_);
  const float var  = sq * (1.f / D_) - mean * mean;
  const float rstd = rsqrtf(var + 1e-5f);
  const float4 gv = ((const float4*)g)[tid];
  const float4 bv = ((const float4*)bb)[tid];
  u16 o[4];
  o[0] = f2bf((v.x - mean) * rstd * gv.x + bv.x);
  o[1] = f2bf((v.y - mean) * rstd * gv.y + bv.y);
  o[2] = f2bf((v.z - mean) * rstd * gv.z + bv.z);
  o[3] = f2bf((v.w - mean) * rstd * gv.w + bv.w);
  *(ushort4*)(out + (size_t)row * D_ + tid * 4) = *(ushort4*)o;
}

// ---------------- GEMM 128x128, BK=64, 4 waves, 64KB LDS -> 2 blocks/CU (TLP),
// counted-vmcnt stage-ahead pipeline + T1 XCD swizzle + T2 conflict-free layout.
template<int ACT, int BIAS, int OUTBF, int PARTIAL>
__global__ __launch_bounds__(256, 2) void gemm128(
    const u16* __restrict__ A, const u16* __restrict__ Bt,
    const float* __restrict__ bias, const float* resid,
    void* Cout, int M, int N, int K, int Kper) {
  __shared__ __attribute__((aligned(16))) u16 LA[2][128 * 64];
  __shared__ __attribute__((aligned(16))) u16 LB[2][128 * 64];

  const int tid = threadIdx.x;
  const int wid = tid >> 6, lane = tid & 63;
  const int wr = wid >> 1, wc = wid & 1;       // wave -> 64x64 C block
  const int frow = lane & 15, hi = lane >> 4;

  const int gx = gridDim.x;
  const int nwg = gx * gridDim.y;
  const int orig = blockIdx.y * gx + blockIdx.x;
  const int cpx = nwg >> 3;
  const int swz = (orig & 7) * cpx + (orig >> 3);
  const int bm = (swz / gx) * 128, bn = (swz % gx) * 128;
  const int z = PARTIAL ? blockIdx.z : 0;
  const int koff = z * Kper;
  const int nt = Kper >> 6;

  const u16* Atile = A + (size_t)bm * K + koff;
  const u16* Btile = Bt + (size_t)bn * K + koff;

  const int srow = tid >> 3;                  // 0..31
  const int gch  = (tid & 7) ^ (srow & 7);    // pre-swizzled 16B chunk

  f32x4 acc[4][4] = {};

  #define STAGE128(kt, db)                                                        \
    {                                                                             \
      _Pragma("unroll")                                                           \
      for (int j = 0; j < 4; j++) {                                               \
        const int rw = j * 32;                                                    \
        gload16(Atile + (size_t)(rw + srow) * K + (size_t)(kt) * 64 + gch * 8,    \
                &LA[db][(rw + wid * 8) * 64]);                                    \
        gload16(Btile + (size_t)(rw + srow) * K + (size_t)(kt) * 64 + gch * 8,    \
                &LB[db][(rw + wid * 8) * 64]);                                    \
      }                                                                           \
    }

  STAGE128(0, 0);
  asm volatile("s_waitcnt vmcnt(0)" ::: "memory");
  __builtin_amdgcn_s_barrier();

  for (int t = 0; t < nt; ++t) {
    const int db = t & 1;
    if (t + 1 < nt) {
      STAGE128(t + 1, db ^ 1);
      asm volatile("s_waitcnt vmcnt(8)" ::: "memory");   // tile t landed; t+1 in flight
    } else {
      asm volatile("s_waitcnt vmcnt(0)" ::: "memory");
    }
    __builtin_amdgcn_s_barrier();

    const u16* Ab = &LA[db][0];
    const u16* Bb = &LB[db][0];

    bf16x8 bfr[4][2];
    #pragma unroll
    for (int ni = 0; ni < 4; ni++)
      #pragma unroll
      for (int ks = 0; ks < 2; ks++) {
        const int row = wc * 64 + ni * 16 + frow;
        bfr[ni][ks] = *(const bf16x8*)(Bb + row * 64 + (((ks * 4 + hi) ^ (row & 7)) << 3));
      }
    #pragma unroll
    for (int half = 0; half < 2; half++) {
      bf16x8 af[2][2];
      #pragma unroll
      for (int m2 = 0; m2 < 2; m2++)
        #pragma unroll
        for (int ks = 0; ks < 2; ks++) {
          const int row = wr * 64 + (half * 2 + m2) * 16 + frow;
          af[m2][ks] = *(const bf16x8*)(Ab + row * 64 + (((ks * 4 + hi) ^ (row & 7)) << 3));
        }
      __builtin_amdgcn_s_setprio(1);
      #pragma unroll
      for (int m2 = 0; m2 < 2; m2++)
        #pragma unroll
        for (int ni = 0; ni < 4; ni++)
          #pragma unroll
          for (int ks = 0; ks < 2; ks++)
            acc[half * 2 + m2][ni] =
                __builtin_amdgcn_mfma_f32_16x16x32_bf16(af[m2][ks], bfr[ni][ks],
                                                        acc[half * 2 + m2][ni], 0, 0, 0);
      __builtin_amdgcn_s_setprio(0);
    }
    __builtin_amdgcn_s_barrier();   // WAR: all waves done with buf db before restage
  }
  #undef STAGE128

  const int r0 = bm + wr * 64 + hi * 4;
  const int c0 = bn + wc * 64 + frow;
  #pragma unroll
  for (int mi = 0; mi < 4; mi++) {
    #pragma unroll
    for (int ni = 0; ni < 4; ni++) {
      #pragma unroll
      for (int r = 0; r < 4; r++) {
        float v = acc[mi][ni][r];
        const int rr = r0 + mi * 16 + r;
        const int cc = c0 + ni * 16;
        if (PARTIAL) {
          ((float*)Cout)[((size_t)z * M + rr) * N + cc] = v;
        } else {
          if (BIAS) v += bias[cc];
          if (ACT == 1) {
            // tanh-approx GELU in exp2 form: v * e/(e+1), e = exp2(2*log2e*u)
            const float u = v * (0.79788456f + 0.03567740814f * v * v);
            const float e = exp2f(fminf(u * 2.885390082f, 80.f));
            v = v * e / (e + 1.0f);
          }
          if (resid) v += resid[(size_t)rr * N + cc];
          if (OUTBF) ((u16*)Cout)[(size_t)rr * N + cc] = f2bf(v);
          else       ((float*)Cout)[(size_t)rr * N + cc] = v;
        }
      }
    }
  }
}

// ---------------- split-K reduce: out = sum(parts) + bias (+resid), fp32
template<int NPART>
__global__ __launch_bounds__(256) void reduce_parts(
    const float* __restrict__ parts, const float* __restrict__ bias,
    const float* __restrict__ resid, float* __restrict__ out, int MN, int N) {
  const int i4 = (blockIdx.x * 256 + threadIdx.x) * 4;
  if (i4 >= MN) return;
  float4 s = *(const float4*)(parts + i4);
  #pragma unroll
  for (int p = 1; p < NPART; p++) {
    const float4 t = *(const float4*)(parts + (size_t)p * MN + i4);
    s.x += t.x; s.y += t.y; s.z += t.z; s.w += t.w;
  }
  const float4 bv = *(const float4*)(bias + (i4 & (N - 1)));
  const float4 rv = *(const float4*)(resid + i4);
  s.x += bv.x + rv.x; s.y += bv.y + rv.y; s.z += bv.z + rv.z; s.w += bv.w + rv.w;
  *(float4*)(out + i4) = s;
}

// ---------------- proj reduce (NPART=2) + bias + residual + LN2 fused.
__global__ __launch_bounds__(256) void reduce2_ln(
    const float* __restrict__ parts, const float* __restrict__ bias,
    const float* __restrict__ resid, const float* __restrict__ g,
    const float* __restrict__ bb, float* __restrict__ xout,
    u16* __restrict__ h2, int MN) {
  const int row = blockIdx.x, tid = threadIdx.x;
  const int i4 = row * D_ + tid * 4;
  float4 s = *(const float4*)(parts + i4);
  const float4 t = *(const float4*)(parts + (size_t)MN + i4);
  const float4 bv = *(const float4*)(bias + tid * 4);
  const float4 rv = *(const float4*)(resid + i4);
  s.x += t.x + bv.x + rv.x; s.y += t.y + bv.y + rv.y;
  s.z += t.z + bv.z + rv.z; s.w += t.w + bv.w + rv.w;
  *(float4*)(xout + i4) = s;
  float sm = s.x + s.y + s.z + s.w;
  float sq = s.x*s.x + s.y*s.y + s.z*s.z + s.w*s.w;
  #pragma unroll
  for (int m = 1; m < 64; m <<= 1) { sm += __shfl_xor(sm, m); sq += __shfl_xor(sq, m); }
  __shared__ float ss[4], qs[4];
  if ((tid & 63) == 0) { ss[tid >> 6] = sm; qs[tid >> 6] = sq; }
  __syncthreads();
  sm = ss[0] + ss[1] + ss[2] + ss[3];
  sq = qs[0] + qs[1] + qs[2] + qs[3];
  const float mean = sm * (1.f / D_);
  const float var  = sq * (1.f / D_) - mean * mean;
  const float rstd = rsqrtf(var + 1e-5f);
  const float4 gv = ((const float4*)g)[tid];
  const float4 b2v = ((const float4*)bb)[tid];
  u16 o[4];
  o[0] = f2bf((s.x - mean) * rstd * gv.x + b2v.x);
  o[1] = f2bf((s.y - mean) * rstd * gv.y + b2v.y);
  o[2] = f2bf((s.z - mean) * rstd * gv.z + b2v.z);
  o[3] = f2bf((s.w - mean) * rstd * gv.w + b2v.w);
  *(ushort4*)(h2 + (size_t)row * D_ + tid * 4) = *(ushort4*)o;
}

// ---------------- repack qkv [bt, 3*D] -> q(SCALED),k [bh, T, 64] and v^T [bh, 64, T]
__global__ __launch_bounds__(256) void repack_qkv(const u16* __restrict__ qkv,
    u16* __restrict__ q, u16* __restrict__ k, u16* __restrict__ vt) {
  const int t0 = blockIdx.x * 64, bh = blockIdx.y;
  const int b = bh >> 4, h = bh & 15;
  const int tid = threadIdx.x;
  const int c = (tid & 7) * 8;
  __shared__ __attribute__((aligned(16))) u16 vs[64][72];
  #pragma unroll
  for (int p = 0; p < 2; p++) {
    const int tl = p * 32 + (tid >> 3);
    const size_t inrow = ((size_t)b * T_ + t0 + tl) * 3072 + h * 64;
    u16x8 qv = *(const u16x8*)(qkv + inrow + c);
    bf16x8 kv = *(const bf16x8*)(qkv + inrow + 1024 + c);
    bf16x8 vv = *(const bf16x8*)(qkv + inrow + 2048 + c);
    alignas(16) u16 qs[8];
    #pragma unroll
    for (int e = 0; e < 8; e++) {
      const float f = __builtin_bit_cast(float, ((unsigned)qv[e]) << 16) * 0.18033688011112042f;
      qs[e] = f2bf(f);
    }
    *(u16x8*)(q + ((size_t)bh * T_ + t0 + tl) * HD_ + c) = *(u16x8*)qs;
    *(bf16x8*)(k + ((size_t)bh * T_ + t0 + tl) * HD_ + c) = kv;
    *(bf16x8*)&vs[tl][c] = vv;
  }
  __syncthreads();
  const int d = tid >> 2, tc = (tid & 3) * 16;
  alignas(16) u16 tmp[16];
  #pragma unroll
  for (int j = 0; j < 16; j++) tmp[j] = vs[tc + j][d];
  *(bf16x8*)(vt + ((size_t)bh * HD_ + d) * T_ + t0 + tc)     = *(bf16x8*)&tmp[0];
  *(bf16x8*)(vt + ((size_t)bh * HD_ + d) * T_ + t0 + tc + 8) = *(bf16x8*)&tmp[8];
}

// ---------------- flash attention v5: 8-wave blocks, QBLK=128 (wave owns 16 rows),
// LPT dispatch + XCD-bh locality, lazy row-max, ones-column l, defer-max.
__global__ __launch_bounds__(512) void attn_fwd(
    const u16* __restrict__ q, const u16* __restrict__ k,
    const u16* __restrict__ vt, u16* __restrict__ out) {
  __shared__ __attribute__((aligned(16))) u16 Ps[8][16 * 64];
  __shared__ __attribute__((aligned(16))) u16 Kb[2][64 * 64];
  __shared__ __attribute__((aligned(16))) u16 Vb[2][64 * 64];

  const int bid = blockIdx.x;                // 512 blocks
  const int xcd = bid & 7, j = bid >> 3;     // j = 0..63
  const int bh  = xcd + 8 * (j & 3);         // 4 bh per xcd -> 2MB K/V, L2-resident
  const int qb  = 15 - (j >> 2);             // 0..15, largest (most work) first
  const int b = bh >> 4, h = bh & 15;
  const int tid = threadIdx.x, wid = tid >> 6, lane = tid & 63;
  const u16* kh = k  + (size_t)bh * T_ * HD_;
  const u16* vh = vt + (size_t)bh * HD_ * T_;
  const int q0 = qb * 128;
  const int nkt = 2 * qb + 2;                // kv tiles for this q-block
  const int wlast = 2 * qb + (wid >> 2);     // last kv tile this wave has unmasked cols

  const int frow = lane & 15;
  const int hi   = lane >> 4;
  const int fk   = hi * 8;
  const int rowb = hi * 4;
  const int colb = frow;
  const int srow = tid >> 3;                 // staging row 0..63
  const int gch  = (tid & 7) ^ (srow & 7);   // pre-swizzled chunk

  u16x8 onebits = (u16x8)((u16)0x3F80);
  bf16x8 b_one = (frow == 0) ? __builtin_bit_cast(bf16x8, onebits) : (bf16x8){};

  u16* Pw = &Ps[wid][0];

  const u16* qrow = q + ((size_t)bh * T_ + q0 + wid * 16 + frow) * HD_;
  bf16x8 aq[2];
  aq[0] = *(const bf16x8*)(qrow + fk);
  aq[1] = *(const bf16x8*)(qrow + 32 + fk);

  float m2[4] = {-3e38f, -3e38f, -3e38f, -3e38f};
  f32x4 acc_l = {};
  f32x4 acc_o[4] = {};

  int cur = 0;
  gload16(kh + (size_t)srow * HD_ + gch * 8, &Kb[0][(wid * 8) * 64]);
  gload16(vh + (size_t)srow * T_ + gch * 8,  &Vb[0][(wid * 8) * 64]);
  __syncthreads();

  for (int kt = 0; kt < nkt; ++kt) {
    if (kt + 1 < nkt) {
      const int nx = cur ^ 1, ktn = kt + 1;
      gload16(kh + (size_t)(ktn * 64 + srow) * HD_ + gch * 8, &Kb[nx][(wid * 8) * 64]);
      gload16(vh + (size_t)srow * T_ + ktn * 64 + gch * 8,    &Vb[nx][(wid * 8) * 64]);
    }

    if (kt <= wlast) {   // wave-uniform: skip fully-masked diagonal tiles
      const u16* Kc = &Kb[cur][0];
      const u16* Vc = &Vb[cur][0];

      float p2[4][4];
      __builtin_amdgcn_s_setprio(1);
      #pragma unroll
      for (int ni = 0; ni < 4; ni++) {
        f32x4 s = {};
        #pragma unroll
        for (int ks = 0; ks < 2; ks++) {
          const int row = ni * 16 + frow;
          const int ch  = ks * 4 + hi;
          bf16x8 bk = *(const bf16x8*)(Kc + row * 64 + ((ch ^ (row & 7)) << 3));
          s = __builtin_amdgcn_mfma_f32_16x16x32_bf16(aq[ks], bk, s, 0, 0, 0);
        }
        #pragma unroll
        for (int r = 0; r < 4; r++) p2[ni][r] = s[r];
      }
      __builtin_amdgcn_s_setprio(0);

      if (kt >= nkt - 2) {  // mask only near the diagonal
        #pragma unroll
        for (int ni = 0; ni < 4; ni++)
          #pragma unroll
          for (int r = 0; r < 4; r++) {
            const bool msk = (kt * 64 + ni * 16 + colb) > (q0 + wid * 16 + rowb + r);
            if (msk) p2[ni][r] = -3e38f;
          }
      }

      float lmax[4];
      #pragma unroll
      for (int r = 0; r < 4; r++)
        lmax[r] = fmaxf(fmaxf(p2[0][r], p2[1][r]), fmaxf(p2[2][r], p2[3][r]));
      int ok = 1;
      #pragma unroll
      for (int r = 0; r < 4; r++) ok &= (lmax[r] <= m2[r] + 8.0f);
      if (!__all(ok)) {
        #pragma unroll
        for (int r = 0; r < 4; r++) {
          float rm = lmax[r];
          rm = fmaxf(rm, __shfl_xor(rm, 1));
          rm = fmaxf(rm, __shfl_xor(rm, 2));
          rm = fmaxf(rm, __shfl_xor(rm, 4));
          rm = fmaxf(rm, __shfl_xor(rm, 8));
          const float mnew = fmaxf(m2[r], rm);
          const float corr = exp2f(m2[r] - mnew);
          m2[r] = mnew;
          acc_l[r] *= corr;
          #pragma unroll
          for (int ni = 0; ni < 4; ni++) acc_o[ni][r] *= corr;
        }
      }
      #pragma unroll
      for (int ni = 0; ni < 4; ni++)
        #pragma unroll
        for (int r = 0; r < 4; r++) p2[ni][r] = exp2f(p2[ni][r] - m2[r]);

      #pragma unroll
      for (int ni = 0; ni < 4; ni++) {
        #pragma unroll
        for (int r = 0; r < 4; r += 2) {
          const unsigned pk = cvt_pk_bf16(p2[ni][r], p2[ni][r + 1]);
          const int lr0 = rowb + r, lr1 = rowb + r + 1;
          const int ch = ni * 2 + (colb >> 3);
          Pw[lr0 * 64 + ((ch ^ (lr0 & 7)) << 3) + (colb & 7)] = (u16)pk;
          Pw[lr1 * 64 + ((ch ^ (lr1 & 7)) << 3) + (colb & 7)] = (u16)(pk >> 16);
        }
      }
      bf16x8 ap[2];
      {
        const int c0 = (0 * 4 + hi) ^ (frow & 7);
        const int c1 = (1 * 4 + hi) ^ (frow & 7);
        ap[0] = *(const bf16x8*)(Pw + frow * 64 + (c0 << 3));
        ap[1] = *(const bf16x8*)(Pw + frow * 64 + (c1 << 3));
      }

      __builtin_amdgcn_s_setprio(1);
      #pragma unroll
      for (int ks = 0; ks < 2; ks++)
        acc_l = __builtin_amdgcn_mfma_f32_16x16x32_bf16(ap[ks], b_one, acc_l, 0, 0, 0);
      #pragma unroll
      for (int ni = 0; ni < 4; ni++) {
        #pragma unroll
        for (int ks = 0; ks < 2; ks++) {
          const int row = ni * 16 + frow;
          const int ch  = ks * 4 + hi;
          bf16x8 bv = *(const bf16x8*)(Vc + row * 64 + ((ch ^ (row & 7)) << 3));
          acc_o[ni] = __builtin_amdgcn_mfma_f32_16x16x32_bf16(ap[ks], bv, acc_o[ni], 0, 0, 0);
        }
      }
      __builtin_amdgcn_s_setprio(0);
    }

    __syncthreads();
    cur ^= 1;
  }

  float linv[4];
  #pragma unroll
  for (int r = 0; r < 4; r++) {
    const float lv = __shfl(acc_l[r], lane & 48);
    linv[r] = 1.0f / lv;
  }
  #pragma unroll
  for (int ni = 0; ni < 4; ni++)
    #pragma unroll
    for (int r = 0; r < 4; r++) {
      const float ov = acc_o[ni][r] * linv[r];
      const size_t row = (size_t)b * T_ + q0 + wid * 16 + rowb + r;
      out[row * D_ + h * HD_ + ni * 16 + colb] = f2bf(ov);
    }
}

extern "C" void kernel_launch(void* const* d_in, const int* in_sizes, int n_in,
                              void* d_out, int out_size, void* d_ws, size_t ws_size,
                              hipStream_t stream) {
  (void)in_sizes; (void)n_in; (void)out_size; (void)ws_size;
  const float* x      = (const float*)d_in[0];
  const float* wq     = (const float*)d_in[1];
  const float* wk     = (const float*)d_in[2];
  const float* wv     = (const float*)d_in[3];
  const float* w_proj = (const float*)d_in[4];
  const float* b_proj = (const float*)d_in[5];
  const float* ln1_g  = (const float*)d_in[6];
  const float* ln1_b  = (const float*)d_in[7];
  const float* ln2_g  = (const float*)d_in[8];
  const float* ln2_b  = (const float*)d_in[9];
  const float* w1     = (const float*)d_in[10];
  const float* b1     = (const float*)d_in[11];
  const float* w2     = (const float*)d_in[12];
  const float* b2     = (const float*)d_in[13];

  uint8_t* ws = (uint8_t*)d_ws;
  const size_t MB = 1024 * 1024;
  u16* wqkv_t = (u16*)(ws + 0);        // [3072,1024]
  u16* wproj_t = (u16*)(ws + 6 * MB);  // [1024,1024]
  u16* w1t  = (u16*)(ws + 8 * MB);     // [4096,1024]
  u16* w2t  = (u16*)(ws + 16 * MB);    // [1024,4096]
  u16* hbuf = (u16*)(ws + 24 * MB);    // [4096,1024]
  u16* qkv  = (u16*)(ws + 32 * MB);    // [4096,3072]  (dead after repack)
  u16* qb   = (u16*)(ws + 56 * MB);    // [32,2048,64] (dead after attn)
  u16* kb   = (u16*)(ws + 64 * MB);    // (dead after attn)
  u16* vtb  = (u16*)(ws + 72 * MB);    // (dead after attn)
  u16* aout = (u16*)(ws + 80 * MB);    // [4096,1024]
  u16* h2   = (u16*)(ws + 88 * MB);    // [4096,1024]
  u16* ff1  = (u16*)(ws + 96 * MB);    // [4096,4096]
  float* pparts = (float*)(ws + 32 * MB);  // proj: 2 x [4096,1024] fp32 = 32 MB
  float* fparts = (float*)(ws + 32 * MB);  // ff2:  4 x [4096,1024] fp32 = 64 MB
  float* xout = (float*)d_out;

  transpose_all<<<12288, dim3(32, 8), 0, stream>>>(
      wq, wk, wv, w_proj, w1, w2, wqkv_t, wproj_t, w1t, w2t);

  ln_rows<<<BT_, 256, 0, stream>>>(x, ln1_g, ln1_b, hbuf);

  // QKV: [4096,1024] x [3072,1024]^T -> bf16 [4096,3072]
  gemm128<0,0,1,0><<<dim3(3072/128, BT_/128), 256, 0, stream>>>(
      hbuf, wqkv_t, nullptr, nullptr, qkv, BT_, 3072, D_, D_);

  repack_qkv<<<dim3(T_/64, B_*H_), 256, 0, stream>>>(qkv, qb, kb, vtb);

  attn_fwd<<<dim3(512), 512, 0, stream>>>(qb, kb, vtb, aout);

  // proj: split-K=2 partials, then fused reduce + bias + x-residual + LN2
  gemm128<0,0,0,1><<<dim3(D_/128, BT_/128, 2), 256, 0, stream>>>(
      aout, wproj_t, nullptr, nullptr, pparts, BT_, D_, D_, D_/2);
  reduce2_ln<<<BT_, 256, 0, stream>>>(
      pparts, b_proj, x, ln2_g, ln2_b, xout, h2, BT_*D_);

  // FF1: [4096,1024] x [4096,1024]^T -> GELU -> bf16 [4096,4096]
  gemm128<1,1,1,0><<<dim3(FF_/128, BT_/128), 256, 0, stream>>>(
      h2, w1t, b1, nullptr, ff1, BT_, FF_, D_, D_);

  // FF2: split-K=4 partials + fused reduce (bias + xout residual) -> xout in place
  gemm128<0,0,0,1><<<dim3(D_/128, BT_/128, 4), 256, 0, stream>>>(
      ff1, w2t, nullptr, nullptr, fparts, BT_, D_, FF_, FF_/4);
  reduce_parts<4><<<(BT_*D_)/1024, 256, 0, stream>>>(
      fparts, b2, xout, xout, BT_*D_, D_);
}

// Round 12
// 249.174 us; speedup vs baseline: 1.6292x; 1.0407x over previous
//
#include <hip/hip_runtime.h>
#include <hip/hip_bf16.h>
#include <cstdint>
#include <cstddef>
#include <math.h>

#define D_ 1024
#define H_ 16
#define HD_ 64
#define T_ 2048
#define B_ 2
#define FF_ 4096
#define BT_ (B_*T_)   // 4096 rows
#define NT_ 32        // T_/64 kv tiles

typedef unsigned short u16;
typedef __attribute__((ext_vector_type(8))) __bf16 bf16x8;
typedef __attribute__((ext_vector_type(8))) u16 u16x8;
typedef __attribute__((ext_vector_type(4))) float f32x4;

__device__ __forceinline__ u16 f2bf(float f) {
  unsigned u = __builtin_bit_cast(unsigned, f);
  u += 0x7FFFu + ((u >> 16) & 1u);
  return (u16)(u >> 16);
}

__device__ __forceinline__ unsigned cvt_pk_bf16(float a, float b) {
  unsigned r;
  asm("v_cvt_pk_bf16_f32 %0, %1, %2" : "=v"(r) : "v"(a), "v"(b));
  return r;
}

__device__ __forceinline__ void gload16(const void* g, void* l) {
  __builtin_amdgcn_global_load_lds((__attribute__((address_space(1))) void*)g,
                                   (__attribute__((address_space(3))) void*)l, 16, 0, 0);
}

// ---------------- fused transpose + fp32->bf16 cast of ALL weights (1 launch)
__global__ __launch_bounds__(256) void transpose_all(
    const float* __restrict__ wq, const float* __restrict__ wk,
    const float* __restrict__ wv, const float* __restrict__ w_proj,
    const float* __restrict__ w1, const float* __restrict__ w2,
    u16* __restrict__ wqkv_t, u16* __restrict__ wproj_t,
    u16* __restrict__ w1t, u16* __restrict__ w2t) {
  __shared__ float tile[32][33];
  const int bid = blockIdx.x;
  const float* in; u16* out; int R, C, tx, ty;
  if (bid < 3072) {          // wq/wk/wv: [16][1024][64] each
    const int w = bid >> 10, rem = bid & 1023;
    const int z = rem >> 6, t = rem & 63;
    tx = t & 1; ty = t >> 1;
    R = D_; C = HD_;
    in  = (w == 0 ? wq : w == 1 ? wk : wv) + (size_t)z * R * C;
    out = wqkv_t + (size_t)w * D_ * D_ + (size_t)z * C * R;
  } else if (bid < 4096) {   // w_proj [1024][1024]
    const int t = bid - 3072;
    tx = t & 31; ty = t >> 5;
    R = D_; C = D_; in = w_proj; out = wproj_t;
  } else if (bid < 8192) {   // w1 [1024][4096]
    const int t = bid - 4096;
    tx = t & 127; ty = t >> 7;
    R = D_; C = FF_; in = w1; out = w1t;
  } else {                   // w2 [4096][1024]
    const int t = bid - 8192;
    tx = t & 31; ty = t >> 5;
    R = FF_; C = D_; in = w2; out = w2t;
  }
  const int x = tx * 32 + threadIdx.x;
  const int y0 = ty * 32 + threadIdx.y;
  #pragma unroll
  for (int j = 0; j < 32; j += 8)
    tile[threadIdx.y + j][threadIdx.x] = in[(size_t)(y0 + j) * C + x];
  __syncthreads();
  const int orr = ty * 32 + threadIdx.x;
  const int oc0 = tx * 32 + threadIdx.y;
  #pragma unroll
  for (int j = 0; j < 32; j += 8)
    out[(size_t)(oc0 + j) * R + orr] = f2bf(tile[threadIdx.x][threadIdx.y + j]);
}

// ---------------- LayerNorm (fp32 in -> bf16 out), one row (D=1024) per block of 256
__global__ __launch_bounds__(256) void ln_rows(const float* __restrict__ x,
    const float* __restrict__ g, const float* __restrict__ bb, u16* __restrict__ out) {
  const int row = blockIdx.x, tid = threadIdx.x;
  const float4 v = ((const float4*)(x + (size_t)row * D_))[tid];
  float s = v.x + v.y + v.z + v.w;
  float sq = v.x*v.x + v.y*v.y + v.z*v.z + v.w*v.w;
  #pragma unroll
  for (int m = 1; m < 64; m <<= 1) { s += __shfl_xor(s, m); sq += __shfl_xor(sq, m); }
  __shared__ float ss[4], qs[4];
  if ((tid & 63) == 0) { ss[tid >> 6] = s; qs[tid >> 6] = sq; }
  __syncthreads();
  s  = ss[0] + ss[1] + ss[2] + ss[3];
  sq = qs[0] + qs[1] + qs[2] + qs[3];
  const float mean = s * (1.f / D_);
  const float var  = sq * (1.f / D_) - mean * mean;
  const float rstd = rsqrtf(var + 1e-5f);
  const float4 gv = ((const float4*)g)[tid];
  const float4 bv = ((const float4*)bb)[tid];
  u16 o[4];
  o[0] = f2bf((v.x - mean) * rstd * gv.x + bv.x);
  o[1] = f2bf((v.y - mean) * rstd * gv.y + bv.y);
  o[2] = f2bf((v.z - mean) * rstd * gv.z + bv.z);
  o[3] = f2bf((v.w - mean) * rstd * gv.w + bv.w);
  *(ushort4*)(out + (size_t)row * D_ + tid * 4) = *(ushort4*)o;
}

// ---------------- GEMM 128x128, BK=32, 4 waves, 32KB LDS -> 4 blocks/CU (TLP),
// counted-vmcnt stage-ahead + T1 XCD swizzle + conflict-free chunk^row XOR layout.
// Per tile: 4 gload16/thread (2 A-pass + 2 B-pass), 8 ds_read_b128/wave, 16 MFMA/wave.
template<int ACT, int BIAS, int OUTBF, int PARTIAL>
__global__ __launch_bounds__(256, 4) void gemm128(
    const u16* __restrict__ A, const u16* __restrict__ Bt,
    const float* __restrict__ bias, const float* resid,
    void* Cout, int M, int N, int K, int Kper) {
  __shared__ __attribute__((aligned(16))) u16 LA[2][128 * 32];
  __shared__ __attribute__((aligned(16))) u16 LB[2][128 * 32];

  const int tid = threadIdx.x;
  const int wid = tid >> 6, lane = tid & 63;
  const int wr = wid >> 1, wc = wid & 1;       // wave -> 64x64 C block
  const int frow = lane & 15, hi = lane >> 4;

  const int gx = gridDim.x;
  const int nwg = gx * gridDim.y;
  const int orig = blockIdx.y * gx + blockIdx.x;
  const int cpx = nwg >> 3;
  const int swz = (orig & 7) * cpx + (orig >> 3);
  const int bm = (swz / gx) * 128, bn = (swz % gx) * 128;
  const int z = PARTIAL ? blockIdx.z : 0;
  const int koff = z * Kper;
  const int nt = Kper >> 5;

  // staging geometry: srow = tid>>2 (row within 64-row pass), chunk = tid&3,
  // global chunk pre-swizzled: gch = (tid&3) ^ (srow&3); LDS dest linear.
  const int srow = tid >> 2;
  const int gch  = (tid & 3) ^ (srow & 3);
  const u16* Ag0 = A + (size_t)(bm + srow) * K + koff + gch * 8;
  const u16* Ag1 = Ag0 + (size_t)64 * K;
  const u16* Bg0 = Bt + (size_t)(bn + srow) * K + koff + gch * 8;
  const u16* Bg1 = Bg0 + (size_t)64 * K;
  const int ldsA0 = (wid * 16) * 32, ldsA1 = (64 + wid * 16) * 32;

  f32x4 acc[4][4] = {};

  #define STAGE32(kt, db)                              \
    {                                                  \
      const int ko = (kt) * 32;                        \
      gload16(Ag0 + ko, &LA[db][ldsA0]);               \
      gload16(Ag1 + ko, &LA[db][ldsA1]);               \
      gload16(Bg0 + ko, &LB[db][ldsA0]);               \
      gload16(Bg1 + ko, &LB[db][ldsA1]);               \
    }

  STAGE32(0, 0);

  for (int t = 0; t < nt; ++t) {
    const int db = t & 1;
    if (t + 1 < nt) {
      STAGE32(t + 1, db ^ 1);
      asm volatile("s_waitcnt vmcnt(4)" ::: "memory");   // tile t landed; t+1 in flight
    } else {
      asm volatile("s_waitcnt vmcnt(0)" ::: "memory");
    }
    __builtin_amdgcn_s_barrier();

    const u16* Ab = &LA[db][0];
    const u16* Bb = &LB[db][0];

    bf16x8 af[4], bfr[4];
    #pragma unroll
    for (int i = 0; i < 4; i++) {
      const int ra = wr * 64 + i * 16 + frow;
      af[i]  = *(const bf16x8*)(Ab + ra * 32 + ((hi ^ (ra & 3)) << 3));
      const int rb = wc * 64 + i * 16 + frow;
      bfr[i] = *(const bf16x8*)(Bb + rb * 32 + ((hi ^ (rb & 3)) << 3));
    }
    __builtin_amdgcn_s_setprio(1);
    #pragma unroll
    for (int mi = 0; mi < 4; mi++)
      #pragma unroll
      for (int ni = 0; ni < 4; ni++)
        acc[mi][ni] = __builtin_amdgcn_mfma_f32_16x16x32_bf16(af[mi], bfr[ni], acc[mi][ni], 0, 0, 0);
    __builtin_amdgcn_s_setprio(0);
    __builtin_amdgcn_s_barrier();   // WAR: all waves done with buf db before restage
  }
  #undef STAGE32

  const int r0 = bm + wr * 64 + hi * 4;
  const int c0 = bn + wc * 64 + frow;
  #pragma unroll
  for (int mi = 0; mi < 4; mi++) {
    #pragma unroll
    for (int ni = 0; ni < 4; ni++) {
      #pragma unroll
      for (int r = 0; r < 4; r++) {
        float v = acc[mi][ni][r];
        const int rr = r0 + mi * 16 + r;
        const int cc = c0 + ni * 16;
        if (PARTIAL) {
          ((float*)Cout)[((size_t)z * M + rr) * N + cc] = v;
        } else {
          if (BIAS) v += bias[cc];
          if (ACT == 1) {
            // tanh-approx GELU: v*e/(1+e) = v - v*rcp(1+e), e = exp2(2*log2e*u)
            const float u = v * (0.79788456f + 0.03567740814f * v * v);
            const float e = exp2f(fminf(u * 2.885390082f, 80.f));
            v = v - v * __builtin_amdgcn_rcpf(1.0f + e);
          }
          if (resid) v += resid[(size_t)rr * N + cc];
          if (OUTBF) ((u16*)Cout)[(size_t)rr * N + cc] = f2bf(v);
          else       ((float*)Cout)[(size_t)rr * N + cc] = v;
        }
      }
    }
  }
}

// ---------------- split-K reduce: out = sum(parts) + bias (+resid), fp32
template<int NPART>
__global__ __launch_bounds__(256) void reduce_parts(
    const float* __restrict__ parts, const float* __restrict__ bias,
    const float* __restrict__ resid, float* __restrict__ out, int MN, int N) {
  const int i4 = (blockIdx.x * 256 + threadIdx.x) * 4;
  if (i4 >= MN) return;
  float4 s = *(const float4*)(parts + i4);
  #pragma unroll
  for (int p = 1; p < NPART; p++) {
    const float4 t = *(const float4*)(parts + (size_t)p * MN + i4);
    s.x += t.x; s.y += t.y; s.z += t.z; s.w += t.w;
  }
  const float4 bv = *(const float4*)(bias + (i4 & (N - 1)));
  const float4 rv = *(const float4*)(resid + i4);
  s.x += bv.x + rv.x; s.y += bv.y + rv.y; s.z += bv.z + rv.z; s.w += bv.w + rv.w;
  *(float4*)(out + i4) = s;
}

// ---------------- proj reduce (NPART=2) + bias + residual + LN2 fused.
__global__ __launch_bounds__(256) void reduce2_ln(
    const float* __restrict__ parts, const float* __restrict__ bias,
    const float* __restrict__ resid, const float* __restrict__ g,
    const float* __restrict__ bb, float* __restrict__ xout,
    u16* __restrict__ h2, int MN) {
  const int row = blockIdx.x, tid = threadIdx.x;
  const int i4 = row * D_ + tid * 4;
  float4 s = *(const float4*)(parts + i4);
  const float4 t = *(const float4*)(parts + (size_t)MN + i4);
  const float4 bv = *(const float4*)(bias + tid * 4);
  const float4 rv = *(const float4*)(resid + i4);
  s.x += t.x + bv.x + rv.x; s.y += t.y + bv.y + rv.y;
  s.z += t.z + bv.z + rv.z; s.w += t.w + bv.w + rv.w;
  *(float4*)(xout + i4) = s;
  float sm = s.x + s.y + s.z + s.w;
  float sq = s.x*s.x + s.y*s.y + s.z*s.z + s.w*s.w;
  #pragma unroll
  for (int m = 1; m < 64; m <<= 1) { sm += __shfl_xor(sm, m); sq += __shfl_xor(sq, m); }
  __shared__ float ss[4], qs[4];
  if ((tid & 63) == 0) { ss[tid >> 6] = sm; qs[tid >> 6] = sq; }
  __syncthreads();
  sm = ss[0] + ss[1] + ss[2] + ss[3];
  sq = qs[0] + qs[1] + qs[2] + qs[3];
  const float mean = sm * (1.f / D_);
  const float var  = sq * (1.f / D_) - mean * mean;
  const float rstd = rsqrtf(var + 1e-5f);
  const float4 gv = ((const float4*)g)[tid];
  const float4 b2v = ((const float4*)bb)[tid];
  u16 o[4];
  o[0] = f2bf((s.x - mean) * rstd * gv.x + b2v.x);
  o[1] = f2bf((s.y - mean) * rstd * gv.y + b2v.y);
  o[2] = f2bf((s.z - mean) * rstd * gv.z + b2v.z);
  o[3] = f2bf((s.w - mean) * rstd * gv.w + b2v.w);
  *(ushort4*)(h2 + (size_t)row * D_ + tid * 4) = *(ushort4*)o;
}

// ---------------- repack qkv [bt, 3*D] -> q(SCALED),k [bh, T, 64] and v^T [bh, 64, T]
__global__ __launch_bounds__(256) void repack_qkv(const u16* __restrict__ qkv,
    u16* __restrict__ q, u16* __restrict__ k, u16* __restrict__ vt) {
  const int t0 = blockIdx.x * 64, bh = blockIdx.y;
  const int b = bh >> 4, h = bh & 15;
  const int tid = threadIdx.x;
  const int c = (tid & 7) * 8;
  __shared__ __attribute__((aligned(16))) u16 vs[64][72];
  #pragma unroll
  for (int p = 0; p < 2; p++) {
    const int tl = p * 32 + (tid >> 3);
    const size_t inrow = ((size_t)b * T_ + t0 + tl) * 3072 + h * 64;
    u16x8 qv = *(const u16x8*)(qkv + inrow + c);
    bf16x8 kv = *(const bf16x8*)(qkv + inrow + 1024 + c);
    bf16x8 vv = *(const bf16x8*)(qkv + inrow + 2048 + c);
    alignas(16) u16 qs[8];
    #pragma unroll
    for (int e = 0; e < 8; e++) {
      const float f = __builtin_bit_cast(float, ((unsigned)qv[e]) << 16) * 0.18033688011112042f;
      qs[e] = f2bf(f);
    }
    *(u16x8*)(q + ((size_t)bh * T_ + t0 + tl) * HD_ + c) = *(u16x8*)qs;
    *(bf16x8*)(k + ((size_t)bh * T_ + t0 + tl) * HD_ + c) = kv;
    *(bf16x8*)&vs[tl][c] = vv;
  }
  __syncthreads();
  const int d = tid >> 2, tc = (tid & 3) * 16;
  alignas(16) u16 tmp[16];
  #pragma unroll
  for (int j = 0; j < 16; j++) tmp[j] = vs[tc + j][d];
  *(bf16x8*)(vt + ((size_t)bh * HD_ + d) * T_ + t0 + tc)     = *(bf16x8*)&tmp[0];
  *(bf16x8*)(vt + ((size_t)bh * HD_ + d) * T_ + t0 + tc + 8) = *(bf16x8*)&tmp[8];
}

// ---------------- flash attention v5: 8-wave blocks, QBLK=128 (wave owns 16 rows),
// LPT dispatch + XCD-bh locality, lazy row-max, ones-column l, defer-max.
__global__ __launch_bounds__(512) void attn_fwd(
    const u16* __restrict__ q, const u16* __restrict__ k,
    const u16* __restrict__ vt, u16* __restrict__ out) {
  __shared__ __attribute__((aligned(16))) u16 Ps[8][16 * 64];
  __shared__ __attribute__((aligned(16))) u16 Kb[2][64 * 64];
  __shared__ __attribute__((aligned(16))) u16 Vb[2][64 * 64];

  const int bid = blockIdx.x;                // 512 blocks
  const int xcd = bid & 7, j = bid >> 3;     // j = 0..63
  const int bh  = xcd + 8 * (j & 3);         // 4 bh per xcd -> 2MB K/V, L2-resident
  const int qb  = 15 - (j >> 2);             // 0..15, largest (most work) first
  const int b = bh >> 4, h = bh & 15;
  const int tid = threadIdx.x, wid = tid >> 6, lane = tid & 63;
  const u16* kh = k  + (size_t)bh * T_ * HD_;
  const u16* vh = vt + (size_t)bh * HD_ * T_;
  const int q0 = qb * 128;
  const int nkt = 2 * qb + 2;                // kv tiles for this q-block
  const int wlast = 2 * qb + (wid >> 2);     // last kv tile this wave has unmasked cols

  const int frow = lane & 15;
  const int hi   = lane >> 4;
  const int fk   = hi * 8;
  const int rowb = hi * 4;
  const int colb = frow;
  const int srow = tid >> 3;                 // staging row 0..63
  const int gch  = (tid & 7) ^ (srow & 7);   // pre-swizzled chunk

  u16x8 onebits = (u16x8)((u16)0x3F80);
  bf16x8 b_one = (frow == 0) ? __builtin_bit_cast(bf16x8, onebits) : (bf16x8){};

  u16* Pw = &Ps[wid][0];

  const u16* qrow = q + ((size_t)bh * T_ + q0 + wid * 16 + frow) * HD_;
  bf16x8 aq[2];
  aq[0] = *(const bf16x8*)(qrow + fk);
  aq[1] = *(const bf16x8*)(qrow + 32 + fk);

  float m2[4] = {-3e38f, -3e38f, -3e38f, -3e38f};
  f32x4 acc_l = {};
  f32x4 acc_o[4] = {};

  int cur = 0;
  gload16(kh + (size_t)srow * HD_ + gch * 8, &Kb[0][(wid * 8) * 64]);
  gload16(vh + (size_t)srow * T_ + gch * 8,  &Vb[0][(wid * 8) * 64]);
  __syncthreads();

  for (int kt = 0; kt < nkt; ++kt) {
    if (kt + 1 < nkt) {
      const int nx = cur ^ 1, ktn = kt + 1;
      gload16(kh + (size_t)(ktn * 64 + srow) * HD_ + gch * 8, &Kb[nx][(wid * 8) * 64]);
      gload16(vh + (size_t)srow * T_ + ktn * 64 + gch * 8,    &Vb[nx][(wid * 8) * 64]);
    }

    if (kt <= wlast) {   // wave-uniform: skip fully-masked diagonal tiles
      const u16* Kc = &Kb[cur][0];
      const u16* Vc = &Vb[cur][0];

      float p2[4][4];
      __builtin_amdgcn_s_setprio(1);
      #pragma unroll
      for (int ni = 0; ni < 4; ni++) {
        f32x4 s = {};
        #pragma unroll
        for (int ks = 0; ks < 2; ks++) {
          const int row = ni * 16 + frow;
          const int ch  = ks * 4 + hi;
          bf16x8 bk = *(const bf16x8*)(Kc + row * 64 + ((ch ^ (row & 7)) << 3));
          s = __builtin_amdgcn_mfma_f32_16x16x32_bf16(aq[ks], bk, s, 0, 0, 0);
        }
        #pragma unroll
        for (int r = 0; r < 4; r++) p2[ni][r] = s[r];
      }
      __builtin_amdgcn_s_setprio(0);

      if (kt >= nkt - 2) {  // mask only near the diagonal
        #pragma unroll
        for (int ni = 0; ni < 4; ni++)
          #pragma unroll
          for (int r = 0; r < 4; r++) {
            const bool msk = (kt * 64 + ni * 16 + colb) > (q0 + wid * 16 + rowb + r);
            if (msk) p2[ni][r] = -3e38f;
          }
      }

      float lmax[4];
      #pragma unroll
      for (int r = 0; r < 4; r++)
        lmax[r] = fmaxf(fmaxf(p2[0][r], p2[1][r]), fmaxf(p2[2][r], p2[3][r]));
      int ok = 1;
      #pragma unroll
      for (int r = 0; r < 4; r++) ok &= (lmax[r] <= m2[r] + 8.0f);
      if (!__all(ok)) {
        #pragma unroll
        for (int r = 0; r < 4; r++) {
          float rm = lmax[r];
          rm = fmaxf(rm, __shfl_xor(rm, 1));
          rm = fmaxf(rm, __shfl_xor(rm, 2));
          rm = fmaxf(rm, __shfl_xor(rm, 4));
          rm = fmaxf(rm, __shfl_xor(rm, 8));
          const float mnew = fmaxf(m2[r], rm);
          const float corr = exp2f(m2[r] - mnew);
          m2[r] = mnew;
          acc_l[r] *= corr;
          #pragma unroll
          for (int ni = 0; ni < 4; ni++) acc_o[ni][r] *= corr;
        }
      }
      #pragma unroll
      for (int ni = 0; ni < 4; ni++)
        #pragma unroll
        for (int r = 0; r < 4; r++) p2[ni][r] = exp2f(p2[ni][r] - m2[r]);

      #pragma unroll
      for (int ni = 0; ni < 4; ni++) {
        #pragma unroll
        for (int r = 0; r < 4; r += 2) {
          const unsigned pk = cvt_pk_bf16(p2[ni][r], p2[ni][r + 1]);
          const int lr0 = rowb + r, lr1 = rowb + r + 1;
          const int ch = ni * 2 + (colb >> 3);
          Pw[lr0 * 64 + ((ch ^ (lr0 & 7)) << 3) + (colb & 7)] = (u16)pk;
          Pw[lr1 * 64 + ((ch ^ (lr1 & 7)) << 3) + (colb & 7)] = (u16)(pk >> 16);
        }
      }
      bf16x8 ap[2];
      {
        const int c0 = (0 * 4 + hi) ^ (frow & 7);
        const int c1 = (1 * 4 + hi) ^ (frow & 7);
        ap[0] = *(const bf16x8*)(Pw + frow * 64 + (c0 << 3));
        ap[1] = *(const bf16x8*)(Pw + frow * 64 + (c1 << 3));
      }

      __builtin_amdgcn_s_setprio(1);
      #pragma unroll
      for (int ks = 0; ks < 2; ks++)
        acc_l = __builtin_amdgcn_mfma_f32_16x16x32_bf16(ap[ks], b_one, acc_l, 0, 0, 0);
      #pragma unroll
      for (int ni = 0; ni < 4; ni++) {
        #pragma unroll
        for (int ks = 0; ks < 2; ks++) {
          const int row = ni * 16 + frow;
          const int ch  = ks * 4 + hi;
          bf16x8 bv = *(const bf16x8*)(Vc + row * 64 + ((ch ^ (row & 7)) << 3));
          acc_o[ni] = __builtin_amdgcn_mfma_f32_16x16x32_bf16(ap[ks], bv, acc_o[ni], 0, 0, 0);
        }
      }
      __builtin_amdgcn_s_setprio(0);
    }

    __syncthreads();
    cur ^= 1;
  }

  float linv[4];
  #pragma unroll
  for (int r = 0; r < 4; r++) {
    const float lv = __shfl(acc_l[r], lane & 48);
    linv[r] = 1.0f / lv;
  }
  #pragma unroll
  for (int ni = 0; ni < 4; ni++)
    #pragma unroll
    for (int r = 0; r < 4; r++) {
      const float ov = acc_o[ni][r] * linv[r];
      const size_t row = (size_t)b * T_ + q0 + wid * 16 + rowb + r;
      out[row * D_ + h * HD_ + ni * 16 + colb] = f2bf(ov);
    }
}

extern "C" void kernel_launch(void* const* d_in, const int* in_sizes, int n_in,
                              void* d_out, int out_size, void* d_ws, size_t ws_size,
                              hipStream_t stream) {
  (void)in_sizes; (void)n_in; (void)out_size; (void)ws_size;
  const float* x      = (const float*)d_in[0];
  const float* wq     = (const float*)d_in[1];
  const float* wk     = (const float*)d_in[2];
  const float* wv     = (const float*)d_in[3];
  const float* w_proj = (const float*)d_in[4];
  const float* b_proj = (const float*)d_in[5];
  const float* ln1_g  = (const float*)d_in[6];
  const float* ln1_b  = (const float*)d_in[7];
  const float* ln2_g  = (const float*)d_in[8];
  const float* ln2_b  = (const float*)d_in[9];
  const float* w1     = (const float*)d_in[10];
  const float* b1     = (const float*)d_in[11];
  const float* w2     = (const float*)d_in[12];
  const float* b2     = (const float*)d_in[13];

  uint8_t* ws = (uint8_t*)d_ws;
  const size_t MB = 1024 * 1024;
  u16* wqkv_t = (u16*)(ws + 0);        // [3072,1024]
  u16* wproj_t = (u16*)(ws + 6 * MB);  // [1024,1024]
  u16* w1t  = (u16*)(ws + 8 * MB);     // [4096,1024]
  u16* w2t  = (u16*)(ws + 16 * MB);    // [1024,4096]
  u16* hbuf = (u16*)(ws + 24 * MB);    // [4096,1024]
  u16* qkv  = (u16*)(ws + 32 * MB);    // [4096,3072]  (dead after repack)
  u16* qb   = (u16*)(ws + 56 * MB);    // [32,2048,64] (dead after attn)
  u16* kb   = (u16*)(ws + 64 * MB);    // (dead after attn)
  u16* vtb  = (u16*)(ws + 72 * MB);    // (dead after attn)
  u16* aout = (u16*)(ws + 80 * MB);    // [4096,1024]
  u16* h2   = (u16*)(ws + 88 * MB);    // [4096,1024]
  u16* ff1  = (u16*)(ws + 96 * MB);    // [4096,4096]
  float* pparts = (float*)(ws + 32 * MB);  // proj: 2 x [4096,1024] fp32 = 32 MB
  float* fparts = (float*)(ws + 32 * MB);  // ff2:  4 x [4096,1024] fp32 = 64 MB
  float* xout = (float*)d_out;

  transpose_all<<<12288, dim3(32, 8), 0, stream>>>(
      wq, wk, wv, w_proj, w1, w2, wqkv_t, wproj_t, w1t, w2t);

  ln_rows<<<BT_, 256, 0, stream>>>(x, ln1_g, ln1_b, hbuf);

  // QKV: [4096,1024] x [3072,1024]^T -> bf16 [4096,3072]
  gemm128<0,0,1,0><<<dim3(3072/128, BT_/128), 256, 0, stream>>>(
      hbuf, wqkv_t, nullptr, nullptr, qkv, BT_, 3072, D_, D_);

  repack_qkv<<<dim3(T_/64, B_*H_), 256, 0, stream>>>(qkv, qb, kb, vtb);

  attn_fwd<<<dim3(512), 512, 0, stream>>>(qb, kb, vtb, aout);

  // proj: split-K=2 partials, then fused reduce + bias + x-residual + LN2
  gemm128<0,0,0,1><<<dim3(D_/128, BT_/128, 2), 256, 0, stream>>>(
      aout, wproj_t, nullptr, nullptr, pparts, BT_, D_, D_, D_/2);
  reduce2_ln<<<BT_, 256, 0, stream>>>(
      pparts, b_proj, x, ln2_g, ln2_b, xout, h2, BT_*D_);

  // FF1: [4096,1024] x [4096,1024]^T -> GELU -> bf16 [4096,4096]
  gemm128<1,1,1,0><<<dim3(FF_/128, BT_/128), 256, 0, stream>>>(
      h2, w1t, b1, nullptr, ff1, BT_, FF_, D_, D_);

  // FF2: split-K=4 partials + fused reduce (bias + xout residual) -> xout in place
  gemm128<0,0,0,1><<<dim3(D_/128, BT_/128, 4), 256, 0, stream>>>(
      ff1, w2t, nullptr, nullptr, fparts, BT_, D_, FF_, FF_/4);
  reduce_parts<4><<<(BT_*D_)/1024, 256, 0, stream>>>(
      fparts, b2, xout, xout, BT_*D_, D_);
}

// Round 13
// 248.338 us; speedup vs baseline: 1.6347x; 1.0034x over previous
//
#include <hip/hip_runtime.h>
#include <hip/hip_bf16.h>
#include <cstdint>
#include <cstddef>
#include <math.h>

#define D_ 1024
#define H_ 16
#define HD_ 64
#define T_ 2048
#define B_ 2
#define FF_ 4096
#define BT_ (B_*T_)   // 4096 rows
#define NT_ 32        // T_/64 kv tiles

typedef unsigned short u16;
typedef __attribute__((ext_vector_type(8))) __bf16 bf16x8;
typedef __attribute__((ext_vector_type(8))) u16 u16x8;
typedef __attribute__((ext_vector_type(4))) float f32x4;

__device__ __forceinline__ u16 f2bf(float f) {
  unsigned u = __builtin_bit_cast(unsigned, f);
  u += 0x7FFFu + ((u >> 16) & 1u);
  return (u16)(u >> 16);
}

__device__ __forceinline__ unsigned cvt_pk_bf16(float a, float b) {
  unsigned r;
  asm("v_cvt_pk_bf16_f32 %0, %1, %2" : "=v"(r) : "v"(a), "v"(b));
  return r;
}

__device__ __forceinline__ void gload16(const void* g, void* l) {
  __builtin_amdgcn_global_load_lds((__attribute__((address_space(1))) void*)g,
                                   (__attribute__((address_space(3))) void*)l, 16, 0, 0);
}

// ---------------- fused transpose + fp32->bf16 cast of ALL weights (1 launch)
__global__ __launch_bounds__(256) void transpose_all(
    const float* __restrict__ wq, const float* __restrict__ wk,
    const float* __restrict__ wv, const float* __restrict__ w_proj,
    const float* __restrict__ w1, const float* __restrict__ w2,
    u16* __restrict__ wqkv_t, u16* __restrict__ wproj_t,
    u16* __restrict__ w1t, u16* __restrict__ w2t) {
  __shared__ float tile[32][33];
  const int bid = blockIdx.x;
  const float* in; u16* out; int R, C, tx, ty;
  if (bid < 3072) {          // wq/wk/wv: [16][1024][64] each
    const int w = bid >> 10, rem = bid & 1023;
    const int z = rem >> 6, t = rem & 63;
    tx = t & 1; ty = t >> 1;
    R = D_; C = HD_;
    in  = (w == 0 ? wq : w == 1 ? wk : wv) + (size_t)z * R * C;
    out = wqkv_t + (size_t)w * D_ * D_ + (size_t)z * C * R;
  } else if (bid < 4096) {   // w_proj [1024][1024]
    const int t = bid - 3072;
    tx = t & 31; ty = t >> 5;
    R = D_; C = D_; in = w_proj; out = wproj_t;
  } else if (bid < 8192) {   // w1 [1024][4096]
    const int t = bid - 4096;
    tx = t & 127; ty = t >> 7;
    R = D_; C = FF_; in = w1; out = w1t;
  } else {                   // w2 [4096][1024]
    const int t = bid - 8192;
    tx = t & 31; ty = t >> 5;
    R = FF_; C = D_; in = w2; out = w2t;
  }
  const int x = tx * 32 + threadIdx.x;
  const int y0 = ty * 32 + threadIdx.y;
  #pragma unroll
  for (int j = 0; j < 32; j += 8)
    tile[threadIdx.y + j][threadIdx.x] = in[(size_t)(y0 + j) * C + x];
  __syncthreads();
  const int orr = ty * 32 + threadIdx.x;
  const int oc0 = tx * 32 + threadIdx.y;
  #pragma unroll
  for (int j = 0; j < 32; j += 8)
    out[(size_t)(oc0 + j) * R + orr] = f2bf(tile[threadIdx.x][threadIdx.y + j]);
}

// ---------------- LayerNorm (fp32 in -> bf16 out), one row (D=1024) per block of 256
__global__ __launch_bounds__(256) void ln_rows(const float* __restrict__ x,
    const float* __restrict__ g, const float* __restrict__ bb, u16* __restrict__ out) {
  const int row = blockIdx.x, tid = threadIdx.x;
  const float4 v = ((const float4*)(x + (size_t)row * D_))[tid];
  float s = v.x + v.y + v.z + v.w;
  float sq = v.x*v.x + v.y*v.y + v.z*v.z + v.w*v.w;
  #pragma unroll
  for (int m = 1; m < 64; m <<= 1) { s += __shfl_xor(s, m); sq += __shfl_xor(sq, m); }
  __shared__ float ss[4], qs[4];
  if ((tid & 63) == 0) { ss[tid >> 6] = s; qs[tid >> 6] = sq; }
  __syncthreads();
  s  = ss[0] + ss[1] + ss[2] + ss[3];
  sq = qs[0] + qs[1] + qs[2] + qs[3];
  const float mean = s * (1.f / D_);
  const float var  = sq * (1.f / D_) - mean * mean;
  const float rstd = rsqrtf(var + 1e-5f);
  const float4 gv = ((const float4*)g)[tid];
  const float4 bv = ((const float4*)bb)[tid];
  u16 o[4];
  o[0] = f2bf((v.x - mean) * rstd * gv.x + bv.x);
  o[1] = f2bf((v.y - mean) * rstd * gv.y + bv.y);
  o[2] = f2bf((v.z - mean) * rstd * gv.z + bv.z);
  o[3] = f2bf((v.w - mean) * rstd * gv.w + bv.w);
  *(ushort4*)(out + (size_t)row * D_ + tid * 4) = *(ushort4*)o;
}

// ---------------- GEMM 128x128, BK=32, 4 waves, 32KB LDS -> 4 blocks/CU,
// counted-vmcnt stage-ahead + T1 XCD swizzle + conflict-free chunk^row XOR layout.
// QKVE=1: epilogue writes the fused-QKV output directly in attention layout:
// Q (pre-scaled by 0.125*log2e) and K as [bh][T][64], V transposed as [bh][64][T].
template<int ACT, int BIAS, int OUTBF, int PARTIAL, int QKVE>
__global__ __launch_bounds__(256, 4) void gemm128(
    const u16* __restrict__ A, const u16* __restrict__ Bt,
    const float* __restrict__ bias, const float* resid,
    void* Cout, int M, int N, int K, int Kper) {
  __shared__ __attribute__((aligned(16))) u16 LA[2][128 * 32];
  __shared__ __attribute__((aligned(16))) u16 LB[2][128 * 32];

  const int tid = threadIdx.x;
  const int wid = tid >> 6, lane = tid & 63;
  const int wr = wid >> 1, wc = wid & 1;       // wave -> 64x64 C block
  const int frow = lane & 15, hi = lane >> 4;

  const int gx = gridDim.x;
  const int nwg = gx * gridDim.y;
  const int orig = blockIdx.y * gx + blockIdx.x;
  const int cpx = nwg >> 3;
  const int swz = (orig & 7) * cpx + (orig >> 3);
  const int bm = (swz / gx) * 128, bn = (swz % gx) * 128;
  const int z = PARTIAL ? blockIdx.z : 0;
  const int koff = z * Kper;
  const int nt = Kper >> 5;

  const int srow = tid >> 2;
  const int gch  = (tid & 3) ^ (srow & 3);
  const u16* Ag0 = A + (size_t)(bm + srow) * K + koff + gch * 8;
  const u16* Ag1 = Ag0 + (size_t)64 * K;
  const u16* Bg0 = Bt + (size_t)(bn + srow) * K + koff + gch * 8;
  const u16* Bg1 = Bg0 + (size_t)64 * K;
  const int ldsA0 = (wid * 16) * 32, ldsA1 = (64 + wid * 16) * 32;

  f32x4 acc[4][4] = {};

  #define STAGE32(kt, db)                              \
    {                                                  \
      const int ko = (kt) * 32;                        \
      gload16(Ag0 + ko, &LA[db][ldsA0]);               \
      gload16(Ag1 + ko, &LA[db][ldsA1]);               \
      gload16(Bg0 + ko, &LB[db][ldsA0]);               \
      gload16(Bg1 + ko, &LB[db][ldsA1]);               \
    }

  STAGE32(0, 0);

  for (int t = 0; t < nt; ++t) {
    const int db = t & 1;
    if (t + 1 < nt) {
      STAGE32(t + 1, db ^ 1);
      asm volatile("s_waitcnt vmcnt(4)" ::: "memory");   // tile t landed; t+1 in flight
    } else {
      asm volatile("s_waitcnt vmcnt(0)" ::: "memory");
    }
    __builtin_amdgcn_s_barrier();

    const u16* Ab = &LA[db][0];
    const u16* Bb = &LB[db][0];

    bf16x8 af[4], bfr[4];
    #pragma unroll
    for (int i = 0; i < 4; i++) {
      const int ra = wr * 64 + i * 16 + frow;
      af[i]  = *(const bf16x8*)(Ab + ra * 32 + ((hi ^ (ra & 3)) << 3));
      const int rb = wc * 64 + i * 16 + frow;
      bfr[i] = *(const bf16x8*)(Bb + rb * 32 + ((hi ^ (rb & 3)) << 3));
    }
    __builtin_amdgcn_s_setprio(1);
    #pragma unroll
    for (int mi = 0; mi < 4; mi++)
      #pragma unroll
      for (int ni = 0; ni < 4; ni++)
        acc[mi][ni] = __builtin_amdgcn_mfma_f32_16x16x32_bf16(af[mi], bfr[ni], acc[mi][ni], 0, 0, 0);
    __builtin_amdgcn_s_setprio(0);
    __builtin_amdgcn_s_barrier();   // WAR: all waves done with buf db before restage
  }
  #undef STAGE32

  const int r0 = bm + wr * 64 + hi * 4;
  const int c0 = bn + wc * 64 + frow;
  #pragma unroll
  for (int mi = 0; mi < 4; mi++) {
    #pragma unroll
    for (int ni = 0; ni < 4; ni++) {
      #pragma unroll
      for (int r = 0; r < 4; r++) {
        float v = acc[mi][ni][r];
        const int rr = r0 + mi * 16 + r;
        const int cc = c0 + ni * 16;
        if (QKVE) {
          // block-uniform region (bn is 128-aligned, 1024 % 128 == 0)
          const int region = bn >> 10;            // 0=Q, 1=K, 2=V
          u16* qo = (u16*)Cout;
          u16* ko = qo + (size_t)4 * 1024 * 1024; // +8MB
          u16* vo = qo + (size_t)8 * 1024 * 1024; // +16MB
          const int c1 = cc & 1023;
          const int h = c1 >> 6, d = c1 & 63;
          const int bb2 = rr >> 11, t2 = rr & 2047;
          const int bh = bb2 * 16 + h;
          if (region == 0)
            qo[((size_t)bh * T_ + t2) * HD_ + d] = f2bf(v * 0.18033688011112042f);
          else if (region == 1)
            ko[((size_t)bh * T_ + t2) * HD_ + d] = f2bf(v);
          else
            vo[((size_t)bh * HD_ + d) * T_ + t2] = f2bf(v);
        } else if (PARTIAL) {
          ((float*)Cout)[((size_t)z * M + rr) * N + cc] = v;
        } else {
          if (BIAS) v += bias[cc];
          if (ACT == 1) {
            const float u = v * (0.79788456f + 0.03567740814f * v * v);
            const float e = exp2f(fminf(u * 2.885390082f, 80.f));
            v = v - v * __builtin_amdgcn_rcpf(1.0f + e);
          }
          if (resid) v += resid[(size_t)rr * N + cc];
          if (OUTBF) ((u16*)Cout)[(size_t)rr * N + cc] = f2bf(v);
          else       ((float*)Cout)[(size_t)rr * N + cc] = v;
        }
      }
    }
  }
}

// ---------------- split-K reduce: out = sum(parts) + bias (+resid), fp32
template<int NPART>
__global__ __launch_bounds__(256) void reduce_parts(
    const float* __restrict__ parts, const float* __restrict__ bias,
    const float* __restrict__ resid, float* __restrict__ out, int MN, int N) {
  const int i4 = (blockIdx.x * 256 + threadIdx.x) * 4;
  if (i4 >= MN) return;
  float4 s = *(const float4*)(parts + i4);
  #pragma unroll
  for (int p = 1; p < NPART; p++) {
    const float4 t = *(const float4*)(parts + (size_t)p * MN + i4);
    s.x += t.x; s.y += t.y; s.z += t.z; s.w += t.w;
  }
  const float4 bv = *(const float4*)(bias + (i4 & (N - 1)));
  const float4 rv = *(const float4*)(resid + i4);
  s.x += bv.x + rv.x; s.y += bv.y + rv.y; s.z += bv.z + rv.z; s.w += bv.w + rv.w;
  *(float4*)(out + i4) = s;
}

// ---------------- proj reduce (NPART=2) + bias + residual + LN2 fused.
__global__ __launch_bounds__(256) void reduce2_ln(
    const float* __restrict__ parts, const float* __restrict__ bias,
    const float* __restrict__ resid, const float* __restrict__ g,
    const float* __restrict__ bb, float* __restrict__ xout,
    u16* __restrict__ h2, int MN) {
  const int row = blockIdx.x, tid = threadIdx.x;
  const int i4 = row * D_ + tid * 4;
  float4 s = *(const float4*)(parts + i4);
  const float4 t = *(const float4*)(parts + (size_t)MN + i4);
  const float4 bv = *(const float4*)(bias + tid * 4);
  const float4 rv = *(const float4*)(resid + i4);
  s.x += t.x + bv.x + rv.x; s.y += t.y + bv.y + rv.y;
  s.z += t.z + bv.z + rv.z; s.w += t.w + bv.w + rv.w;
  *(float4*)(xout + i4) = s;
  float sm = s.x + s.y + s.z + s.w;
  float sq = s.x*s.x + s.y*s.y + s.z*s.z + s.w*s.w;
  #pragma unroll
  for (int m = 1; m < 64; m <<= 1) { sm += __shfl_xor(sm, m); sq += __shfl_xor(sq, m); }
  __shared__ float ss[4], qs[4];
  if ((tid & 63) == 0) { ss[tid >> 6] = sm; qs[tid >> 6] = sq; }
  __syncthreads();
  sm = ss[0] + ss[1] + ss[2] + ss[3];
  sq = qs[0] + qs[1] + qs[2] + qs[3];
  const float mean = sm * (1.f / D_);
  const float var  = sq * (1.f / D_) - mean * mean;
  const float rstd = rsqrtf(var + 1e-5f);
  const float4 gv = ((const float4*)g)[tid];
  const float4 b2v = ((const float4*)bb)[tid];
  u16 o[4];
  o[0] = f2bf((s.x - mean) * rstd * gv.x + b2v.x);
  o[1] = f2bf((s.y - mean) * rstd * gv.y + b2v.y);
  o[2] = f2bf((s.z - mean) * rstd * gv.z + b2v.z);
  o[3] = f2bf((s.w - mean) * rstd * gv.w + b2v.w);
  *(ushort4*)(h2 + (size_t)row * D_ + tid * 4) = *(ushort4*)o;
}

// ---------------- flash attention v6: 8-wave blocks, QBLK=128, PAIRED q-blocks
// (qp, 15-qp) -> uniform 34 kv-tile-rounds per block; 256 blocks, XCD-bh locality.
// Lazy row-max, ones-column l, defer-max, cvt_pk P conversion.
__global__ __launch_bounds__(512) void attn_fwd(
    const u16* __restrict__ q, const u16* __restrict__ k,
    const u16* __restrict__ vt, u16* __restrict__ out) {
  __shared__ __attribute__((aligned(16))) u16 Ps[8][16 * 64];
  __shared__ __attribute__((aligned(16))) u16 Kb[2][64 * 64];
  __shared__ __attribute__((aligned(16))) u16 Vb[2][64 * 64];

  const int bid = blockIdx.x;                // 256 blocks
  const int xcd = bid & 7, j = bid >> 3;     // j = 0..31
  const int bh  = xcd + 8 * (j & 3);         // 4 bh per xcd -> 2MB K/V, L2-resident
  const int qp  = j >> 2;                    // 0..7 -> q-blocks {qp, 15-qp}
  const int b = bh >> 4, h = bh & 15;
  const int tid = threadIdx.x, wid = tid >> 6, lane = tid & 63;
  const u16* kh = k  + (size_t)bh * T_ * HD_;
  const u16* vh = vt + (size_t)bh * HD_ * T_;

  const int frow = lane & 15;
  const int hi   = lane >> 4;
  const int fk   = hi * 8;
  const int rowb = hi * 4;
  const int colb = frow;
  const int srow = tid >> 3;                 // staging row 0..63
  const int gch  = (tid & 7) ^ (srow & 7);   // pre-swizzled chunk

  u16x8 onebits = (u16x8)((u16)0x3F80);
  bf16x8 b_one = (frow == 0) ? __builtin_bit_cast(bf16x8, onebits) : (bf16x8){};

  u16* Pw = &Ps[wid][0];

  for (int qi = 0; qi < 2; ++qi) {
    const int qb = qi ? (15 - qp) : qp;
    const int q0 = qb * 128;
    const int nkt = 2 * qb + 2;
    const int wlast = 2 * qb + (wid >> 2);

    const u16* qrow = q + ((size_t)bh * T_ + q0 + wid * 16 + frow) * HD_;
    bf16x8 aq[2];
    aq[0] = *(const bf16x8*)(qrow + fk);
    aq[1] = *(const bf16x8*)(qrow + 32 + fk);

    float m2[4] = {-3e38f, -3e38f, -3e38f, -3e38f};
    f32x4 acc_l = {};
    f32x4 acc_o[4] = {};

    int cur = 0;
    gload16(kh + (size_t)srow * HD_ + gch * 8, &Kb[0][(wid * 8) * 64]);
    gload16(vh + (size_t)srow * T_ + gch * 8,  &Vb[0][(wid * 8) * 64]);
    __syncthreads();

    for (int kt = 0; kt < nkt; ++kt) {
      if (kt + 1 < nkt) {
        const int nx = cur ^ 1, ktn = kt + 1;
        gload16(kh + (size_t)(ktn * 64 + srow) * HD_ + gch * 8, &Kb[nx][(wid * 8) * 64]);
        gload16(vh + (size_t)srow * T_ + ktn * 64 + gch * 8,    &Vb[nx][(wid * 8) * 64]);
      }

      if (kt <= wlast) {   // wave-uniform: skip fully-masked diagonal tiles
        const u16* Kc = &Kb[cur][0];
        const u16* Vc = &Vb[cur][0];

        float p2[4][4];
        __builtin_amdgcn_s_setprio(1);
        #pragma unroll
        for (int ni = 0; ni < 4; ni++) {
          f32x4 s = {};
          #pragma unroll
          for (int ks = 0; ks < 2; ks++) {
            const int row = ni * 16 + frow;
            const int ch  = ks * 4 + hi;
            bf16x8 bk = *(const bf16x8*)(Kc + row * 64 + ((ch ^ (row & 7)) << 3));
            s = __builtin_amdgcn_mfma_f32_16x16x32_bf16(aq[ks], bk, s, 0, 0, 0);
          }
          #pragma unroll
          for (int r = 0; r < 4; r++) p2[ni][r] = s[r];
        }
        __builtin_amdgcn_s_setprio(0);

        if (kt >= nkt - 2) {  // mask only near the diagonal
          #pragma unroll
          for (int ni = 0; ni < 4; ni++)
            #pragma unroll
            for (int r = 0; r < 4; r++) {
              const bool msk = (kt * 64 + ni * 16 + colb) > (q0 + wid * 16 + rowb + r);
              if (msk) p2[ni][r] = -3e38f;
            }
        }

        float lmax[4];
        #pragma unroll
        for (int r = 0; r < 4; r++)
          lmax[r] = fmaxf(fmaxf(p2[0][r], p2[1][r]), fmaxf(p2[2][r], p2[3][r]));
        int ok = 1;
        #pragma unroll
        for (int r = 0; r < 4; r++) ok &= (lmax[r] <= m2[r] + 8.0f);
        if (!__all(ok)) {
          #pragma unroll
          for (int r = 0; r < 4; r++) {
            float rm = lmax[r];
            rm = fmaxf(rm, __shfl_xor(rm, 1));
            rm = fmaxf(rm, __shfl_xor(rm, 2));
            rm = fmaxf(rm, __shfl_xor(rm, 4));
            rm = fmaxf(rm, __shfl_xor(rm, 8));
            const float mnew = fmaxf(m2[r], rm);
            const float corr = exp2f(m2[r] - mnew);
            m2[r] = mnew;
            acc_l[r] *= corr;
            #pragma unroll
            for (int ni = 0; ni < 4; ni++) acc_o[ni][r] *= corr;
          }
        }
        #pragma unroll
        for (int ni = 0; ni < 4; ni++)
          #pragma unroll
          for (int r = 0; r < 4; r++) p2[ni][r] = exp2f(p2[ni][r] - m2[r]);

        #pragma unroll
        for (int ni = 0; ni < 4; ni++) {
          #pragma unroll
          for (int r = 0; r < 4; r += 2) {
            const unsigned pk = cvt_pk_bf16(p2[ni][r], p2[ni][r + 1]);
            const int lr0 = rowb + r, lr1 = rowb + r + 1;
            const int ch = ni * 2 + (colb >> 3);
            Pw[lr0 * 64 + ((ch ^ (lr0 & 7)) << 3) + (colb & 7)] = (u16)pk;
            Pw[lr1 * 64 + ((ch ^ (lr1 & 7)) << 3) + (colb & 7)] = (u16)(pk >> 16);
          }
        }
        bf16x8 ap[2];
        {
          const int c0 = (0 * 4 + hi) ^ (frow & 7);
          const int c1 = (1 * 4 + hi) ^ (frow & 7);
          ap[0] = *(const bf16x8*)(Pw + frow * 64 + (c0 << 3));
          ap[1] = *(const bf16x8*)(Pw + frow * 64 + (c1 << 3));
        }

        __builtin_amdgcn_s_setprio(1);
        #pragma unroll
        for (int ks = 0; ks < 2; ks++)
          acc_l = __builtin_amdgcn_mfma_f32_16x16x32_bf16(ap[ks], b_one, acc_l, 0, 0, 0);
        #pragma unroll
        for (int ni = 0; ni < 4; ni++) {
          #pragma unroll
          for (int ks = 0; ks < 2; ks++) {
            const int row = ni * 16 + frow;
            const int ch  = ks * 4 + hi;
            bf16x8 bv = *(const bf16x8*)(Vc + row * 64 + ((ch ^ (row & 7)) << 3));
            acc_o[ni] = __builtin_amdgcn_mfma_f32_16x16x32_bf16(ap[ks], bv, acc_o[ni], 0, 0, 0);
          }
        }
        __builtin_amdgcn_s_setprio(0);
      }

      __syncthreads();
      cur ^= 1;
    }

    float linv[4];
    #pragma unroll
    for (int r = 0; r < 4; r++) {
      const float lv = __shfl(acc_l[r], lane & 48);
      linv[r] = 1.0f / lv;
    }
    #pragma unroll
    for (int ni = 0; ni < 4; ni++)
      #pragma unroll
      for (int r = 0; r < 4; r++) {
        const float ov = acc_o[ni][r] * linv[r];
        const size_t row = (size_t)b * T_ + q0 + wid * 16 + rowb + r;
        out[row * D_ + h * HD_ + ni * 16 + colb] = f2bf(ov);
      }
  }
}

extern "C" void kernel_launch(void* const* d_in, const int* in_sizes, int n_in,
                              void* d_out, int out_size, void* d_ws, size_t ws_size,
                              hipStream_t stream) {
  (void)in_sizes; (void)n_in; (void)out_size; (void)ws_size;
  const float* x      = (const float*)d_in[0];
  const float* wq     = (const float*)d_in[1];
  const float* wk     = (const float*)d_in[2];
  const float* wv     = (const float*)d_in[3];
  const float* w_proj = (const float*)d_in[4];
  const float* b_proj = (const float*)d_in[5];
  const float* ln1_g  = (const float*)d_in[6];
  const float* ln1_b  = (const float*)d_in[7];
  const float* ln2_g  = (const float*)d_in[8];
  const float* ln2_b  = (const float*)d_in[9];
  const float* w1     = (const float*)d_in[10];
  const float* b1     = (const float*)d_in[11];
  const float* w2     = (const float*)d_in[12];
  const float* b2     = (const float*)d_in[13];

  uint8_t* ws = (uint8_t*)d_ws;
  const size_t MB = 1024 * 1024;
  u16* wqkv_t = (u16*)(ws + 0);        // [3072,1024]
  u16* wproj_t = (u16*)(ws + 6 * MB);  // [1024,1024]
  u16* w1t  = (u16*)(ws + 8 * MB);     // [4096,1024]
  u16* w2t  = (u16*)(ws + 16 * MB);    // [1024,4096]
  u16* hbuf = (u16*)(ws + 24 * MB);    // [4096,1024]
  u16* qb   = (u16*)(ws + 56 * MB);    // [32,2048,64]  Q (scaled)
  u16* kb   = (u16*)(ws + 64 * MB);    // [32,2048,64]  K   (qb+8MB)
  u16* vtb  = (u16*)(ws + 72 * MB);    // [32,64,2048]  V^T (qb+16MB)
  u16* aout = (u16*)(ws + 80 * MB);    // [4096,1024]
  u16* h2   = (u16*)(ws + 88 * MB);    // [4096,1024]
  u16* ff1  = (u16*)(ws + 96 * MB);    // [4096,4096]
  float* pparts = (float*)(ws + 32 * MB);  // proj: 2 x [4096,1024] fp32 = 32 MB
  float* fparts = (float*)(ws + 32 * MB);  // ff2:  4 x [4096,1024] fp32 = 64 MB
  float* xout = (float*)d_out;

  transpose_all<<<12288, dim3(32, 8), 0, stream>>>(
      wq, wk, wv, w_proj, w1, w2, wqkv_t, wproj_t, w1t, w2t);

  ln_rows<<<BT_, 256, 0, stream>>>(x, ln1_g, ln1_b, hbuf);

  // QKV GEMM with fused repack epilogue: writes q(scaled)/k/vt directly
  gemm128<0,0,0,0,1><<<dim3(3072/128, BT_/128), 256, 0, stream>>>(
      hbuf, wqkv_t, nullptr, nullptr, qb, BT_, 3072, D_, D_);

  attn_fwd<<<dim3(256), 512, 0, stream>>>(qb, kb, vtb, aout);

  // proj: split-K=2 partials, then fused reduce + bias + x-residual + LN2
  gemm128<0,0,0,1,0><<<dim3(D_/128, BT_/128, 2), 256, 0, stream>>>(
      aout, wproj_t, nullptr, nullptr, pparts, BT_, D_, D_, D_/2);
  reduce2_ln<<<BT_, 256, 0, stream>>>(
      pparts, b_proj, x, ln2_g, ln2_b, xout, h2, BT_*D_);

  // FF1: [4096,1024] x [4096,1024]^T -> GELU -> bf16 [4096,4096]
  gemm128<1,1,1,0,0><<<dim3(FF_/128, BT_/128), 256, 0, stream>>>(
      h2, w1t, b1, nullptr, ff1, BT_, FF_, D_, D_);

  // FF2: split-K=4 partials + fused reduce (bias + xout residual) -> xout in place
  gemm128<0,0,0,1,0><<<dim3(D_/128, BT_/128, 4), 256, 0, stream>>>(
      ff1, w2t, nullptr, nullptr, fparts, BT_, D_, FF_, FF_/4);
  reduce_parts<4><<<(BT_*D_)/1024, 256, 0, stream>>>(
      fparts, b2, xout, xout, BT_*D_, D_);
}

// Round 14
// 246.251 us; speedup vs baseline: 1.6486x; 1.0085x over previous
//
#include <hip/hip_runtime.h>
#include <hip/hip_bf16.h>
#include <cstdint>
#include <cstddef>
#include <math.h>

#define D_ 1024
#define H_ 16
#define HD_ 64
#define T_ 2048
#define B_ 2
#define FF_ 4096
#define BT_ (B_*T_)   // 4096 rows
#define NT_ 32        // T_/64 kv tiles

typedef unsigned short u16;
typedef __attribute__((ext_vector_type(8))) __bf16 bf16x8;
typedef __attribute__((ext_vector_type(8))) u16 u16x8;
typedef __attribute__((ext_vector_type(4))) float f32x4;

__device__ __forceinline__ u16 f2bf(float f) {
  unsigned u = __builtin_bit_cast(unsigned, f);
  u += 0x7FFFu + ((u >> 16) & 1u);
  return (u16)(u >> 16);
}

__device__ __forceinline__ unsigned cvt_pk_bf16(float a, float b) {
  unsigned r;
  asm("v_cvt_pk_bf16_f32 %0, %1, %2" : "=v"(r) : "v"(a), "v"(b));
  return r;
}

__device__ __forceinline__ void gload16(const void* g, void* l) {
  __builtin_amdgcn_global_load_lds((__attribute__((address_space(1))) void*)g,
                                   (__attribute__((address_space(3))) void*)l, 16, 0, 0);
}

// ---------------- fused transpose + fp32->bf16 cast of ALL weights (1 launch)
__global__ __launch_bounds__(256) void transpose_all(
    const float* __restrict__ wq, const float* __restrict__ wk,
    const float* __restrict__ wv, const float* __restrict__ w_proj,
    const float* __restrict__ w1, const float* __restrict__ w2,
    u16* __restrict__ wqkv_t, u16* __restrict__ wproj_t,
    u16* __restrict__ w1t, u16* __restrict__ w2t) {
  __shared__ float tile[32][33];
  const int bid = blockIdx.x;
  const float* in; u16* out; int R, C, tx, ty;
  if (bid < 3072) {          // wq/wk/wv: [16][1024][64] each
    const int w = bid >> 10, rem = bid & 1023;
    const int z = rem >> 6, t = rem & 63;
    tx = t & 1; ty = t >> 1;
    R = D_; C = HD_;
    in  = (w == 0 ? wq : w == 1 ? wk : wv) + (size_t)z * R * C;
    out = wqkv_t + (size_t)w * D_ * D_ + (size_t)z * C * R;
  } else if (bid < 4096) {   // w_proj [1024][1024]
    const int t = bid - 3072;
    tx = t & 31; ty = t >> 5;
    R = D_; C = D_; in = w_proj; out = wproj_t;
  } else if (bid < 8192) {   // w1 [1024][4096]
    const int t = bid - 4096;
    tx = t & 127; ty = t >> 7;
    R = D_; C = FF_; in = w1; out = w1t;
  } else {                   // w2 [4096][1024]
    const int t = bid - 8192;
    tx = t & 31; ty = t >> 5;
    R = FF_; C = D_; in = w2; out = w2t;
  }
  const int x = tx * 32 + threadIdx.x;
  const int y0 = ty * 32 + threadIdx.y;
  #pragma unroll
  for (int j = 0; j < 32; j += 8)
    tile[threadIdx.y + j][threadIdx.x] = in[(size_t)(y0 + j) * C + x];
  __syncthreads();
  const int orr = ty * 32 + threadIdx.x;
  const int oc0 = tx * 32 + threadIdx.y;
  #pragma unroll
  for (int j = 0; j < 32; j += 8)
    out[(size_t)(oc0 + j) * R + orr] = f2bf(tile[threadIdx.x][threadIdx.y + j]);
}

// ---------------- LayerNorm (fp32 in -> bf16 out), one row (D=1024) per block of 256
__global__ __launch_bounds__(256) void ln_rows(const float* __restrict__ x,
    const float* __restrict__ g, const float* __restrict__ bb, u16* __restrict__ out) {
  const int row = blockIdx.x, tid = threadIdx.x;
  const float4 v = ((const float4*)(x + (size_t)row * D_))[tid];
  float s = v.x + v.y + v.z + v.w;
  float sq = v.x*v.x + v.y*v.y + v.z*v.z + v.w*v.w;
  #pragma unroll
  for (int m = 1; m < 64; m <<= 1) { s += __shfl_xor(s, m); sq += __shfl_xor(sq, m); }
  __shared__ float ss[4], qs[4];
  if ((tid & 63) == 0) { ss[tid >> 6] = s; qs[tid >> 6] = sq; }
  __syncthreads();
  s  = ss[0] + ss[1] + ss[2] + ss[3];
  sq = qs[0] + qs[1] + qs[2] + qs[3];
  const float mean = s * (1.f / D_);
  const float var  = sq * (1.f / D_) - mean * mean;
  const float rstd = rsqrtf(var + 1e-5f);
  const float4 gv = ((const float4*)g)[tid];
  const float4 bv = ((const float4*)bb)[tid];
  u16 o[4];
  o[0] = f2bf((v.x - mean) * rstd * gv.x + bv.x);
  o[1] = f2bf((v.y - mean) * rstd * gv.y + bv.y);
  o[2] = f2bf((v.z - mean) * rstd * gv.z + bv.z);
  o[3] = f2bf((v.w - mean) * rstd * gv.w + bv.w);
  *(ushort4*)(out + (size_t)row * D_ + tid * 4) = *(ushort4*)o;
}

// ---------------- GEMM 128x128, BK=32, 4 waves, 32KB LDS -> 4 blocks/CU,
// counted-vmcnt stage-ahead + T1 XCD swizzle + conflict-free chunk^row XOR layout.
// QKVE=1: epilogue writes the fused-QKV output directly in attention layout.
template<int ACT, int BIAS, int OUTBF, int PARTIAL, int QKVE>
__global__ __launch_bounds__(256, 4) void gemm128(
    const u16* __restrict__ A, const u16* __restrict__ Bt,
    const float* __restrict__ bias, const float* resid,
    void* Cout, int M, int N, int K, int Kper) {
  __shared__ __attribute__((aligned(16))) u16 LA[2][128 * 32];
  __shared__ __attribute__((aligned(16))) u16 LB[2][128 * 32];

  const int tid = threadIdx.x;
  const int wid = tid >> 6, lane = tid & 63;
  const int wr = wid >> 1, wc = wid & 1;       // wave -> 64x64 C block
  const int frow = lane & 15, hi = lane >> 4;

  const int gx = gridDim.x;
  const int nwg = gx * gridDim.y;
  const int orig = blockIdx.y * gx + blockIdx.x;
  const int cpx = nwg >> 3;
  const int swz = (orig & 7) * cpx + (orig >> 3);
  const int bm = (swz / gx) * 128, bn = (swz % gx) * 128;
  const int z = PARTIAL ? blockIdx.z : 0;
  const int koff = z * Kper;
  const int nt = Kper >> 5;

  const int srow = tid >> 2;
  const int gch  = (tid & 3) ^ (srow & 3);
  const u16* Ag0 = A + (size_t)(bm + srow) * K + koff + gch * 8;
  const u16* Ag1 = Ag0 + (size_t)64 * K;
  const u16* Bg0 = Bt + (size_t)(bn + srow) * K + koff + gch * 8;
  const u16* Bg1 = Bg0 + (size_t)64 * K;
  const int ldsA0 = (wid * 16) * 32, ldsA1 = (64 + wid * 16) * 32;

  f32x4 acc[4][4] = {};

  #define STAGE32(kt, db)                              \
    {                                                  \
      const int ko = (kt) * 32;                        \
      gload16(Ag0 + ko, &LA[db][ldsA0]);               \
      gload16(Ag1 + ko, &LA[db][ldsA1]);               \
      gload16(Bg0 + ko, &LB[db][ldsA0]);               \
      gload16(Bg1 + ko, &LB[db][ldsA1]);               \
    }

  STAGE32(0, 0);

  for (int t = 0; t < nt; ++t) {
    const int db = t & 1;
    if (t + 1 < nt) {
      STAGE32(t + 1, db ^ 1);
      asm volatile("s_waitcnt vmcnt(4)" ::: "memory");   // tile t landed; t+1 in flight
    } else {
      asm volatile("s_waitcnt vmcnt(0)" ::: "memory");
    }
    __builtin_amdgcn_s_barrier();

    const u16* Ab = &LA[db][0];
    const u16* Bb = &LB[db][0];

    bf16x8 af[4], bfr[4];
    #pragma unroll
    for (int i = 0; i < 4; i++) {
      const int ra = wr * 64 + i * 16 + frow;
      af[i]  = *(const bf16x8*)(Ab + ra * 32 + ((hi ^ (ra & 3)) << 3));
      const int rb = wc * 64 + i * 16 + frow;
      bfr[i] = *(const bf16x8*)(Bb + rb * 32 + ((hi ^ (rb & 3)) << 3));
    }
    __builtin_amdgcn_s_setprio(1);
    #pragma unroll
    for (int mi = 0; mi < 4; mi++)
      #pragma unroll
      for (int ni = 0; ni < 4; ni++)
        acc[mi][ni] = __builtin_amdgcn_mfma_f32_16x16x32_bf16(af[mi], bfr[ni], acc[mi][ni], 0, 0, 0);
    __builtin_amdgcn_s_setprio(0);
    __builtin_amdgcn_s_barrier();   // WAR: all waves done with buf db before restage
  }
  #undef STAGE32

  const int r0 = bm + wr * 64 + hi * 4;
  const int c0 = bn + wc * 64 + frow;
  #pragma unroll
  for (int mi = 0; mi < 4; mi++) {
    #pragma unroll
    for (int ni = 0; ni < 4; ni++) {
      #pragma unroll
      for (int r = 0; r < 4; r++) {
        float v = acc[mi][ni][r];
        const int rr = r0 + mi * 16 + r;
        const int cc = c0 + ni * 16;
        if (QKVE) {
          const int region = bn >> 10;            // 0=Q, 1=K, 2=V
          u16* qo = (u16*)Cout;
          u16* ko = qo + (size_t)4 * 1024 * 1024; // +8MB
          u16* vo = qo + (size_t)8 * 1024 * 1024; // +16MB
          const int c1 = cc & 1023;
          const int h = c1 >> 6, d = c1 & 63;
          const int bb2 = rr >> 11, t2 = rr & 2047;
          const int bh = bb2 * 16 + h;
          if (region == 0)
            qo[((size_t)bh * T_ + t2) * HD_ + d] = f2bf(v * 0.18033688011112042f);
          else if (region == 1)
            ko[((size_t)bh * T_ + t2) * HD_ + d] = f2bf(v);
          else
            vo[((size_t)bh * HD_ + d) * T_ + t2] = f2bf(v);
        } else if (PARTIAL) {
          ((float*)Cout)[((size_t)z * M + rr) * N + cc] = v;
        } else {
          if (BIAS) v += bias[cc];
          if (ACT == 1) {
            const float u = v * (0.79788456f + 0.03567740814f * v * v);
            const float e = exp2f(fminf(u * 2.885390082f, 80.f));
            v = v - v * __builtin_amdgcn_rcpf(1.0f + e);
          }
          if (resid) v += resid[(size_t)rr * N + cc];
          if (OUTBF) ((u16*)Cout)[(size_t)rr * N + cc] = f2bf(v);
          else       ((float*)Cout)[(size_t)rr * N + cc] = v;
        }
      }
    }
  }
}

// ---------------- split-K reduce: out = sum(parts) + bias (+resid), fp32
template<int NPART>
__global__ __launch_bounds__(256) void reduce_parts(
    const float* __restrict__ parts, const float* __restrict__ bias,
    const float* __restrict__ resid, float* __restrict__ out, int MN, int N) {
  const int i4 = (blockIdx.x * 256 + threadIdx.x) * 4;
  if (i4 >= MN) return;
  float4 s = *(const float4*)(parts + i4);
  #pragma unroll
  for (int p = 1; p < NPART; p++) {
    const float4 t = *(const float4*)(parts + (size_t)p * MN + i4);
    s.x += t.x; s.y += t.y; s.z += t.z; s.w += t.w;
  }
  const float4 bv = *(const float4*)(bias + (i4 & (N - 1)));
  const float4 rv = *(const float4*)(resid + i4);
  s.x += bv.x + rv.x; s.y += bv.y + rv.y; s.z += bv.z + rv.z; s.w += bv.w + rv.w;
  *(float4*)(out + i4) = s;
}

// ---------------- proj reduce (NPART=2) + bias + residual + LN2 fused.
__global__ __launch_bounds__(256) void reduce2_ln(
    const float* __restrict__ parts, const float* __restrict__ bias,
    const float* __restrict__ resid, const float* __restrict__ g,
    const float* __restrict__ bb, float* __restrict__ xout,
    u16* __restrict__ h2, int MN) {
  const int row = blockIdx.x, tid = threadIdx.x;
  const int i4 = row * D_ + tid * 4;
  float4 s = *(const float4*)(parts + i4);
  const float4 t = *(const float4*)(parts + (size_t)MN + i4);
  const float4 bv = *(const float4*)(bias + tid * 4);
  const float4 rv = *(const float4*)(resid + i4);
  s.x += t.x + bv.x + rv.x; s.y += t.y + bv.y + rv.y;
  s.z += t.z + bv.z + rv.z; s.w += t.w + bv.w + rv.w;
  *(float4*)(xout + i4) = s;
  float sm = s.x + s.y + s.z + s.w;
  float sq = s.x*s.x + s.y*s.y + s.z*s.z + s.w*s.w;
  #pragma unroll
  for (int m = 1; m < 64; m <<= 1) { sm += __shfl_xor(sm, m); sq += __shfl_xor(sq, m); }
  __shared__ float ss[4], qs[4];
  if ((tid & 63) == 0) { ss[tid >> 6] = sm; qs[tid >> 6] = sq; }
  __syncthreads();
  sm = ss[0] + ss[1] + ss[2] + ss[3];
  sq = qs[0] + qs[1] + qs[2] + qs[3];
  const float mean = sm * (1.f / D_);
  const float var  = sq * (1.f / D_) - mean * mean;
  const float rstd = rsqrtf(var + 1e-5f);
  const float4 gv = ((const float4*)g)[tid];
  const float4 b2v = ((const float4*)bb)[tid];
  u16 o[4];
  o[0] = f2bf((s.x - mean) * rstd * gv.x + b2v.x);
  o[1] = f2bf((s.y - mean) * rstd * gv.y + b2v.y);
  o[2] = f2bf((s.z - mean) * rstd * gv.z + b2v.z);
  o[3] = f2bf((s.w - mean) * rstd * gv.w + b2v.w);
  *(ushort4*)(h2 + (size_t)row * D_ + tid * 4) = *(ushort4*)o;
}

// ---------------- flash attention v7: 4-wave blocks, QBLK=64 (wave owns 16 rows),
// paired q-blocks (qb, 31-qb) -> 512 blocks x uniform 33 kv-tile rounds,
// 2 independent blocks/CU (separate barrier domains backfill each other's stalls).
// XCD-bh L2 locality, lazy row-max, ones-column l, defer-max, cvt_pk.
__global__ __launch_bounds__(256, 2) void attn_fwd(
    const u16* __restrict__ q, const u16* __restrict__ k,
    const u16* __restrict__ vt, u16* __restrict__ out) {
  __shared__ __attribute__((aligned(16))) u16 Ps[4][16 * 64];   // 8KB
  __shared__ __attribute__((aligned(16))) u16 Kb[2][64 * 64];   // 16KB
  __shared__ __attribute__((aligned(16))) u16 Vb[2][64 * 64];   // 16KB

  const int bid = blockIdx.x;                // 512 blocks
  const int xcd = bid & 7, j = bid >> 3;     // j = 0..63
  const int bh  = xcd + 8 * (j & 3);         // 4 bh per xcd -> 2MB K/V, L2-resident
  const int qp  = j >> 2;                    // 0..15 -> q-blocks {qp, 31-qp}
  const int b = bh >> 4, h = bh & 15;
  const int tid = threadIdx.x, wid = tid >> 6, lane = tid & 63;
  const u16* kh = k  + (size_t)bh * T_ * HD_;
  const u16* vh = vt + (size_t)bh * HD_ * T_;

  const int frow = lane & 15;
  const int hi   = lane >> 4;
  const int fk   = hi * 8;
  const int rowb = hi * 4;
  const int colb = frow;
  const int srow = tid >> 3;                 // staging row 0..31 (per 32-row pass)
  const int gch  = (tid & 7) ^ (srow & 7);   // pre-swizzled chunk

  u16x8 onebits = (u16x8)((u16)0x3F80);
  bf16x8 b_one = (frow == 0) ? __builtin_bit_cast(bf16x8, onebits) : (bf16x8){};

  u16* Pw = &Ps[wid][0];

  for (int qi = 0; qi < 2; ++qi) {
    const int qb = qi ? (31 - qp) : qp;      // q-block of 64 rows
    const int q0 = qb * 64;
    const int nkt = qb + 1;

    const u16* qrow = q + ((size_t)bh * T_ + q0 + wid * 16 + frow) * HD_;
    bf16x8 aq[2];
    aq[0] = *(const bf16x8*)(qrow + fk);
    aq[1] = *(const bf16x8*)(qrow + 32 + fk);

    float m2[4] = {-3e38f, -3e38f, -3e38f, -3e38f};
    f32x4 acc_l = {};
    f32x4 acc_o[4] = {};

    int cur = 0;
    #pragma unroll
    for (int p = 0; p < 2; p++) {
      gload16(kh + (size_t)(p * 32 + srow) * HD_ + gch * 8, &Kb[0][(p * 32 + wid * 8) * 64]);
      gload16(vh + (size_t)(p * 32 + srow) * T_ + gch * 8,  &Vb[0][(p * 32 + wid * 8) * 64]);
    }
    __syncthreads();

    for (int kt = 0; kt < nkt; ++kt) {
      if (kt + 1 < nkt) {
        const int nx = cur ^ 1, ktn = kt + 1;
        #pragma unroll
        for (int p = 0; p < 2; p++) {
          gload16(kh + (size_t)(ktn * 64 + p * 32 + srow) * HD_ + gch * 8,
                  &Kb[nx][(p * 32 + wid * 8) * 64]);
          gload16(vh + (size_t)(p * 32 + srow) * T_ + ktn * 64 + gch * 8,
                  &Vb[nx][(p * 32 + wid * 8) * 64]);
        }
      }

      const u16* Kc = &Kb[cur][0];
      const u16* Vc = &Vb[cur][0];

      // ---- QK^T (q pre-scaled by 0.125*log2e)
      float p2[4][4];
      __builtin_amdgcn_s_setprio(1);
      #pragma unroll
      for (int ni = 0; ni < 4; ni++) {
        f32x4 s = {};
        #pragma unroll
        for (int ks = 0; ks < 2; ks++) {
          const int row = ni * 16 + frow;
          const int ch  = ks * 4 + hi;
          bf16x8 bk = *(const bf16x8*)(Kc + row * 64 + ((ch ^ (row & 7)) << 3));
          s = __builtin_amdgcn_mfma_f32_16x16x32_bf16(aq[ks], bk, s, 0, 0, 0);
        }
        #pragma unroll
        for (int r = 0; r < 4; r++) p2[ni][r] = s[r];
      }
      __builtin_amdgcn_s_setprio(0);

      if (kt == nkt - 1) {  // diagonal tile: mask cols > row
        #pragma unroll
        for (int ni = 0; ni < 4; ni++)
          #pragma unroll
          for (int r = 0; r < 4; r++) {
            const bool msk = (ni * 16 + colb) > (wid * 16 + rowb + r);
            if (msk) p2[ni][r] = -3e38f;
          }
      }

      // ---- lazy row max: local check, shuffles only on rescale events
      float lmax[4];
      #pragma unroll
      for (int r = 0; r < 4; r++)
        lmax[r] = fmaxf(fmaxf(p2[0][r], p2[1][r]), fmaxf(p2[2][r], p2[3][r]));
      int ok = 1;
      #pragma unroll
      for (int r = 0; r < 4; r++) ok &= (lmax[r] <= m2[r] + 8.0f);
      if (!__all(ok)) {
        #pragma unroll
        for (int r = 0; r < 4; r++) {
          float rm = lmax[r];
          rm = fmaxf(rm, __shfl_xor(rm, 1));
          rm = fmaxf(rm, __shfl_xor(rm, 2));
          rm = fmaxf(rm, __shfl_xor(rm, 4));
          rm = fmaxf(rm, __shfl_xor(rm, 8));
          const float mnew = fmaxf(m2[r], rm);
          const float corr = exp2f(m2[r] - mnew);
          m2[r] = mnew;
          acc_l[r] *= corr;
          #pragma unroll
          for (int ni = 0; ni < 4; ni++) acc_o[ni][r] *= corr;
        }
      }
      #pragma unroll
      for (int ni = 0; ni < 4; ni++)
        #pragma unroll
        for (int r = 0; r < 4; r++) p2[ni][r] = exp2f(p2[ni][r] - m2[r]);

      // ---- P -> per-wave swizzled LDS (cvt_pk), reload as A-frag
      #pragma unroll
      for (int ni = 0; ni < 4; ni++) {
        #pragma unroll
        for (int r = 0; r < 4; r += 2) {
          const unsigned pk = cvt_pk_bf16(p2[ni][r], p2[ni][r + 1]);
          const int lr0 = rowb + r, lr1 = rowb + r + 1;
          const int ch = ni * 2 + (colb >> 3);
          Pw[lr0 * 64 + ((ch ^ (lr0 & 7)) << 3) + (colb & 7)] = (u16)pk;
          Pw[lr1 * 64 + ((ch ^ (lr1 & 7)) << 3) + (colb & 7)] = (u16)(pk >> 16);
        }
      }
      bf16x8 ap[2];
      {
        const int c0 = (0 * 4 + hi) ^ (frow & 7);
        const int c1 = (1 * 4 + hi) ^ (frow & 7);
        ap[0] = *(const bf16x8*)(Pw + frow * 64 + (c0 << 3));
        ap[1] = *(const bf16x8*)(Pw + frow * 64 + (c1 << 3));
      }

      // ---- PV (+ ones-column for l)
      __builtin_amdgcn_s_setprio(1);
      #pragma unroll
      for (int ks = 0; ks < 2; ks++)
        acc_l = __builtin_amdgcn_mfma_f32_16x16x32_bf16(ap[ks], b_one, acc_l, 0, 0, 0);
      #pragma unroll
      for (int ni = 0; ni < 4; ni++) {
        #pragma unroll
        for (int ks = 0; ks < 2; ks++) {
          const int row = ni * 16 + frow;
          const int ch  = ks * 4 + hi;
          bf16x8 bv = *(const bf16x8*)(Vc + row * 64 + ((ch ^ (row & 7)) << 3));
          acc_o[ni] = __builtin_amdgcn_mfma_f32_16x16x32_bf16(ap[ks], bv, acc_o[ni], 0, 0, 0);
        }
      }
      __builtin_amdgcn_s_setprio(0);

      __syncthreads();
      cur ^= 1;
    }

    float linv[4];
    #pragma unroll
    for (int r = 0; r < 4; r++) {
      const float lv = __shfl(acc_l[r], lane & 48);
      linv[r] = 1.0f / lv;
    }
    #pragma unroll
    for (int ni = 0; ni < 4; ni++)
      #pragma unroll
      for (int r = 0; r < 4; r++) {
        const float ov = acc_o[ni][r] * linv[r];
        const size_t row = (size_t)b * T_ + q0 + wid * 16 + rowb + r;
        out[row * D_ + h * HD_ + ni * 16 + colb] = f2bf(ov);
      }
  }
}

extern "C" void kernel_launch(void* const* d_in, const int* in_sizes, int n_in,
                              void* d_out, int out_size, void* d_ws, size_t ws_size,
                              hipStream_t stream) {
  (void)in_sizes; (void)n_in; (void)out_size; (void)ws_size;
  const float* x      = (const float*)d_in[0];
  const float* wq     = (const float*)d_in[1];
  const float* wk     = (const float*)d_in[2];
  const float* wv     = (const float*)d_in[3];
  const float* w_proj = (const float*)d_in[4];
  const float* b_proj = (const float*)d_in[5];
  const float* ln1_g  = (const float*)d_in[6];
  const float* ln1_b  = (const float*)d_in[7];
  const float* ln2_g  = (const float*)d_in[8];
  const float* ln2_b  = (const float*)d_in[9];
  const float* w1     = (const float*)d_in[10];
  const float* b1     = (const float*)d_in[11];
  const float* w2     = (const float*)d_in[12];
  const float* b2     = (const float*)d_in[13];

  uint8_t* ws = (uint8_t*)d_ws;
  const size_t MB = 1024 * 1024;
  u16* wqkv_t = (u16*)(ws + 0);        // [3072,1024]
  u16* wproj_t = (u16*)(ws + 6 * MB);  // [1024,1024]
  u16* w1t  = (u16*)(ws + 8 * MB);     // [4096,1024]
  u16* w2t  = (u16*)(ws + 16 * MB);    // [1024,4096]
  u16* hbuf = (u16*)(ws + 24 * MB);    // [4096,1024]
  u16* qb   = (u16*)(ws + 56 * MB);    // [32,2048,64]  Q (scaled)
  u16* kb   = (u16*)(ws + 64 * MB);    // [32,2048,64]  K   (qb+8MB)
  u16* vtb  = (u16*)(ws + 72 * MB);    // [32,64,2048]  V^T (qb+16MB)
  u16* aout = (u16*)(ws + 80 * MB);    // [4096,1024]
  u16* h2   = (u16*)(ws + 88 * MB);    // [4096,1024]
  u16* ff1  = (u16*)(ws + 96 * MB);    // [4096,4096]
  float* pparts = (float*)(ws + 32 * MB);  // proj: 2 x [4096,1024] fp32 = 32 MB
  float* fparts = (float*)(ws + 32 * MB);  // ff2:  4 x [4096,1024] fp32 = 64 MB
  float* xout = (float*)d_out;

  transpose_all<<<12288, dim3(32, 8), 0, stream>>>(
      wq, wk, wv, w_proj, w1, w2, wqkv_t, wproj_t, w1t, w2t);

  ln_rows<<<BT_, 256, 0, stream>>>(x, ln1_g, ln1_b, hbuf);

  // QKV GEMM with fused repack epilogue: writes q(scaled)/k/vt directly
  gemm128<0,0,0,0,1><<<dim3(3072/128, BT_/128), 256, 0, stream>>>(
      hbuf, wqkv_t, nullptr, nullptr, qb, BT_, 3072, D_, D_);

  attn_fwd<<<dim3(512), 256, 0, stream>>>(qb, kb, vtb, aout);

  // proj: split-K=2 partials, then fused reduce + bias + x-residual + LN2
  gemm128<0,0,0,1,0><<<dim3(D_/128, BT_/128, 2), 256, 0, stream>>>(
      aout, wproj_t, nullptr, nullptr, pparts, BT_, D_, D_, D_/2);
  reduce2_ln<<<BT_, 256, 0, stream>>>(
      pparts, b_proj, x, ln2_g, ln2_b, xout, h2, BT_*D_);

  // FF1: [4096,1024] x [4096,1024]^T -> GELU -> bf16 [4096,4096]
  gemm128<1,1,1,0,0><<<dim3(FF_/128, BT_/128), 256, 0, stream>>>(
      h2, w1t, b1, nullptr, ff1, BT_, FF_, D_, D_);

  // FF2: split-K=4 partials + fused reduce (bias + xout residual) -> xout in place
  gemm128<0,0,0,1,0><<<dim3(D_/128, BT_/128, 4), 256, 0, stream>>>(
      ff1, w2t, nullptr, nullptr, fparts, BT_, D_, FF_, FF_/4);
  reduce_parts<4><<<(BT_*D_)/1024, 256, 0, stream>>>(
      fparts, b2, xout, xout, BT_*D_, D_);
}